// Round 1
// baseline (2135.598 us; speedup 1.0000x reference)
//
#include <hip/hip_runtime.h>
#include <hip/hip_bf16.h>
#include <cstdint>
#include <cstddef>

constexpr int Bc = 4, Lc = 4096, Dc = 768, Nc = 16;
constexpr int M_TOT = Bc * Lc;     // 16384
constexpr int TWO_D = 2 * Dc;      // 1536

__device__ __forceinline__ float softplusf(float x) {
    return (x > 20.0f) ? x : log1pf(__expf(x));
}
__device__ __forceinline__ float siluf(float x) {
    return x / (1.0f + __expf(-x));
}

// C[M,N] = A[M,K] @ B[K,N], row-major, all dims % 128 == 0 (K % 16 == 0).
// EPI 0: plain store; 1: softplus(v + bias[col])
template<int EPI>
__global__ __launch_bounds__(256)
void gemm128(const float* __restrict__ A, const float* __restrict__ Bm,
             float* __restrict__ C, int M, int N, int K,
             const float* __restrict__ bias)
{
    __shared__ float As[16][128];   // [k][m] (transposed on store)
    __shared__ float Bs[16][128];   // [k][n]
    const int tid = threadIdx.x;
    const int tx = tid & 15, ty = tid >> 4;
    const int row0 = blockIdx.y * 128, col0 = blockIdx.x * 128;

    // staging indices
    const int ar = tid >> 1;          // 0..127 (row within A tile)
    const int ak = (tid & 1) * 8;     // k offset 0 or 8
    const int bk = tid >> 4;          // 0..15  (k row of B tile)
    const int bn = (tid & 15) * 8;    // col offset within B tile

    const float* Ap = A + (size_t)(row0 + ar) * K + ak;
    const float* Bp = Bm + (size_t)bk * N + col0 + bn;

    float acc[8][8];
    #pragma unroll
    for (int i = 0; i < 8; ++i)
        #pragma unroll
        for (int j = 0; j < 8; ++j) acc[i][j] = 0.f;

    const int KT = K >> 4;
    for (int kt = 0; kt < KT; ++kt) {
        float4 va0 = *(const float4*)(Ap);
        float4 va1 = *(const float4*)(Ap + 4);
        float4 vb0 = *(const float4*)(Bp);
        float4 vb1 = *(const float4*)(Bp + 4);
        Ap += 16;
        Bp += (size_t)16 * N;
        __syncthreads();
        As[ak + 0][ar] = va0.x; As[ak + 1][ar] = va0.y;
        As[ak + 2][ar] = va0.z; As[ak + 3][ar] = va0.w;
        As[ak + 4][ar] = va1.x; As[ak + 5][ar] = va1.y;
        As[ak + 6][ar] = va1.z; As[ak + 7][ar] = va1.w;
        *(float4*)&Bs[bk][bn]     = vb0;
        *(float4*)&Bs[bk][bn + 4] = vb1;
        __syncthreads();
        #pragma unroll
        for (int k = 0; k < 16; ++k) {
            float a[8], b[8];
            *(float4*)&a[0] = *(const float4*)&As[k][ty * 4];
            *(float4*)&a[4] = *(const float4*)&As[k][64 + ty * 4];
            *(float4*)&b[0] = *(const float4*)&Bs[k][tx * 4];
            *(float4*)&b[4] = *(const float4*)&Bs[k][64 + tx * 4];
            #pragma unroll
            for (int i = 0; i < 8; ++i)
                #pragma unroll
                for (int j = 0; j < 8; ++j)
                    acc[i][j] = fmaf(a[i], b[j], acc[i][j]);
        }
    }

    #pragma unroll
    for (int i = 0; i < 8; ++i) {
        const int row = row0 + ((i < 4) ? (ty * 4 + i) : (64 + ty * 4 + (i - 4)));
        float* crow = C + (size_t)row * N + col0;
        #pragma unroll
        for (int h = 0; h < 2; ++h) {
            const int cb = h * 64 + tx * 4;
            float4 v;
            v.x = acc[i][h * 4 + 0]; v.y = acc[i][h * 4 + 1];
            v.z = acc[i][h * 4 + 2]; v.w = acc[i][h * 4 + 3];
            if (EPI == 1) {
                v.x = softplusf(v.x + bias[col0 + cb + 0]);
                v.y = softplusf(v.y + bias[col0 + cb + 1]);
                v.z = softplusf(v.z + bias[col0 + cb + 2]);
                v.w = softplusf(v.w + bias[col0 + cb + 3]);
            }
            *(float4*)(crow + cb) = v;
        }
    }
}

// x_ssm[b,t,d] = silu(conv_b[d] + sum_k xz[b, t+k-3, d] * conv_w[d,k]), xz first half
__global__ __launch_bounds__(256)
void conv_silu_kernel(const float* __restrict__ xz, const float* __restrict__ cw,
                      const float* __restrict__ cb, float* __restrict__ xs)
{
    const int idx = blockIdx.x * 256 + threadIdx.x;
    if (idx >= M_TOT * Dc) return;
    const int d = idx % Dc;
    const int r = idx / Dc;
    const int t = r & (Lc - 1);
    const int b = r >> 12;
    float acc = cb[d];
    #pragma unroll
    for (int k = 0; k < 4; ++k) {
        const int tt = t + k - 3;
        if (tt >= 0)
            acc = fmaf(xz[(size_t)(b * Lc + tt) * TWO_D + d], cw[d * 4 + k], acc);
    }
    xs[idx] = siluf(acc);
}

// BC[r, 0..31] = xs[r,:] @ W_x   (B = cols 0..15, C = cols 16..31)
__global__ __launch_bounds__(256)
void bc_kernel(const float* __restrict__ xs, const float* __restrict__ Wx,
               float* __restrict__ BC)
{
    __shared__ float xsh[8][768];
    const int r0 = blockIdx.x * 8;
    const int tid = threadIdx.x;
    for (int i = tid; i < 1536; i += 256) {
        const int rr = i / 192, c4 = i % 192;
        *(float4*)&xsh[rr][c4 * 4] = *(const float4*)(xs + (size_t)(r0 + rr) * Dc + c4 * 4);
    }
    __syncthreads();
    const int c = tid & 31, rr = tid >> 5;
    float acc = 0.f;
    for (int k = 0; k < Dc; ++k)
        acc = fmaf(xsh[rr][k], Wx[k * 32 + c], acc);
    BC[(size_t)(r0 + rr) * 32 + c] = acc;
}

// selective scan: 16 lanes per (b,d), lane = n. 1-step prefetch to hide latency.
__global__ __launch_bounds__(256)
void scan_kernel(const float* __restrict__ dt, const float* xs,
                 float* y, const float* __restrict__ BC,
                 const float* __restrict__ A_log, const float* __restrict__ Dvec)
{
    const int tid = blockIdx.x * 256 + threadIdx.x;
    const int g = tid >> 4;
    const int n = tid & 15;
    const int bi = g / Dc;
    const int di = g % Dc;
    const float A = -expf(A_log[di * Nc + n]);
    const float Dd = Dvec[di];
    const float* dtp = dt + (size_t)bi * Lc * Dc + di;
    const float* xp  = xs + (size_t)bi * Lc * Dc + di;
    float*       yp  = y  + (size_t)bi * Lc * Dc + di;
    const float* bcp = BC + (size_t)bi * Lc * 32;

    float s = 0.f;
    float dtv = dtp[0];
    float xv  = xp[0];
    float Bv  = bcp[n];
    float Cv  = bcp[16 + n];
    for (int t = 0; t < Lc; ++t) {
        const float dt_c = dtv, x_c = xv, B_c = Bv, C_c = Cv;
        if (t + 1 < Lc) {
            const size_t o = (size_t)(t + 1) * Dc;
            dtv = dtp[o];
            xv  = xp[o];
            Bv  = bcp[(t + 1) * 32 + n];
            Cv  = bcp[(t + 1) * 32 + 16 + n];
        }
        const float dA = __expf(dt_c * A);
        s = fmaf(s, dA, B_c * x_c);
        float p = s * C_c;
        p += __shfl_xor(p, 1, 16);
        p += __shfl_xor(p, 2, 16);
        p += __shfl_xor(p, 4, 16);
        p += __shfl_xor(p, 8, 16);
        if (n == 0) yp[(size_t)t * Dc] = p + Dd * x_c;
    }
}

// y *= silu(z), z = xz[:, 768:1536]
__global__ __launch_bounds__(256)
void gate_kernel(float* __restrict__ y, const float* __restrict__ xz)
{
    const size_t i4 = (size_t)blockIdx.x * 256 + threadIdx.x;
    if (i4 >= (size_t)M_TOT * Dc / 4) return;
    const size_t e0 = i4 * 4;
    const size_t r = e0 / Dc;
    const int c = (int)(e0 % Dc);
    const float4 zv = *(const float4*)(xz + r * TWO_D + Dc + c);
    float4 yv = ((float4*)y)[i4];
    yv.x *= siluf(zv.x);
    yv.y *= siluf(zv.y);
    yv.z *= siluf(zv.z);
    yv.w *= siluf(zv.w);
    ((float4*)y)[i4] = yv;
}

extern "C" void kernel_launch(void* const* d_in, const int* in_sizes, int n_in,
                              void* d_out, int out_size, void* d_ws, size_t ws_size,
                              hipStream_t stream)
{
    const float* x      = (const float*)d_in[0];
    const float* state  = (const float*)d_in[1];
    const float* W_in   = (const float*)d_in[2];
    const float* conv_w = (const float*)d_in[3];
    const float* conv_b = (const float*)d_in[4];
    const float* W_x    = (const float*)d_in[5];
    const float* W_dt   = (const float*)d_in[6];
    const float* b_dt   = (const float*)d_in[7];
    const float* A_log  = (const float*)d_in[8];
    const float* Dvec   = (const float*)d_in[9];
    const float* W_out  = (const float*)d_in[10];
    float* out = (float*)d_out;

    float* ws  = (float*)d_ws;
    float* xz  = ws;                                  // [16384,1536]
    float* xs  = xz  + (size_t)M_TOT * TWO_D;         // [16384,768]
    float* dtb = xs  + (size_t)M_TOT * Dc;            // [16384,768]
    float* yb  = dtb + (size_t)M_TOT * Dc;            // [16384,768]
    float* bc  = yb  + (size_t)M_TOT * Dc;            // [16384,32]

    // 1) xz = x @ W_in
    gemm128<0><<<dim3(TWO_D / 128, M_TOT / 128), 256, 0, stream>>>(
        x, W_in, xz, M_TOT, TWO_D, Dc, nullptr);
    // 2) x_ssm = silu(causal depthwise conv(xz[:, :768]))
    conv_silu_kernel<<<(M_TOT * Dc + 255) / 256, 256, 0, stream>>>(xz, conv_w, conv_b, xs);
    // 3) dt = softplus(x_ssm @ W_dt + b_dt)
    gemm128<1><<<dim3(Dc / 128, M_TOT / 128), 256, 0, stream>>>(
        xs, W_dt, dtb, M_TOT, Dc, Dc, b_dt);
    // 4) BC = x_ssm @ W_x
    bc_kernel<<<M_TOT / 8, 256, 0, stream>>>(xs, W_x, bc);
    // 5) selective scan -> y (includes D*x)
    scan_kernel<<<(Bc * Dc * Nc) / 256, 256, 0, stream>>>(dtb, xs, yb, bc, A_log, Dvec);
    // 6) y *= silu(z)
    gate_kernel<<<(M_TOT * Dc / 4 + 255) / 256, 256, 0, stream>>>(yb, xz);
    // 7) out = y @ W_out
    gemm128<0><<<dim3(Dc / 128, M_TOT / 128), 256, 0, stream>>>(
        yb, W_out, out, M_TOT, Dc, Dc, nullptr);
    // 8) state pass-through
    hipMemcpyAsync(out + (size_t)M_TOT * Dc, state,
                   (size_t)(Bc * Dc * Nc) * sizeof(float),
                   hipMemcpyDeviceToDevice, stream);
}

// Round 2
// 1344.771 us; speedup vs baseline: 1.5881x; 1.5881x over previous
//
#include <hip/hip_runtime.h>
#include <hip/hip_bf16.h>
#include <cstdint>
#include <cstddef>

constexpr int Bc = 4, Lc = 4096, Dc = 768, Nc = 16;
constexpr int M_TOT = Bc * Lc;     // 16384
constexpr int TWO_D = 2 * Dc;      // 1536
constexpr int NCH = 32;            // chunks per sequence
constexpr int TCH = Lc / NCH;      // 128 timesteps per chunk

__device__ __forceinline__ float softplusf(float x) {
    return (x > 20.0f) ? x : log1pf(__expf(x));
}
__device__ __forceinline__ float siluf(float x) {
    return x / (1.0f + __expf(-x));
}

// C[M,N] = A[M,K] @ B[K,N], row-major, all dims % 128 == 0 (K % 16 == 0).
// EPI 0: plain store; 1: softplus(v + bias[col])
template<int EPI>
__global__ __launch_bounds__(256)
void gemm128(const float* __restrict__ A, const float* __restrict__ Bm,
             float* __restrict__ C, int M, int N, int K,
             const float* __restrict__ bias)
{
    __shared__ float As[16][128];   // [k][m] (transposed on store)
    __shared__ float Bs[16][128];   // [k][n]
    const int tid = threadIdx.x;
    const int tx = tid & 15, ty = tid >> 4;
    const int row0 = blockIdx.y * 128, col0 = blockIdx.x * 128;

    const int ar = tid >> 1;          // 0..127 (row within A tile)
    const int ak = (tid & 1) * 8;     // k offset 0 or 8
    const int bk = tid >> 4;          // 0..15  (k row of B tile)
    const int bn = (tid & 15) * 8;    // col offset within B tile

    const float* Ap = A + (size_t)(row0 + ar) * K + ak;
    const float* Bp = Bm + (size_t)bk * N + col0 + bn;

    float acc[8][8];
    #pragma unroll
    for (int i = 0; i < 8; ++i)
        #pragma unroll
        for (int j = 0; j < 8; ++j) acc[i][j] = 0.f;

    const int KT = K >> 4;
    for (int kt = 0; kt < KT; ++kt) {
        float4 va0 = *(const float4*)(Ap);
        float4 va1 = *(const float4*)(Ap + 4);
        float4 vb0 = *(const float4*)(Bp);
        float4 vb1 = *(const float4*)(Bp + 4);
        Ap += 16;
        Bp += (size_t)16 * N;
        __syncthreads();
        As[ak + 0][ar] = va0.x; As[ak + 1][ar] = va0.y;
        As[ak + 2][ar] = va0.z; As[ak + 3][ar] = va0.w;
        As[ak + 4][ar] = va1.x; As[ak + 5][ar] = va1.y;
        As[ak + 6][ar] = va1.z; As[ak + 7][ar] = va1.w;
        *(float4*)&Bs[bk][bn]     = vb0;
        *(float4*)&Bs[bk][bn + 4] = vb1;
        __syncthreads();
        #pragma unroll
        for (int k = 0; k < 16; ++k) {
            float a[8], b[8];
            *(float4*)&a[0] = *(const float4*)&As[k][ty * 4];
            *(float4*)&a[4] = *(const float4*)&As[k][64 + ty * 4];
            *(float4*)&b[0] = *(const float4*)&Bs[k][tx * 4];
            *(float4*)&b[4] = *(const float4*)&Bs[k][64 + tx * 4];
            #pragma unroll
            for (int i = 0; i < 8; ++i)
                #pragma unroll
                for (int j = 0; j < 8; ++j)
                    acc[i][j] = fmaf(a[i], b[j], acc[i][j]);
        }
    }

    #pragma unroll
    for (int i = 0; i < 8; ++i) {
        const int row = row0 + ((i < 4) ? (ty * 4 + i) : (64 + ty * 4 + (i - 4)));
        float* crow = C + (size_t)row * N + col0;
        #pragma unroll
        for (int h = 0; h < 2; ++h) {
            const int cb = h * 64 + tx * 4;
            float4 v;
            v.x = acc[i][h * 4 + 0]; v.y = acc[i][h * 4 + 1];
            v.z = acc[i][h * 4 + 2]; v.w = acc[i][h * 4 + 3];
            if (EPI == 1) {
                v.x = softplusf(v.x + bias[col0 + cb + 0]);
                v.y = softplusf(v.y + bias[col0 + cb + 1]);
                v.z = softplusf(v.z + bias[col0 + cb + 2]);
                v.w = softplusf(v.w + bias[col0 + cb + 3]);
            }
            *(float4*)(crow + cb) = v;
        }
    }
}

// x_ssm[b,t,d] = silu(conv_b[d] + sum_k xz[b, t+k-3, d] * conv_w[d,k]), xz first half
__global__ __launch_bounds__(256)
void conv_silu_kernel(const float* __restrict__ xz, const float* __restrict__ cw,
                      const float* __restrict__ cb, float* __restrict__ xs)
{
    const int idx = blockIdx.x * 256 + threadIdx.x;
    if (idx >= M_TOT * Dc) return;
    const int d = idx % Dc;
    const int r = idx / Dc;
    const int t = r & (Lc - 1);
    const int b = r >> 12;
    float acc = cb[d];
    #pragma unroll
    for (int k = 0; k < 4; ++k) {
        const int tt = t + k - 3;
        if (tt >= 0)
            acc = fmaf(xz[(size_t)(b * Lc + tt) * TWO_D + d], cw[d * 4 + k], acc);
    }
    xs[idx] = siluf(acc);
}

// BC[r, 0..31] = xs[r,:] @ W_x   (B = cols 0..15, C = cols 16..31)
__global__ __launch_bounds__(256)
void bc_kernel(const float* __restrict__ xs, const float* __restrict__ Wx,
               float* __restrict__ BC)
{
    __shared__ float xsh[8][768];
    const int r0 = blockIdx.x * 8;
    const int tid = threadIdx.x;
    for (int i = tid; i < 1536; i += 256) {
        const int rr = i / 192, c4 = i % 192;
        *(float4*)&xsh[rr][c4 * 4] = *(const float4*)(xs + (size_t)(r0 + rr) * Dc + c4 * 4);
    }
    __syncthreads();
    const int c = tid & 31, rr = tid >> 5;
    float acc = 0.f;
    for (int k = 0; k < Dc; ++k)
        acc = fmaf(xsh[rr][k], Wx[k * 32 + c], acc);
    BC[(size_t)(r0 + rr) * 32 + c] = acc;
}

// ---------------- chunked parallel selective scan ----------------
// Thread mapping (phases A/C): tid = ((b*NCH + ch)*Dc + d)*16 + n
// 16 lanes per (b,ch,d) group share dt/xs loads (broadcast); n across lanes.

// Phase A: local scan from s=0 over chunk; emit P = prod(dA), S = local state.
__global__ __launch_bounds__(256)
void scan_phase_a(const float* __restrict__ dt, const float* __restrict__ xs,
                  const float* __restrict__ BC, const float* __restrict__ A_log,
                  float* __restrict__ Pout, float* __restrict__ Sout)
{
    const int tid = blockIdx.x * 256 + threadIdx.x;
    const int n = tid & 15;
    const int g = tid >> 4;
    const int d = g % Dc;
    const int bch = g / Dc;            // b*NCH + ch
    const int ch = bch % NCH;
    const int b = bch / NCH;
    const int t0 = ch * TCH;
    const float A = -expf(A_log[d * Nc + n]);
    const float* dtp = dt + ((size_t)(b * Lc + t0)) * Dc + d;
    const float* xp  = xs + ((size_t)(b * Lc + t0)) * Dc + d;
    const float* bp  = BC + ((size_t)(b * Lc + t0)) * 32 + n;

    float s = 0.f, P = 1.f;
    float dtv = dtp[0], xv = xp[0], Bv = bp[0];
    for (int t = 0; t < TCH; ++t) {
        const float dt_c = dtv, x_c = xv, B_c = Bv;
        if (t + 1 < TCH) {
            dtv = dtp[(size_t)(t + 1) * Dc];
            xv  = xp[(size_t)(t + 1) * Dc];
            Bv  = bp[(t + 1) * 32];
        }
        const float dA = __expf(dt_c * A);
        s = fmaf(s, dA, B_c * x_c);
        P *= dA;
    }
    Pout[tid] = P;
    Sout[tid] = s;
}

// Phase B: sequential combine across chunks; emit init state per chunk.
__global__ __launch_bounds__(256)
void scan_phase_b(const float* __restrict__ P, const float* __restrict__ S,
                  float* __restrict__ I)
{
    const int tid = blockIdx.x * 256 + threadIdx.x;   // (b, d, n)
    const int n = tid & 15;
    const int d = (tid >> 4) % Dc;
    const int b = tid / (16 * Dc);
    float s = 0.f;
    for (int ch = 0; ch < NCH; ++ch) {
        const size_t idx = ((size_t)((b * NCH + ch) * Dc) + d) * 16 + n;
        I[idx] = s;
        s = fmaf(s, P[idx], S[idx]);
    }
}

// Phase C: re-run local scan from true init; produce y = (<s,C> + D*x) * silu(z).
// Writes y IN-PLACE over xs (each element read before written by its own thread).
__global__ __launch_bounds__(256)
void scan_phase_c(const float* __restrict__ dt, float* __restrict__ xs_y,
                  const float* __restrict__ BC, const float* __restrict__ A_log,
                  const float* __restrict__ Dvec, const float* __restrict__ I,
                  const float* __restrict__ xz)
{
    const int tid = blockIdx.x * 256 + threadIdx.x;
    const int n = tid & 15;
    const int g = tid >> 4;
    const int d = g % Dc;
    const int bch = g / Dc;
    const int ch = bch % NCH;
    const int b = bch / NCH;
    const int t0 = ch * TCH;
    const float A = -expf(A_log[d * Nc + n]);
    const float Dd = Dvec[d];
    const float* dtp = dt + ((size_t)(b * Lc + t0)) * Dc + d;
    float* xyp       = xs_y + ((size_t)(b * Lc + t0)) * Dc + d;
    const float* bcp = BC + ((size_t)(b * Lc + t0)) * 32;
    const float* zp  = xz + ((size_t)(b * Lc + t0)) * TWO_D + Dc + d;

    float s = I[tid];
    float dtv = dtp[0], xv = xyp[0], Bv = bcp[n], Cv = bcp[16 + n], zv = zp[0];
    for (int t = 0; t < TCH; ++t) {
        const float dt_c = dtv, x_c = xv, B_c = Bv, C_c = Cv, z_c = zv;
        if (t + 1 < TCH) {
            dtv = dtp[(size_t)(t + 1) * Dc];
            xv  = xyp[(size_t)(t + 1) * Dc];
            Bv  = bcp[(t + 1) * 32 + n];
            Cv  = bcp[(t + 1) * 32 + 16 + n];
            zv  = zp[(size_t)(t + 1) * TWO_D];
        }
        const float dA = __expf(dt_c * A);
        s = fmaf(s, dA, B_c * x_c);
        float p = s * C_c;
        p += __shfl_xor(p, 1, 16);
        p += __shfl_xor(p, 2, 16);
        p += __shfl_xor(p, 4, 16);
        p += __shfl_xor(p, 8, 16);
        if (n == 0)
            xyp[(size_t)t * Dc] = (p + Dd * x_c) * siluf(z_c);
    }
}

extern "C" void kernel_launch(void* const* d_in, const int* in_sizes, int n_in,
                              void* d_out, int out_size, void* d_ws, size_t ws_size,
                              hipStream_t stream)
{
    const float* x      = (const float*)d_in[0];
    const float* state  = (const float*)d_in[1];
    const float* W_in   = (const float*)d_in[2];
    const float* conv_w = (const float*)d_in[3];
    const float* conv_b = (const float*)d_in[4];
    const float* W_x    = (const float*)d_in[5];
    const float* W_dt   = (const float*)d_in[6];
    const float* b_dt   = (const float*)d_in[7];
    const float* A_log  = (const float*)d_in[8];
    const float* Dvec   = (const float*)d_in[9];
    const float* W_out  = (const float*)d_in[10];
    float* out = (float*)d_out;

    float* ws  = (float*)d_ws;
    float* xz  = ws;                                  // [16384,1536]
    float* xs  = xz  + (size_t)M_TOT * TWO_D;         // [16384,768]  (y in-place later)
    float* dtb = xs  + (size_t)M_TOT * Dc;            // [16384,768]
    float* bc  = dtb + (size_t)M_TOT * Dc;            // [16384,32]
    float* Pb  = bc  + (size_t)M_TOT * 32;            // [b,ch,d,n] = 1.57M
    float* Sb  = Pb  + (size_t)Bc * NCH * Dc * Nc;
    float* Ib  = Sb  + (size_t)Bc * NCH * Dc * Nc;

    // 1) xz = x @ W_in
    gemm128<0><<<dim3(TWO_D / 128, M_TOT / 128), 256, 0, stream>>>(
        x, W_in, xz, M_TOT, TWO_D, Dc, nullptr);
    // 2) x_ssm = silu(causal depthwise conv(xz[:, :768]))
    conv_silu_kernel<<<(M_TOT * Dc + 255) / 256, 256, 0, stream>>>(xz, conv_w, conv_b, xs);
    // 3) dt = softplus(x_ssm @ W_dt + b_dt)
    gemm128<1><<<dim3(Dc / 128, M_TOT / 128), 256, 0, stream>>>(
        xs, W_dt, dtb, M_TOT, Dc, Dc, b_dt);
    // 4) BC = x_ssm @ W_x
    bc_kernel<<<M_TOT / 8, 256, 0, stream>>>(xs, W_x, bc);
    // 5) chunked selective scan (+ fused D*x and gate); y overwrites xs
    const int ngA = Bc * NCH * Dc * Nc / 256;   // 6144 blocks
    scan_phase_a<<<ngA, 256, 0, stream>>>(dtb, xs, bc, A_log, Pb, Sb);
    scan_phase_b<<<(Bc * Dc * Nc) / 256, 256, 0, stream>>>(Pb, Sb, Ib);
    scan_phase_c<<<ngA, 256, 0, stream>>>(dtb, xs, bc, A_log, Dvec, Ib, xz);
    // 6) out = y @ W_out
    gemm128<0><<<dim3(Dc / 128, M_TOT / 128), 256, 0, stream>>>(
        xs, W_out, out, M_TOT, Dc, Dc, nullptr);
    // 7) state pass-through
    hipMemcpyAsync(out + (size_t)M_TOT * Dc, state,
                   (size_t)(Bc * Dc * Nc) * sizeof(float),
                   hipMemcpyDeviceToDevice, stream);
}

// Round 6
// 1188.494 us; speedup vs baseline: 1.7969x; 1.1315x over previous
//
#include <hip/hip_runtime.h>
#include <hip/hip_bf16.h>
#include <cstdint>
#include <cstddef>

constexpr int Bc = 4, Lc = 4096, Dc = 768, Nc = 16;
constexpr int M_TOT = Bc * Lc;     // 16384
constexpr int TWO_D = 2 * Dc;      // 1536
constexpr int NCH = 32;            // chunks per sequence
constexpr int TCH = Lc / NCH;      // 128
constexpr int Kd = 768;

typedef __attribute__((ext_vector_type(8))) short short8v;   // 8 bf16 (4 VGPRs)
typedef __attribute__((ext_vector_type(4))) float f32x4;     // MFMA acc

__device__ __forceinline__ float softplusf(float x) {
    return (x > 20.0f) ? x : log1pf(__expf(x));
}
__device__ __forceinline__ float siluf(float x) {
    return x / (1.0f + __expf(-x));
}

// ---------------- fp32 GEMM (round-2 verbatim, known-good) ----------------
template<int EPI>
__global__ __launch_bounds__(256)
void gemm128(const float* __restrict__ A, const float* __restrict__ Bm,
             float* __restrict__ C, int M, int N, int K,
             const float* __restrict__ bias)
{
    __shared__ float As[16][128];
    __shared__ float Bs[16][128];
    const int tid = threadIdx.x;
    const int tx = tid & 15, ty = tid >> 4;
    const int row0 = blockIdx.y * 128, col0 = blockIdx.x * 128;

    const int ar = tid >> 1;
    const int ak = (tid & 1) * 8;
    const int bk = tid >> 4;
    const int bn = (tid & 15) * 8;

    const float* Ap = A + (size_t)(row0 + ar) * K + ak;
    const float* Bp = Bm + (size_t)bk * N + col0 + bn;

    float acc[8][8];
    #pragma unroll
    for (int i = 0; i < 8; ++i)
        #pragma unroll
        for (int j = 0; j < 8; ++j) acc[i][j] = 0.f;

    const int KT = K >> 4;
    for (int kt = 0; kt < KT; ++kt) {
        float4 va0 = *(const float4*)(Ap);
        float4 va1 = *(const float4*)(Ap + 4);
        float4 vb0 = *(const float4*)(Bp);
        float4 vb1 = *(const float4*)(Bp + 4);
        Ap += 16;
        Bp += (size_t)16 * N;
        __syncthreads();
        As[ak + 0][ar] = va0.x; As[ak + 1][ar] = va0.y;
        As[ak + 2][ar] = va0.z; As[ak + 3][ar] = va0.w;
        As[ak + 4][ar] = va1.x; As[ak + 5][ar] = va1.y;
        As[ak + 6][ar] = va1.z; As[ak + 7][ar] = va1.w;
        *(float4*)&Bs[bk][bn]     = vb0;
        *(float4*)&Bs[bk][bn + 4] = vb1;
        __syncthreads();
        #pragma unroll
        for (int k = 0; k < 16; ++k) {
            float a[8], b[8];
            *(float4*)&a[0] = *(const float4*)&As[k][ty * 4];
            *(float4*)&a[4] = *(const float4*)&As[k][64 + ty * 4];
            *(float4*)&b[0] = *(const float4*)&Bs[k][tx * 4];
            *(float4*)&b[4] = *(const float4*)&Bs[k][64 + tx * 4];
            #pragma unroll
            for (int i = 0; i < 8; ++i)
                #pragma unroll
                for (int j = 0; j < 8; ++j)
                    acc[i][j] = fmaf(a[i], b[j], acc[i][j]);
        }
    }

    #pragma unroll
    for (int i = 0; i < 8; ++i) {
        const int row = row0 + ((i < 4) ? (ty * 4 + i) : (64 + ty * 4 + (i - 4)));
        float* crow = C + (size_t)row * N + col0;
        #pragma unroll
        for (int h = 0; h < 2; ++h) {
            const int cb = h * 64 + tx * 4;
            float4 v;
            v.x = acc[i][h * 4 + 0]; v.y = acc[i][h * 4 + 1];
            v.z = acc[i][h * 4 + 2]; v.w = acc[i][h * 4 + 3];
            if (EPI == 1) {
                v.x = softplusf(v.x + bias[col0 + cb + 0]);
                v.y = softplusf(v.y + bias[col0 + cb + 1]);
                v.z = softplusf(v.z + bias[col0 + cb + 2]);
                v.w = softplusf(v.w + bias[col0 + cb + 3]);
            }
            *(float4*)(crow + cb) = v;
        }
    }
}

// ---------------- bf16 MFMA GEMM (round-5 core, EPI=0 only) — UNDER TEST ----------------
__global__ __launch_bounds__(256)
void gemm_bf16(const __hip_bfloat16* __restrict__ Ab,
               const __hip_bfloat16* __restrict__ Wt,
               int N, float* __restrict__ out0)
{
    __shared__ __hip_bfloat16 Asm[128 * 32];   // [row][k] linear, 64 B rows
    __shared__ __hip_bfloat16 Bsm[128 * 32];
    const int tid = threadIdx.x;
    const int w = tid >> 6, lane = tid & 63;
    const int lr = lane & 15, lc = lane >> 4;
    const int row0 = blockIdx.y * 128, col0 = blockIdx.x * 128;
    const int wrow = (w >> 1) * 64, wcol = (w & 1) * 64;

    const int sr = tid >> 1;
    const int sh = (tid & 1) * 16;
    const size_t ga = (size_t)(row0 + sr) * Kd + sh;
    const size_t gb = (size_t)(col0 + sr) * Kd + sh;
    const int wo0 = sr * 64 + sh * 2;
    const int wo1 = wo0 + 16;

    f32x4 acc[4][4] = {};

    const int KT = Kd / 32;
    for (int kt = 0; kt < KT; ++kt) {
        const int4 av0 = *(const int4*)(Ab + ga + kt * 32);
        const int4 av1 = *(const int4*)(Ab + ga + kt * 32 + 8);
        const int4 bv0 = *(const int4*)(Wt + gb + kt * 32);
        const int4 bv1 = *(const int4*)(Wt + gb + kt * 32 + 8);
        __syncthreads();
        *(int4*)((char*)Asm + wo0) = av0;
        *(int4*)((char*)Asm + wo1) = av1;
        *(int4*)((char*)Bsm + wo0) = bv0;
        *(int4*)((char*)Bsm + wo1) = bv1;
        __syncthreads();

        short8v a[4], b[4];
        #pragma unroll
        for (int m = 0; m < 4; ++m)
            a[m] = *(const short8v*)((char*)Asm + (wrow + m * 16 + lr) * 64 + lc * 16);
        #pragma unroll
        for (int nf = 0; nf < 4; ++nf)
            b[nf] = *(const short8v*)((char*)Bsm + (wcol + nf * 16 + lr) * 64 + lc * 16);
        #pragma unroll
        for (int m = 0; m < 4; ++m)
            #pragma unroll
            for (int nf = 0; nf < 4; ++nf)
                acc[m][nf] = __builtin_amdgcn_mfma_f32_16x16x32_bf16(
                    a[m], b[nf], acc[m][nf], 0, 0, 0);
    }

    #pragma unroll
    for (int m = 0; m < 4; ++m)
        #pragma unroll
        for (int nf = 0; nf < 4; ++nf)
            #pragma unroll
            for (int j = 0; j < 4; ++j) {
                const int rg = row0 + wrow + m * 16 + lc * 4 + j;
                const int cg = col0 + wcol + nf * 16 + lr;
                out0[(size_t)rg * N + cg] = acc[m][nf][j];
            }
}

// ---------------- prep (under test) ----------------
__global__ __launch_bounds__(256)
void to_bf16_kernel(const float* __restrict__ src, __hip_bfloat16* __restrict__ dst, int n4)
{
    const int i = blockIdx.x * 256 + threadIdx.x;
    if (i >= n4) return;
    const float4 v = ((const float4*)src)[i];
    dst[i * 4 + 0] = __float2bfloat16(v.x);
    dst[i * 4 + 1] = __float2bfloat16(v.y);
    dst[i * 4 + 2] = __float2bfloat16(v.z);
    dst[i * 4 + 3] = __float2bfloat16(v.w);
}

__global__ __launch_bounds__(256)
void wtrans_kernel(const float* __restrict__ src, __hip_bfloat16* __restrict__ dst, int N)
{
    const int idx = blockIdx.x * 256 + threadIdx.x;
    if (idx >= N * Kd) return;
    const int n = idx / Kd, k = idx % Kd;
    dst[idx] = __float2bfloat16(src[(size_t)k * N + n]);
}

// ---------------- conv + silu (round-2 verbatim) ----------------
__global__ __launch_bounds__(256)
void conv_silu_kernel(const float* __restrict__ xz, const float* __restrict__ cw,
                      const float* __restrict__ cb, float* __restrict__ xs)
{
    const int idx = blockIdx.x * 256 + threadIdx.x;
    if (idx >= M_TOT * Dc) return;
    const int d = idx % Dc;
    const int r = idx / Dc;
    const int t = r & (Lc - 1);
    const int b = r >> 12;
    float acc = cb[d];
    #pragma unroll
    for (int k = 0; k < 4; ++k) {
        const int tt = t + k - 3;
        if (tt >= 0)
            acc = fmaf(xz[(size_t)(b * Lc + tt) * TWO_D + d], cw[d * 4 + k], acc);
    }
    xs[idx] = siluf(acc);
}

// ---------------- BC (round-2 verbatim) ----------------
__global__ __launch_bounds__(256)
void bc_kernel(const float* __restrict__ xs, const float* __restrict__ Wx,
               float* __restrict__ BC)
{
    __shared__ float xsh[8][768];
    const int r0 = blockIdx.x * 8;
    const int tid = threadIdx.x;
    for (int i = tid; i < 1536; i += 256) {
        const int rr = i / 192, c4 = i % 192;
        *(float4*)&xsh[rr][c4 * 4] = *(const float4*)(xs + (size_t)(r0 + rr) * Dc + c4 * 4);
    }
    __syncthreads();
    const int c = tid & 31, rr = tid >> 5;
    float acc = 0.f;
    for (int k = 0; k < Dc; ++k)
        acc = fmaf(xsh[rr][k], Wx[k * 32 + c], acc);
    BC[(size_t)(r0 + rr) * 32 + c] = acc;
}

// ---------------- chunked scan (round-2 verbatim) ----------------
__global__ __launch_bounds__(256)
void scan_phase_a(const float* __restrict__ dt, const float* __restrict__ xs,
                  const float* __restrict__ BC, const float* __restrict__ A_log,
                  float* __restrict__ Pout, float* __restrict__ Sout)
{
    const int tid = blockIdx.x * 256 + threadIdx.x;
    const int n = tid & 15;
    const int g = tid >> 4;
    const int d = g % Dc;
    const int bch = g / Dc;
    const int ch = bch % NCH;
    const int b = bch / NCH;
    const int t0 = ch * TCH;
    const float A = -expf(A_log[d * Nc + n]);
    const float* dtp = dt + ((size_t)(b * Lc + t0)) * Dc + d;
    const float* xp  = xs + ((size_t)(b * Lc + t0)) * Dc + d;
    const float* bp  = BC + ((size_t)(b * Lc + t0)) * 32 + n;

    float s = 0.f, P = 1.f;
    float dtv = dtp[0], xv = xp[0], Bv = bp[0];
    for (int t = 0; t < TCH; ++t) {
        const float dt_c = dtv, x_c = xv, B_c = Bv;
        if (t + 1 < TCH) {
            dtv = dtp[(size_t)(t + 1) * Dc];
            xv  = xp[(size_t)(t + 1) * Dc];
            Bv  = bp[(t + 1) * 32];
        }
        const float dA = __expf(dt_c * A);
        s = fmaf(s, dA, B_c * x_c);
        P *= dA;
    }
    Pout[tid] = P;
    Sout[tid] = s;
}

__global__ __launch_bounds__(256)
void scan_phase_b(const float* __restrict__ P, const float* __restrict__ S,
                  float* __restrict__ I)
{
    const int tid = blockIdx.x * 256 + threadIdx.x;
    const int n = tid & 15;
    const int d = (tid >> 4) % Dc;
    const int b = tid / (16 * Dc);
    float s = 0.f;
    for (int ch = 0; ch < NCH; ++ch) {
        const size_t idx = ((size_t)((b * NCH + ch) * Dc) + d) * 16 + n;
        I[idx] = s;
        s = fmaf(s, P[idx], S[idx]);
    }
}

__global__ __launch_bounds__(256)
void scan_phase_c(const float* __restrict__ dt, float* __restrict__ xs_y,
                  const float* __restrict__ BC, const float* __restrict__ A_log,
                  const float* __restrict__ Dvec, const float* __restrict__ I,
                  const float* __restrict__ xz)
{
    const int tid = blockIdx.x * 256 + threadIdx.x;
    const int n = tid & 15;
    const int g = tid >> 4;
    const int d = g % Dc;
    const int bch = g / Dc;
    const int ch = bch % NCH;
    const int b = bch / NCH;
    const int t0 = ch * TCH;
    const float A = -expf(A_log[d * Nc + n]);
    const float Dd = Dvec[d];
    const float* dtp = dt + ((size_t)(b * Lc + t0)) * Dc + d;
    float* xyp       = xs_y + ((size_t)(b * Lc + t0)) * Dc + d;
    const float* bcp = BC + ((size_t)(b * Lc + t0)) * 32;
    const float* zp  = xz + ((size_t)(b * Lc + t0)) * TWO_D + Dc + d;

    float s = I[tid];
    float dtv = dtp[0], xv = xyp[0], Bv = bcp[n], Cv = bcp[16 + n], zv = zp[0];
    for (int t = 0; t < TCH; ++t) {
        const float dt_c = dtv, x_c = xv, B_c = Bv, C_c = Cv, z_c = zv;
        if (t + 1 < TCH) {
            dtv = dtp[(size_t)(t + 1) * Dc];
            xv  = xyp[(size_t)(t + 1) * Dc];
            Bv  = bcp[(t + 1) * 32 + n];
            Cv  = bcp[(t + 1) * 32 + 16 + n];
            zv  = zp[(size_t)(t + 1) * TWO_D];
        }
        const float dA = __expf(dt_c * A);
        s = fmaf(s, dA, B_c * x_c);
        float p = s * C_c;
        p += __shfl_xor(p, 1, 16);
        p += __shfl_xor(p, 2, 16);
        p += __shfl_xor(p, 4, 16);
        p += __shfl_xor(p, 8, 16);
        if (n == 0)
            xyp[(size_t)t * Dc] = (p + Dd * x_c) * siluf(z_c);
    }
}

extern "C" void kernel_launch(void* const* d_in, const int* in_sizes, int n_in,
                              void* d_out, int out_size, void* d_ws, size_t ws_size,
                              hipStream_t stream)
{
    const float* x      = (const float*)d_in[0];
    const float* state  = (const float*)d_in[1];
    const float* W_in   = (const float*)d_in[2];
    const float* conv_w = (const float*)d_in[3];
    const float* conv_b = (const float*)d_in[4];
    const float* W_x    = (const float*)d_in[5];
    const float* W_dt   = (const float*)d_in[6];
    const float* b_dt   = (const float*)d_in[7];
    const float* A_log  = (const float*)d_in[8];
    const float* Dvec   = (const float*)d_in[9];
    const float* W_out  = (const float*)d_in[10];
    float* out = (float*)d_out;

    // ---- workspace: round-2 layout + bf16 tail (248.6 MB <= 253.75 verified) ----
    char* wsb = (char*)d_ws;
    float* xz  = (float*)wsb;                        wsb += (size_t)M_TOT * TWO_D * 4;
    float* xs  = (float*)wsb;                        wsb += (size_t)M_TOT * Dc * 4;
    float* dtb = (float*)wsb;                        wsb += (size_t)M_TOT * Dc * 4;
    float* bc  = (float*)wsb;                        wsb += (size_t)M_TOT * 32 * 4;
    float* Pb  = (float*)wsb;                        wsb += (size_t)Bc * NCH * Dc * Nc * 4;
    float* Sb  = (float*)wsb;                        wsb += (size_t)Bc * NCH * Dc * Nc * 4;
    float* Ib  = (float*)wsb;                        wsb += (size_t)Bc * NCH * Dc * Nc * 4;
    __hip_bfloat16* ybf  = (__hip_bfloat16*)wsb;     wsb += (size_t)M_TOT * Dc * 2;
    __hip_bfloat16* WoutT = (__hip_bfloat16*)wsb;    wsb += (size_t)Dc * Kd * 2;

    // 1) xz = x @ W_in   (fp32, known-good)
    gemm128<0><<<dim3(TWO_D / 128, M_TOT / 128), 256, 0, stream>>>(
        x, W_in, xz, M_TOT, TWO_D, Dc, nullptr);
    // 2) conv + silu
    conv_silu_kernel<<<(M_TOT * Dc + 255) / 256, 256, 0, stream>>>(xz, conv_w, conv_b, xs);
    // 3) dt (fp32, known-good)
    gemm128<1><<<dim3(Dc / 128, M_TOT / 128), 256, 0, stream>>>(
        xs, W_dt, dtb, M_TOT, Dc, Dc, b_dt);
    // 4) BC
    bc_kernel<<<M_TOT / 8, 256, 0, stream>>>(xs, W_x, bc);
    // 5) chunked scan (+gate, +D*x); y in-place over xs (fp32)
    const int ngA = Bc * NCH * Dc * Nc / 256;
    scan_phase_a<<<ngA, 256, 0, stream>>>(dtb, xs, bc, A_log, Pb, Sb);
    scan_phase_b<<<(Bc * Dc * Nc) / 256, 256, 0, stream>>>(Pb, Sb, Ib);
    scan_phase_c<<<ngA, 256, 0, stream>>>(dtb, xs, bc, A_log, Dvec, Ib, xz);
    // 6) BISECT TARGET: out = y @ W_out via bf16 MFMA (prep + gemm_bf16)
    to_bf16_kernel<<<(M_TOT * Dc / 4 + 255) / 256, 256, 0, stream>>>(xs, ybf, M_TOT * Dc / 4);
    wtrans_kernel<<<(Dc * Kd + 255) / 256, 256, 0, stream>>>(W_out, WoutT, Dc);
    gemm_bf16<<<dim3(Dc / 128, M_TOT / 128), 256, 0, stream>>>(ybf, WoutT, Dc, out);
    // 7) state pass-through
    hipMemcpyAsync(out + (size_t)M_TOT * Dc, state,
                   (size_t)(Bc * Dc * Nc) * sizeof(float),
                   hipMemcpyDeviceToDevice, stream);
}

// Round 7
// 681.020 us; speedup vs baseline: 3.1359x; 1.7452x over previous
//
#include <hip/hip_runtime.h>
#include <hip/hip_bf16.h>
#include <cstdint>
#include <cstddef>

constexpr int Bc = 4, Lc = 4096, Dc = 768, Nc = 16;
constexpr int M_TOT = Bc * Lc;     // 16384
constexpr int TWO_D = 2 * Dc;      // 1536
constexpr int NCH = 32;            // chunks per sequence
constexpr int TCH = Lc / NCH;      // 128
constexpr int Kd = 768;            // K of all GEMMs

typedef __attribute__((ext_vector_type(8))) short short8v;   // 8 bf16 (4 VGPRs)
typedef __attribute__((ext_vector_type(4))) float f32x4;     // MFMA acc

__device__ __forceinline__ float softplusf(float x) {
    return (x > 20.0f) ? x : log1pf(__expf(x));
}
__device__ __forceinline__ float siluf(float x) {
    return x / (1.0f + __expf(-x));
}

// ---------- bf16 MFMA GEMM, fp32 A staged w/ in-register convert ----------
// C[M,N] = A[M,768] @ WT[N,768]^T.  A fp32 row-major; WT bf16 row-major.
// Single fp32 output. EPI 0: plain store. EPI 1: softplus(v + bias[col]).
// LDS: linear [row][32] bf16 (64 B rows); staging dest = tid*16 B (contiguous
// per wave, conflict-free); frag-read/MFMA/epilogue = round-6 HW-verified.
template<int EPI>
__global__ __launch_bounds__(256)
void gemm_a32(const float* __restrict__ Af, const __hip_bfloat16* __restrict__ Wt,
              int N, float* __restrict__ out0, const float* __restrict__ bias)
{
    __shared__ __hip_bfloat16 Asm[128 * 32];
    __shared__ __hip_bfloat16 Bsm[128 * 32];
    const int tid = threadIdx.x;
    const int w = tid >> 6, lane = tid & 63;
    const int lr = lane & 15, lc = lane >> 4;
    const int row0 = blockIdx.y * 128, col0 = blockIdx.x * 128;
    const int wrow = (w >> 1) * 64, wcol = (w & 1) * 64;

    // staging: thread owns elems [tc, tc+8) of rows tr and 64+tr
    const int tr = tid >> 2;          // 0..63
    const int tc = (tid & 3) * 8;     // 0,8,16,24
    const size_t gaA0 = (size_t)(row0 + tr) * Kd + tc;
    const size_t gaA1 = (size_t)(row0 + 64 + tr) * Kd + tc;
    const size_t gbB0 = (size_t)(col0 + tr) * Kd + tc;
    const size_t gbB1 = (size_t)(col0 + 64 + tr) * Kd + tc;
    const int wo0 = tid * 16;         // LDS bytes: row tr, byte tc*2
    const int wo1 = 4096 + tid * 16;  // row 64+tr

    f32x4 acc[4][4] = {};

    const int KT = Kd / 32;
    for (int kt = 0; kt < KT; ++kt) {
        const int ko = kt * 32;
        const float4 a00 = *(const float4*)(Af + gaA0 + ko);
        const float4 a01 = *(const float4*)(Af + gaA0 + ko + 4);
        const float4 a10 = *(const float4*)(Af + gaA1 + ko);
        const float4 a11 = *(const float4*)(Af + gaA1 + ko + 4);
        const int4  b0  = *(const int4*)(Wt + gbB0 + ko);
        const int4  b1  = *(const int4*)(Wt + gbB1 + ko);
        __hip_bfloat16 ab[16];
        ab[0]  = __float2bfloat16(a00.x); ab[1]  = __float2bfloat16(a00.y);
        ab[2]  = __float2bfloat16(a00.z); ab[3]  = __float2bfloat16(a00.w);
        ab[4]  = __float2bfloat16(a01.x); ab[5]  = __float2bfloat16(a01.y);
        ab[6]  = __float2bfloat16(a01.z); ab[7]  = __float2bfloat16(a01.w);
        ab[8]  = __float2bfloat16(a10.x); ab[9]  = __float2bfloat16(a10.y);
        ab[10] = __float2bfloat16(a10.z); ab[11] = __float2bfloat16(a10.w);
        ab[12] = __float2bfloat16(a11.x); ab[13] = __float2bfloat16(a11.y);
        ab[14] = __float2bfloat16(a11.z); ab[15] = __float2bfloat16(a11.w);
        const int4 av0 = *(const int4*)&ab[0];
        const int4 av1 = *(const int4*)&ab[8];
        __syncthreads();                 // previous iter's readers done
        *(int4*)((char*)Asm + wo0) = av0;
        *(int4*)((char*)Asm + wo1) = av1;
        *(int4*)((char*)Bsm + wo0) = b0;
        *(int4*)((char*)Bsm + wo1) = b1;
        __syncthreads();                 // tile visible

        short8v a[4], b[4];
        #pragma unroll
        for (int m = 0; m < 4; ++m)
            a[m] = *(const short8v*)((char*)Asm + (wrow + m * 16 + lr) * 64 + lc * 16);
        #pragma unroll
        for (int nf = 0; nf < 4; ++nf)
            b[nf] = *(const short8v*)((char*)Bsm + (wcol + nf * 16 + lr) * 64 + lc * 16);
        #pragma unroll
        for (int m = 0; m < 4; ++m)
            #pragma unroll
            for (int nf = 0; nf < 4; ++nf)
                acc[m][nf] = __builtin_amdgcn_mfma_f32_16x16x32_bf16(
                    a[m], b[nf], acc[m][nf], 0, 0, 0);
    }

    // epilogue: C/D frag mapping col=lane&15, row=(lane>>4)*4+reg [HW-verified r6]
    #pragma unroll
    for (int m = 0; m < 4; ++m)
        #pragma unroll
        for (int nf = 0; nf < 4; ++nf)
            #pragma unroll
            for (int j = 0; j < 4; ++j) {
                const int rg = row0 + wrow + m * 16 + lc * 4 + j;
                const int cg = col0 + wcol + nf * 16 + lr;
                float v = acc[m][nf][j];
                if (EPI == 1) v = softplusf(v + bias[cg]);
                out0[(size_t)rg * N + cg] = v;
            }
}

// W[K=768][N] fp32 -> WT[N][768] bf16 (HW-verified round 6)
__global__ __launch_bounds__(256)
void wtrans_kernel(const float* __restrict__ src, __hip_bfloat16* __restrict__ dst, int N)
{
    const int idx = blockIdx.x * 256 + threadIdx.x;
    if (idx >= N * Kd) return;
    const int n = idx / Kd, k = idx % Kd;
    dst[idx] = __float2bfloat16(src[(size_t)k * N + n]);
}

// ---------------- conv + silu (round-2 verbatim) ----------------
__global__ __launch_bounds__(256)
void conv_silu_kernel(const float* __restrict__ xz, const float* __restrict__ cw,
                      const float* __restrict__ cb, float* __restrict__ xs)
{
    const int idx = blockIdx.x * 256 + threadIdx.x;
    if (idx >= M_TOT * Dc) return;
    const int d = idx % Dc;
    const int r = idx / Dc;
    const int t = r & (Lc - 1);
    const int b = r >> 12;
    float acc = cb[d];
    #pragma unroll
    for (int k = 0; k < 4; ++k) {
        const int tt = t + k - 3;
        if (tt >= 0)
            acc = fmaf(xz[(size_t)(b * Lc + tt) * TWO_D + d], cw[d * 4 + k], acc);
    }
    xs[idx] = siluf(acc);
}

// ---------------- BC (round-2 verbatim) ----------------
__global__ __launch_bounds__(256)
void bc_kernel(const float* __restrict__ xs, const float* __restrict__ Wx,
               float* __restrict__ BC)
{
    __shared__ float xsh[8][768];
    const int r0 = blockIdx.x * 8;
    const int tid = threadIdx.x;
    for (int i = tid; i < 1536; i += 256) {
        const int rr = i / 192, c4 = i % 192;
        *(float4*)&xsh[rr][c4 * 4] = *(const float4*)(xs + (size_t)(r0 + rr) * Dc + c4 * 4);
    }
    __syncthreads();
    const int c = tid & 31, rr = tid >> 5;
    float acc = 0.f;
    for (int k = 0; k < Dc; ++k)
        acc = fmaf(xsh[rr][k], Wx[k * 32 + c], acc);
    BC[(size_t)(r0 + rr) * 32 + c] = acc;
}

// ---------------- chunked scan (round-2 verbatim) ----------------
__global__ __launch_bounds__(256)
void scan_phase_a(const float* __restrict__ dt, const float* __restrict__ xs,
                  const float* __restrict__ BC, const float* __restrict__ A_log,
                  float* __restrict__ Pout, float* __restrict__ Sout)
{
    const int tid = blockIdx.x * 256 + threadIdx.x;
    const int n = tid & 15;
    const int g = tid >> 4;
    const int d = g % Dc;
    const int bch = g / Dc;
    const int ch = bch % NCH;
    const int b = bch / NCH;
    const int t0 = ch * TCH;
    const float A = -expf(A_log[d * Nc + n]);
    const float* dtp = dt + ((size_t)(b * Lc + t0)) * Dc + d;
    const float* xp  = xs + ((size_t)(b * Lc + t0)) * Dc + d;
    const float* bp  = BC + ((size_t)(b * Lc + t0)) * 32 + n;

    float s = 0.f, P = 1.f;
    float dtv = dtp[0], xv = xp[0], Bv = bp[0];
    for (int t = 0; t < TCH; ++t) {
        const float dt_c = dtv, x_c = xv, B_c = Bv;
        if (t + 1 < TCH) {
            dtv = dtp[(size_t)(t + 1) * Dc];
            xv  = xp[(size_t)(t + 1) * Dc];
            Bv  = bp[(t + 1) * 32];
        }
        const float dA = __expf(dt_c * A);
        s = fmaf(s, dA, B_c * x_c);
        P *= dA;
    }
    Pout[tid] = P;
    Sout[tid] = s;
}

__global__ __launch_bounds__(256)
void scan_phase_b(const float* __restrict__ P, const float* __restrict__ S,
                  float* __restrict__ I)
{
    const int tid = blockIdx.x * 256 + threadIdx.x;
    const int n = tid & 15;
    const int d = (tid >> 4) % Dc;
    const int b = tid / (16 * Dc);
    float s = 0.f;
    for (int ch = 0; ch < NCH; ++ch) {
        const size_t idx = ((size_t)((b * NCH + ch) * Dc) + d) * 16 + n;
        I[idx] = s;
        s = fmaf(s, P[idx], S[idx]);
    }
}

__global__ __launch_bounds__(256)
void scan_phase_c(const float* __restrict__ dt, float* __restrict__ xs_y,
                  const float* __restrict__ BC, const float* __restrict__ A_log,
                  const float* __restrict__ Dvec, const float* __restrict__ I,
                  const float* __restrict__ xz)
{
    const int tid = blockIdx.x * 256 + threadIdx.x;
    const int n = tid & 15;
    const int g = tid >> 4;
    const int d = g % Dc;
    const int bch = g / Dc;
    const int ch = bch % NCH;
    const int b = bch / NCH;
    const int t0 = ch * TCH;
    const float A = -expf(A_log[d * Nc + n]);
    const float Dd = Dvec[d];
    const float* dtp = dt + ((size_t)(b * Lc + t0)) * Dc + d;
    float* xyp       = xs_y + ((size_t)(b * Lc + t0)) * Dc + d;
    const float* bcp = BC + ((size_t)(b * Lc + t0)) * 32;
    const float* zp  = xz + ((size_t)(b * Lc + t0)) * TWO_D + Dc + d;

    float s = I[tid];
    float dtv = dtp[0], xv = xyp[0], Bv = bcp[n], Cv = bcp[16 + n], zv = zp[0];
    for (int t = 0; t < TCH; ++t) {
        const float dt_c = dtv, x_c = xv, B_c = Bv, C_c = Cv, z_c = zv;
        if (t + 1 < TCH) {
            dtv = dtp[(size_t)(t + 1) * Dc];
            xv  = xyp[(size_t)(t + 1) * Dc];
            Bv  = bcp[(t + 1) * 32 + n];
            Cv  = bcp[(t + 1) * 32 + 16 + n];
            zv  = zp[(size_t)(t + 1) * TWO_D];
        }
        const float dA = __expf(dt_c * A);
        s = fmaf(s, dA, B_c * x_c);
        float p = s * C_c;
        p += __shfl_xor(p, 1, 16);
        p += __shfl_xor(p, 2, 16);
        p += __shfl_xor(p, 4, 16);
        p += __shfl_xor(p, 8, 16);
        if (n == 0)
            xyp[(size_t)t * Dc] = (p + Dd * x_c) * siluf(z_c);
    }
}

extern "C" void kernel_launch(void* const* d_in, const int* in_sizes, int n_in,
                              void* d_out, int out_size, void* d_ws, size_t ws_size,
                              hipStream_t stream)
{
    const float* x      = (const float*)d_in[0];
    const float* state  = (const float*)d_in[1];
    const float* W_in   = (const float*)d_in[2];
    const float* conv_w = (const float*)d_in[3];
    const float* conv_b = (const float*)d_in[4];
    const float* W_x    = (const float*)d_in[5];
    const float* W_dt   = (const float*)d_in[6];
    const float* b_dt   = (const float*)d_in[7];
    const float* A_log  = (const float*)d_in[8];
    const float* Dvec   = (const float*)d_in[9];
    const float* W_out  = (const float*)d_in[10];
    float* out = (float*)d_out;

    // ---- workspace (227.0 MB <= 253.75 verified) ----
    char* wsb = (char*)d_ws;
    float* xz  = (float*)wsb;                        wsb += (size_t)M_TOT * TWO_D * 4;
    float* xs  = (float*)wsb;                        wsb += (size_t)M_TOT * Dc * 4;
    float* dtb = (float*)wsb;                        wsb += (size_t)M_TOT * Dc * 4;
    float* bc  = (float*)wsb;                        wsb += (size_t)M_TOT * 32 * 4;
    float* Pb  = (float*)wsb;                        wsb += (size_t)Bc * NCH * Dc * Nc * 4;
    float* Sb  = (float*)wsb;                        wsb += (size_t)Bc * NCH * Dc * Nc * 4;
    float* Ib  = (float*)wsb;                        wsb += (size_t)Bc * NCH * Dc * Nc * 4;
    __hip_bfloat16* WinT  = (__hip_bfloat16*)wsb;    wsb += (size_t)1536 * Kd * 2;
    __hip_bfloat16* WdtT  = (__hip_bfloat16*)wsb;    wsb += (size_t)768 * Kd * 2;
    __hip_bfloat16* WoutT = (__hip_bfloat16*)wsb;    wsb += (size_t)768 * Kd * 2;

    // ---- weight prep ----
    wtrans_kernel<<<(1536 * Kd + 255) / 256, 256, 0, stream>>>(W_in, WinT, 1536);
    wtrans_kernel<<<(768 * Kd + 255) / 256, 256, 0, stream>>>(W_dt, WdtT, 768);
    wtrans_kernel<<<(768 * Kd + 255) / 256, 256, 0, stream>>>(W_out, WoutT, 768);

    // 1) xz = x @ W_in  (bf16 MFMA, fp32 in/out)
    gemm_a32<0><<<dim3(TWO_D / 128, M_TOT / 128), 256, 0, stream>>>(
        x, WinT, TWO_D, xz, nullptr);
    // 2) conv + silu
    conv_silu_kernel<<<(M_TOT * Dc + 255) / 256, 256, 0, stream>>>(xz, conv_w, conv_b, xs);
    // 3) dt = softplus(xs @ W_dt + b_dt)
    gemm_a32<1><<<dim3(Dc / 128, M_TOT / 128), 256, 0, stream>>>(
        xs, WdtT, Dc, dtb, b_dt);
    // 4) BC = xs @ W_x
    bc_kernel<<<M_TOT / 8, 256, 0, stream>>>(xs, W_x, bc);
    // 5) chunked scan (+gate, +D*x); y in-place over xs
    const int ngA = Bc * NCH * Dc * Nc / 256;
    scan_phase_a<<<ngA, 256, 0, stream>>>(dtb, xs, bc, A_log, Pb, Sb);
    scan_phase_b<<<(Bc * Dc * Nc) / 256, 256, 0, stream>>>(Pb, Sb, Ib);
    scan_phase_c<<<ngA, 256, 0, stream>>>(dtb, xs, bc, A_log, Dvec, Ib, xz);
    // 6) out = y @ W_out
    gemm_a32<0><<<dim3(Dc / 128, M_TOT / 128), 256, 0, stream>>>(
        xs, WoutT, Dc, out, nullptr);
    // 7) state pass-through
    hipMemcpyAsync(out + (size_t)M_TOT * Dc, state,
                   (size_t)(Bc * Dc * Nc) * sizeof(float),
                   hipMemcpyDeviceToDevice, stream);
}

// Round 8
// 538.334 us; speedup vs baseline: 3.9671x; 1.2651x over previous
//
#include <hip/hip_runtime.h>
#include <hip/hip_bf16.h>
#include <cstdint>
#include <cstddef>

constexpr int Bc = 4, Lc = 4096, Dc = 768, Nc = 16;
constexpr int M_TOT = Bc * Lc;     // 16384
constexpr int NCH = 64;            // chunks per sequence
constexpr int TCH = Lc / NCH;      // 64
constexpr int Kd = 768;            // K of all GEMMs

typedef __attribute__((ext_vector_type(8))) short short8v;   // 8 bf16 (4 VGPRs)
typedef __attribute__((ext_vector_type(4))) float f32x4;     // MFMA acc

__device__ __forceinline__ float softplusf(float x) {
    return (x > 20.0f) ? x : log1pf(__expf(x));
}
__device__ __forceinline__ float siluf(float x) {
    return x / (1.0f + __expf(-x));
}

// ---------- bf16 MFMA GEMM (round-7 HW-verified, verbatim) ----------
template<int EPI>
__global__ __launch_bounds__(256)
void gemm_a32(const float* __restrict__ Af, const __hip_bfloat16* __restrict__ Wt,
              int N, float* __restrict__ out0, const float* __restrict__ bias)
{
    __shared__ __hip_bfloat16 Asm[128 * 32];
    __shared__ __hip_bfloat16 Bsm[128 * 32];
    const int tid = threadIdx.x;
    const int w = tid >> 6, lane = tid & 63;
    const int lr = lane & 15, lc = lane >> 4;
    const int row0 = blockIdx.y * 128, col0 = blockIdx.x * 128;
    const int wrow = (w >> 1) * 64, wcol = (w & 1) * 64;

    const int tr = tid >> 2;
    const int tc = (tid & 3) * 8;
    const size_t gaA0 = (size_t)(row0 + tr) * Kd + tc;
    const size_t gaA1 = (size_t)(row0 + 64 + tr) * Kd + tc;
    const size_t gbB0 = (size_t)(col0 + tr) * Kd + tc;
    const size_t gbB1 = (size_t)(col0 + 64 + tr) * Kd + tc;
    const int wo0 = tid * 16;
    const int wo1 = 4096 + tid * 16;

    f32x4 acc[4][4] = {};

    const int KT = Kd / 32;
    for (int kt = 0; kt < KT; ++kt) {
        const int ko = kt * 32;
        const float4 a00 = *(const float4*)(Af + gaA0 + ko);
        const float4 a01 = *(const float4*)(Af + gaA0 + ko + 4);
        const float4 a10 = *(const float4*)(Af + gaA1 + ko);
        const float4 a11 = *(const float4*)(Af + gaA1 + ko + 4);
        const int4  b0  = *(const int4*)(Wt + gbB0 + ko);
        const int4  b1  = *(const int4*)(Wt + gbB1 + ko);
        __hip_bfloat16 ab[16];
        ab[0]  = __float2bfloat16(a00.x); ab[1]  = __float2bfloat16(a00.y);
        ab[2]  = __float2bfloat16(a00.z); ab[3]  = __float2bfloat16(a00.w);
        ab[4]  = __float2bfloat16(a01.x); ab[5]  = __float2bfloat16(a01.y);
        ab[6]  = __float2bfloat16(a01.z); ab[7]  = __float2bfloat16(a01.w);
        ab[8]  = __float2bfloat16(a10.x); ab[9]  = __float2bfloat16(a10.y);
        ab[10] = __float2bfloat16(a10.z); ab[11] = __float2bfloat16(a10.w);
        ab[12] = __float2bfloat16(a11.x); ab[13] = __float2bfloat16(a11.y);
        ab[14] = __float2bfloat16(a11.z); ab[15] = __float2bfloat16(a11.w);
        const int4 av0 = *(const int4*)&ab[0];
        const int4 av1 = *(const int4*)&ab[8];
        __syncthreads();
        *(int4*)((char*)Asm + wo0) = av0;
        *(int4*)((char*)Asm + wo1) = av1;
        *(int4*)((char*)Bsm + wo0) = b0;
        *(int4*)((char*)Bsm + wo1) = b1;
        __syncthreads();

        short8v a[4], b[4];
        #pragma unroll
        for (int m = 0; m < 4; ++m)
            a[m] = *(const short8v*)((char*)Asm + (wrow + m * 16 + lr) * 64 + lc * 16);
        #pragma unroll
        for (int nf = 0; nf < 4; ++nf)
            b[nf] = *(const short8v*)((char*)Bsm + (wcol + nf * 16 + lr) * 64 + lc * 16);
        #pragma unroll
        for (int m = 0; m < 4; ++m)
            #pragma unroll
            for (int nf = 0; nf < 4; ++nf)
                acc[m][nf] = __builtin_amdgcn_mfma_f32_16x16x32_bf16(
                    a[m], b[nf], acc[m][nf], 0, 0, 0);
    }

    #pragma unroll
    for (int m = 0; m < 4; ++m)
        #pragma unroll
        for (int nf = 0; nf < 4; ++nf)
            #pragma unroll
            for (int j = 0; j < 4; ++j) {
                const int rg = row0 + wrow + m * 16 + lc * 4 + j;
                const int cg = col0 + wcol + nf * 16 + lr;
                float v = acc[m][nf][j];
                if (EPI == 1) v = softplusf(v + bias[cg]);
                out0[(size_t)rg * N + cg] = v;
            }
}

// W[K=768][N] fp32 -> WT[N][768] bf16 (HW-verified)
__global__ __launch_bounds__(256)
void wtrans_kernel(const float* __restrict__ src, __hip_bfloat16* __restrict__ dst, int N)
{
    const int idx = blockIdx.x * 256 + threadIdx.x;
    if (idx >= N * Kd) return;
    const int n = idx / Kd, k = idx % Kd;
    dst[idx] = __float2bfloat16(src[(size_t)k * N + n]);
}

// Abuf[d][n] = -exp(A_log[d][n])
__global__ __launch_bounds__(256)
void aprep_kernel(const float* __restrict__ A_log, float* __restrict__ Abuf)
{
    const int i = blockIdx.x * 256 + threadIdx.x;
    if (i < Dc * Nc) Abuf[i] = -expf(A_log[i]);
}

// ---------------- conv + silu (xc stride Dc now) ----------------
__global__ __launch_bounds__(256)
void conv_silu_kernel(const float* __restrict__ xc, const float* __restrict__ cw,
                      const float* __restrict__ cb, float* __restrict__ xs)
{
    const int idx = blockIdx.x * 256 + threadIdx.x;
    if (idx >= M_TOT * Dc) return;
    const int d = idx % Dc;
    const int t = (idx / Dc) & (Lc - 1);
    float acc = cb[d];
    #pragma unroll
    for (int k = 0; k < 4; ++k) {
        const int tt = t + k - 3;
        if (tt >= 0)
            acc = fmaf(xc[(size_t)idx + (ptrdiff_t)(k - 3) * Dc], cw[d * 4 + k], acc);
    }
    xs[idx] = siluf(acc);
}

// ---------------- BC (round-2 verbatim) ----------------
__global__ __launch_bounds__(256)
void bc_kernel(const float* __restrict__ xs, const float* __restrict__ Wx,
               float* __restrict__ BC)
{
    __shared__ float xsh[8][768];
    const int r0 = blockIdx.x * 8;
    const int tid = threadIdx.x;
    for (int i = tid; i < 1536; i += 256) {
        const int rr = i / 192, c4 = i % 192;
        *(float4*)&xsh[rr][c4 * 4] = *(const float4*)(xs + (size_t)(r0 + rr) * Dc + c4 * 4);
    }
    __syncthreads();
    const int c = tid & 31, rr = tid >> 5;
    float acc = 0.f;
    for (int k = 0; k < Dc; ++k)
        acc = fmaf(xsh[rr][k], Wx[k * 32 + c], acc);
    BC[(size_t)(r0 + rr) * 32 + c] = acc;
}

// ---------------- NEW chunked scan ----------------
// Phase A: block=(b,ch,dblk); thread owns (b,ch,d) with all 16 n in registers.
// Emits yloc=<s_local,C_t>, dcum (in-place over dt), and end-of-chunk P,S.
__global__ __launch_bounds__(256)
void scanA(const float* __restrict__ dtb, const float* __restrict__ xs,
           const float* __restrict__ bc, const float* __restrict__ Abuf,
           float* __restrict__ dcum, float* __restrict__ yloc,
           float* __restrict__ P, float* __restrict__ S)
{
    const int blk = blockIdx.x;
    const int dblk = blk % 3, ch = (blk / 3) % NCH, b = blk / (3 * NCH);
    const int d = dblk * 256 + threadIdx.x;
    const int t0 = ch * TCH;

    __shared__ float bcs[TCH * 32];   // 8 KB chunk tile of (B|C)
    {
        const float* src = bc + ((size_t)(b * Lc + t0)) * 32;
        *(float4*)&bcs[threadIdx.x * 8]     = *(const float4*)(src + threadIdx.x * 8);
        *(float4*)&bcs[threadIdx.x * 8 + 4] = *(const float4*)(src + threadIdx.x * 8 + 4);
    }
    __syncthreads();

    float A[16];
    #pragma unroll
    for (int q = 0; q < 4; ++q)
        *(float4*)&A[q * 4] = *(const float4*)(Abuf + d * 16 + q * 4);

    float s[16];
    #pragma unroll
    for (int n = 0; n < 16; ++n) s[n] = 0.f;

    const size_t base = ((size_t)(b * Lc + t0)) * Dc + d;
    float dc = 0.f;
    for (int t = 0; t < TCH; ++t) {
        const float dt = dtb[base + (size_t)t * Dc];
        const float x  = xs[base + (size_t)t * Dc];
        dc += dt;
        float Bt[16], Ct[16];
        #pragma unroll
        for (int q = 0; q < 4; ++q) {
            *(float4*)&Bt[q * 4] = *(const float4*)&bcs[t * 32 + q * 4];
            *(float4*)&Ct[q * 4] = *(const float4*)&bcs[t * 32 + 16 + q * 4];
        }
        float yl = 0.f;
        #pragma unroll
        for (int n = 0; n < 16; ++n) {
            const float dA = __expf(dt * A[n]);
            s[n] = fmaf(s[n], dA, Bt[n] * x);
            yl = fmaf(s[n], Ct[n], yl);
        }
        yloc[base + (size_t)t * Dc] = yl;
        dcum[base + (size_t)t * Dc] = dc;   // overwrites dt (already consumed)
    }
    const size_t o = (((size_t)(b * NCH + ch) * Dc) + d) * 16;
    #pragma unroll
    for (int n = 0; n < 16; ++n) {
        P[o + n] = __expf(dc * A[n]);
        S[o + n] = s[n];
    }
}

// Phase B: sequential combine across chunks (tiny).
__global__ __launch_bounds__(256)
void scanB(const float* __restrict__ P, const float* __restrict__ S,
           float* __restrict__ I)
{
    const int tid = blockIdx.x * 256 + threadIdx.x;   // (b, d, n)
    const int n = tid & 15;
    const int d = (tid >> 4) % Dc;
    const int b = tid / (16 * Dc);
    float s = 0.f;
    for (int ch = 0; ch < NCH; ++ch) {
        const size_t idx = ((size_t)((b * NCH + ch) * Dc) + d) * 16 + n;
        I[idx] = s;
        s = fmaf(s, P[idx], S[idx]);
    }
}

// Phase C: ELEMENTWISE. y = (yloc + sum_n I_n*exp(A_n*dcum)*C_n + D*x)*silu(z).
// Writes y in-place over yloc.
__global__ __launch_bounds__(256)
void scanC(const float* __restrict__ xs, const float* __restrict__ zb,
           float* __restrict__ yloc, const float* __restrict__ dcum,
           const float* __restrict__ bc, const float* __restrict__ Abuf,
           const float* __restrict__ Ibuf, const float* __restrict__ Dvec)
{
    const int blk = blockIdx.x;
    const int dblk = blk % 3, ch = (blk / 3) % NCH, b = blk / (3 * NCH);
    const int d = dblk * 256 + threadIdx.x;
    const int t0 = ch * TCH;

    __shared__ float bcs[TCH * 32];
    {
        const float* src = bc + ((size_t)(b * Lc + t0)) * 32;
        *(float4*)&bcs[threadIdx.x * 8]     = *(const float4*)(src + threadIdx.x * 8);
        *(float4*)&bcs[threadIdx.x * 8 + 4] = *(const float4*)(src + threadIdx.x * 8 + 4);
    }
    __syncthreads();

    float A[16], In[16];
    #pragma unroll
    for (int q = 0; q < 4; ++q)
        *(float4*)&A[q * 4] = *(const float4*)(Abuf + d * 16 + q * 4);
    const size_t o = (((size_t)(b * NCH + ch) * Dc) + d) * 16;
    #pragma unroll
    for (int q = 0; q < 4; ++q)
        *(float4*)&In[q * 4] = *(const float4*)(Ibuf + o + q * 4);
    const float Dd = Dvec[d];

    const size_t base = ((size_t)(b * Lc + t0)) * Dc + d;
    for (int t = 0; t < TCH; ++t) {
        const float x  = xs[base + (size_t)t * Dc];
        const float z  = zb[base + (size_t)t * Dc];
        const float yl = yloc[base + (size_t)t * Dc];
        const float dc = dcum[base + (size_t)t * Dc];
        float Ct[16];
        #pragma unroll
        for (int q = 0; q < 4; ++q)
            *(float4*)&Ct[q * 4] = *(const float4*)&bcs[t * 32 + 16 + q * 4];
        float acc = fmaf(Dd, x, yl);
        #pragma unroll
        for (int n = 0; n < 16; ++n)
            acc = fmaf(In[n] * __expf(dc * A[n]), Ct[n], acc);
        yloc[base + (size_t)t * Dc] = acc * siluf(z);
    }
}

extern "C" void kernel_launch(void* const* d_in, const int* in_sizes, int n_in,
                              void* d_out, int out_size, void* d_ws, size_t ws_size,
                              hipStream_t stream)
{
    const float* x      = (const float*)d_in[0];
    const float* state  = (const float*)d_in[1];
    const float* W_in   = (const float*)d_in[2];
    const float* conv_w = (const float*)d_in[3];
    const float* conv_b = (const float*)d_in[4];
    const float* W_x    = (const float*)d_in[5];
    const float* W_dt   = (const float*)d_in[6];
    const float* b_dt   = (const float*)d_in[7];
    const float* A_log  = (const float*)d_in[8];
    const float* Dvec   = (const float*)d_in[9];
    const float* W_out  = (const float*)d_in[10];
    float* out = (float*)d_out;

    // ---- workspace (245.9 MB <= 253.75 verified) ----
    char* wsb = (char*)d_ws;
    float* xc   = (float*)wsb;                       wsb += (size_t)M_TOT * Dc * 4;  // in_proj x-half; yloc aliases later
    float* zb   = (float*)wsb;                       wsb += (size_t)M_TOT * Dc * 4;  // in_proj z-half
    float* xs   = (float*)wsb;                       wsb += (size_t)M_TOT * Dc * 4;  // silu(conv)
    float* dtb  = (float*)wsb;                       wsb += (size_t)M_TOT * Dc * 4;  // dt -> dcum in-place
    float* bc   = (float*)wsb;                       wsb += (size_t)M_TOT * 32 * 4;
    float* Pb   = (float*)wsb;                       wsb += (size_t)Bc * NCH * Dc * Nc * 4;
    float* Sb   = (float*)wsb;                       wsb += (size_t)Bc * NCH * Dc * Nc * 4;
    float* Ib   = (float*)wsb;                       wsb += (size_t)Bc * NCH * Dc * Nc * 4;
    float* Abuf = (float*)wsb;                       wsb += (size_t)Dc * Nc * 4;
    __hip_bfloat16* WinT  = (__hip_bfloat16*)wsb;    wsb += (size_t)1536 * Kd * 2;
    __hip_bfloat16* WdtT  = (__hip_bfloat16*)wsb;    wsb += (size_t)768 * Kd * 2;
    __hip_bfloat16* WoutT = (__hip_bfloat16*)wsb;    wsb += (size_t)768 * Kd * 2;
    float* yloc = xc;   // alias: xc dead after conv

    // ---- prep ----
    wtrans_kernel<<<(1536 * Kd + 255) / 256, 256, 0, stream>>>(W_in, WinT, 1536);
    wtrans_kernel<<<(768 * Kd + 255) / 256, 256, 0, stream>>>(W_dt, WdtT, 768);
    wtrans_kernel<<<(768 * Kd + 255) / 256, 256, 0, stream>>>(W_out, WoutT, 768);
    aprep_kernel<<<(Dc * Nc + 255) / 256, 256, 0, stream>>>(A_log, Abuf);

    // 1) in_proj as two single-output GEMMs: xc = x@W_in[:, :768], z = x@W_in[:, 768:]
    gemm_a32<0><<<dim3(Dc / 128, M_TOT / 128), 256, 0, stream>>>(
        x, WinT, Dc, xc, nullptr);
    gemm_a32<0><<<dim3(Dc / 128, M_TOT / 128), 256, 0, stream>>>(
        x, WinT + (size_t)768 * Kd, Dc, zb, nullptr);
    // 2) conv + silu
    conv_silu_kernel<<<(M_TOT * Dc + 255) / 256, 256, 0, stream>>>(xc, conv_w, conv_b, xs);
    // 3) dt = softplus(xs @ W_dt + b_dt)
    gemm_a32<1><<<dim3(Dc / 128, M_TOT / 128), 256, 0, stream>>>(
        xs, WdtT, Dc, dtb, b_dt);
    // 4) BC = xs @ W_x
    bc_kernel<<<M_TOT / 8, 256, 0, stream>>>(xs, W_x, bc);
    // 5) scan: A (local, 16n/thread) -> B (combine) -> C (elementwise)
    scanA<<<Bc * NCH * 3, 256, 0, stream>>>(dtb, xs, bc, Abuf, dtb, yloc, Pb, Sb);
    scanB<<<(Bc * Dc * Nc) / 256, 256, 0, stream>>>(Pb, Sb, Ib);
    scanC<<<Bc * NCH * 3, 256, 0, stream>>>(xs, zb, yloc, dtb, bc, Abuf, Ib, Dvec);
    // 6) out = y @ W_out
    gemm_a32<0><<<dim3(Dc / 128, M_TOT / 128), 256, 0, stream>>>(
        yloc, WoutT, Dc, out, nullptr);
    // 7) state pass-through
    hipMemcpyAsync(out + (size_t)M_TOT * Dc, state,
                   (size_t)(Bc * Dc * Nc) * sizeof(float),
                   hipMemcpyDeviceToDevice, stream);
}

// Round 10
// 495.964 us; speedup vs baseline: 4.3060x; 1.0854x over previous
//
#include <hip/hip_runtime.h>
#include <hip/hip_bf16.h>
#include <cstdint>
#include <cstddef>

constexpr int Bc = 4, Lc = 4096, Dc = 768, Nc = 16;
constexpr int M_TOT = Bc * Lc;     // 16384
constexpr int NCH = 64;            // chunks per sequence
constexpr int TCH = Lc / NCH;      // 64
constexpr int Kd = 768;            // K of all GEMMs

typedef __attribute__((ext_vector_type(8))) short short8v;   // 8 bf16 (4 VGPRs)
typedef __attribute__((ext_vector_type(4))) float f32x4;     // MFMA acc

__device__ __forceinline__ float softplusf(float x) {
    return (x > 20.0f) ? x : log1pf(__expf(x));
}
__device__ __forceinline__ float siluf(float x) {
    return x / (1.0f + __expf(-x));
}

// ---------- bf16 MFMA GEMM (P5b / round-6 HW-VERIFIED, verbatim; N=768 only) ----------
__global__ __launch_bounds__(256)
void gemm_bf16(const __hip_bfloat16* __restrict__ Ab,
               const __hip_bfloat16* __restrict__ Wt,
               int N, float* __restrict__ out0)
{
    __shared__ __hip_bfloat16 Asm[128 * 32];   // [row][k] linear, 64 B rows
    __shared__ __hip_bfloat16 Bsm[128 * 32];
    const int tid = threadIdx.x;
    const int w = tid >> 6, lane = tid & 63;
    const int lr = lane & 15, lc = lane >> 4;
    const int row0 = blockIdx.y * 128, col0 = blockIdx.x * 128;
    const int wrow = (w >> 1) * 64, wcol = (w & 1) * 64;

    const int sr = tid >> 1;
    const int sh = (tid & 1) * 16;
    const size_t ga = (size_t)(row0 + sr) * Kd + sh;
    const size_t gb = (size_t)(col0 + sr) * Kd + sh;
    const int wo0 = sr * 64 + sh * 2;
    const int wo1 = wo0 + 16;

    f32x4 acc[4][4] = {};

    const int KT = Kd / 32;
    for (int kt = 0; kt < KT; ++kt) {
        const int4 av0 = *(const int4*)(Ab + ga + kt * 32);
        const int4 av1 = *(const int4*)(Ab + ga + kt * 32 + 8);
        const int4 bv0 = *(const int4*)(Wt + gb + kt * 32);
        const int4 bv1 = *(const int4*)(Wt + gb + kt * 32 + 8);
        __syncthreads();
        *(int4*)((char*)Asm + wo0) = av0;
        *(int4*)((char*)Asm + wo1) = av1;
        *(int4*)((char*)Bsm + wo0) = bv0;
        *(int4*)((char*)Bsm + wo1) = bv1;
        __syncthreads();

        short8v a[4], b[4];
        #pragma unroll
        for (int m = 0; m < 4; ++m)
            a[m] = *(const short8v*)((char*)Asm + (wrow + m * 16 + lr) * 64 + lc * 16);
        #pragma unroll
        for (int nf = 0; nf < 4; ++nf)
            b[nf] = *(const short8v*)((char*)Bsm + (wcol + nf * 16 + lr) * 64 + lc * 16);
        #pragma unroll
        for (int m = 0; m < 4; ++m)
            #pragma unroll
            for (int nf = 0; nf < 4; ++nf)
                acc[m][nf] = __builtin_amdgcn_mfma_f32_16x16x32_bf16(
                    a[m], b[nf], acc[m][nf], 0, 0, 0);
    }

    #pragma unroll
    for (int m = 0; m < 4; ++m)
        #pragma unroll
        for (int nf = 0; nf < 4; ++nf)
            #pragma unroll
            for (int j = 0; j < 4; ++j) {
                const int rg = row0 + wrow + m * 16 + lc * 4 + j;
                const int cg = col0 + wcol + nf * 16 + lr;
                out0[(size_t)rg * N + cg] = acc[m][nf][j];
            }
}

// ---------------- prep kernels (HW-verified) ----------------
__global__ __launch_bounds__(256)
void to_bf16_kernel(const float* __restrict__ src, __hip_bfloat16* __restrict__ dst, int n4)
{
    const int i = blockIdx.x * 256 + threadIdx.x;
    if (i >= n4) return;
    const float4 v = ((const float4*)src)[i];
    dst[i * 4 + 0] = __float2bfloat16(v.x);
    dst[i * 4 + 1] = __float2bfloat16(v.y);
    dst[i * 4 + 2] = __float2bfloat16(v.z);
    dst[i * 4 + 3] = __float2bfloat16(v.w);
}

__global__ __launch_bounds__(256)
void wtrans_kernel(const float* __restrict__ src, __hip_bfloat16* __restrict__ dst, int N)
{
    const int idx = blockIdx.x * 256 + threadIdx.x;
    if (idx >= N * Kd) return;
    const int n = idx / Kd, k = idx % Kd;
    dst[idx] = __float2bfloat16(src[(size_t)k * N + n]);
}

__global__ __launch_bounds__(256)
void aprep_kernel(const float* __restrict__ A_log, float* __restrict__ Abuf)
{
    const int i = blockIdx.x * 256 + threadIdx.x;
    if (i < Dc * Nc) Abuf[i] = -expf(A_log[i]);
}

// ---------------- conv + silu: xc fp32 (stride Dc) -> bf16 xsb ----------------
__global__ __launch_bounds__(256)
void conv_silu_kernel(const float* __restrict__ xc, const float* __restrict__ cw,
                      const float* __restrict__ cb, __hip_bfloat16* __restrict__ xsb)
{
    const int idx = blockIdx.x * 256 + threadIdx.x;
    if (idx >= M_TOT * Dc) return;
    const int d = idx % Dc;
    const int t = (idx / Dc) & (Lc - 1);
    float acc = cb[d];
    #pragma unroll
    for (int k = 0; k < 4; ++k) {
        const int tt = t + k - 3;
        if (tt >= 0)
            acc = fmaf(xc[(size_t)idx + (ptrdiff_t)(k - 3) * Dc], cw[d * 4 + k], acc);
    }
    xsb[idx] = __float2bfloat16(siluf(acc));
}

// ---------------- BC = x_ssm @ W_x (bf16 input staged to fp32 LDS) ----------------
__global__ __launch_bounds__(256)
void bc_kernel(const __hip_bfloat16* __restrict__ xsb, const float* __restrict__ Wx,
               float* __restrict__ BC)
{
    __shared__ float xsh[8][768];
    const int r0 = blockIdx.x * 8;
    const int tid = threadIdx.x;
    for (int i = tid; i < 1536; i += 256) {
        const int rr = i / 192, c4 = (i % 192) * 4;
        const __hip_bfloat16* src = xsb + (size_t)(r0 + rr) * Dc + c4;
        xsh[rr][c4 + 0] = __bfloat162float(src[0]);
        xsh[rr][c4 + 1] = __bfloat162float(src[1]);
        xsh[rr][c4 + 2] = __bfloat162float(src[2]);
        xsh[rr][c4 + 3] = __bfloat162float(src[3]);
    }
    __syncthreads();
    const int c = tid & 31, rr = tid >> 5;
    float acc = 0.f;
    for (int k = 0; k < Kd; ++k)
        acc = fmaf(xsh[rr][k], Wx[k * 32 + c], acc);
    BC[(size_t)(r0 + rr) * 32 + c] = acc;
}

// ---------------- chunked scan, closed-form carry (P7 HW-verified structure) ----------------
// Phase A: thread owns (b,ch,d), 16 n in regs. dt = softplus(dtraw + b_dt[d]).
// Emits yloc, dcum (in-place over dtraw), end-of-chunk P,S.
__global__ __launch_bounds__(256)
void scanA(float* __restrict__ dtb, const __hip_bfloat16* __restrict__ xsb,
           const float* __restrict__ bc, const float* __restrict__ Abuf,
           const float* __restrict__ bdt, float* __restrict__ yloc,
           float* __restrict__ P, float* __restrict__ S)
{
    const int blk = blockIdx.x;
    const int dblk = blk % 3, ch = (blk / 3) % NCH, b = blk / (3 * NCH);
    const int d = dblk * 256 + threadIdx.x;
    const int t0 = ch * TCH;

    __shared__ float bcs[TCH * 32];   // 8 KB (B|C) chunk tile
    {
        const float* src = bc + ((size_t)(b * Lc + t0)) * 32;
        *(float4*)&bcs[threadIdx.x * 8]     = *(const float4*)(src + threadIdx.x * 8);
        *(float4*)&bcs[threadIdx.x * 8 + 4] = *(const float4*)(src + threadIdx.x * 8 + 4);
    }
    __syncthreads();

    float A[16];
    #pragma unroll
    for (int q = 0; q < 4; ++q)
        *(float4*)&A[q * 4] = *(const float4*)(Abuf + d * 16 + q * 4);
    const float bd = bdt[d];

    float s[16];
    #pragma unroll
    for (int n = 0; n < 16; ++n) s[n] = 0.f;

    const size_t base = ((size_t)(b * Lc + t0)) * Dc + d;
    float dc = 0.f;
    for (int t = 0; t < TCH; ++t) {
        const float dt = softplusf(dtb[base + (size_t)t * Dc] + bd);
        const float x  = __bfloat162float(xsb[base + (size_t)t * Dc]);
        dc += dt;
        float yl = 0.f;
        #pragma unroll
        for (int n = 0; n < 16; ++n) {
            const float dA = __expf(dt * A[n]);
            s[n] = fmaf(s[n], dA, bcs[t * 32 + n] * x);
            yl = fmaf(s[n], bcs[t * 32 + 16 + n], yl);
        }
        yloc[base + (size_t)t * Dc] = yl;
        dtb[base + (size_t)t * Dc] = dc;   // dcum over dtraw (consumed)
    }
    const size_t o = (((size_t)(b * NCH + ch) * Dc) + d) * 16;
    #pragma unroll
    for (int n = 0; n < 16; ++n) {
        P[o + n] = __expf(dc * A[n]);
        S[o + n] = s[n];
    }
}

// Phase B: combine across chunks (P7 verbatim).
__global__ __launch_bounds__(256)
void scanB(const float* __restrict__ P, const float* __restrict__ S,
           float* __restrict__ I)
{
    const int tid = blockIdx.x * 256 + threadIdx.x;   // (b, d, n)
    const int n = tid & 15;
    const int d = (tid >> 4) % Dc;
    const int b = tid / (16 * Dc);
    float s = 0.f;
    for (int ch = 0; ch < NCH; ++ch) {
        const size_t idx = ((size_t)((b * NCH + ch) * Dc) + d) * 16 + n;
        I[idx] = s;
        s = fmaf(s, P[idx], S[idx]);
    }
}

// Phase C: elementwise; y = (yloc + sum_n I_n*exp(A_n*dcum)*C_n + D*x)*silu(z),
// fp32 in-place over yloc (P7 verbatim; x from bf16).
__global__ __launch_bounds__(256)
void scanC(const __hip_bfloat16* __restrict__ xsb, const float* __restrict__ zb,
           float* __restrict__ yloc, const float* __restrict__ dcum,
           const float* __restrict__ bc, const float* __restrict__ Abuf,
           const float* __restrict__ Ibuf, const float* __restrict__ Dvec)
{
    const int blk = blockIdx.x;
    const int dblk = blk % 3, ch = (blk / 3) % NCH, b = blk / (3 * NCH);
    const int d = dblk * 256 + threadIdx.x;
    const int t0 = ch * TCH;

    __shared__ float bcs[TCH * 32];
    {
        const float* src = bc + ((size_t)(b * Lc + t0)) * 32;
        *(float4*)&bcs[threadIdx.x * 8]     = *(const float4*)(src + threadIdx.x * 8);
        *(float4*)&bcs[threadIdx.x * 8 + 4] = *(const float4*)(src + threadIdx.x * 8 + 4);
    }
    __syncthreads();

    float A[16], In[16];
    #pragma unroll
    for (int q = 0; q < 4; ++q)
        *(float4*)&A[q * 4] = *(const float4*)(Abuf + d * 16 + q * 4);
    const size_t o = (((size_t)(b * NCH + ch) * Dc) + d) * 16;
    #pragma unroll
    for (int q = 0; q < 4; ++q)
        *(float4*)&In[q * 4] = *(const float4*)(Ibuf + o + q * 4);
    const float Dd = Dvec[d];

    const size_t base = ((size_t)(b * Lc + t0)) * Dc + d;
    for (int t = 0; t < TCH; ++t) {
        const float x  = __bfloat162float(xsb[base + (size_t)t * Dc]);
        const float z  = zb[base + (size_t)t * Dc];
        const float yl = yloc[base + (size_t)t * Dc];
        const float dc = dcum[base + (size_t)t * Dc];
        float acc = fmaf(Dd, x, yl);
        #pragma unroll
        for (int n = 0; n < 16; ++n)
            acc = fmaf(In[n] * __expf(dc * A[n]), bcs[t * 32 + 16 + n], acc);
        yloc[base + (size_t)t * Dc] = acc * siluf(z);
    }
}

extern "C" void kernel_launch(void* const* d_in, const int* in_sizes, int n_in,
                              void* d_out, int out_size, void* d_ws, size_t ws_size,
                              hipStream_t stream)
{
    const float* x      = (const float*)d_in[0];
    const float* state  = (const float*)d_in[1];
    const float* W_in   = (const float*)d_in[2];
    const float* conv_w = (const float*)d_in[3];
    const float* conv_b = (const float*)d_in[4];
    const float* W_x    = (const float*)d_in[5];
    const float* W_dt   = (const float*)d_in[6];
    const float* b_dt   = (const float*)d_in[7];
    const float* A_log  = (const float*)d_in[8];
    const float* Dvec   = (const float*)d_in[9];
    const float* W_out  = (const float*)d_in[10];
    float* out = (float*)d_out;

    // ---- workspace (245.94 MB <= 253.75 verified); no risky aliases ----
    char* wsb = (char*)d_ws;
    float* xc   = (float*)wsb;                       wsb += (size_t)M_TOT * Dc * 4;  // x-half; yloc in-place later
    float* zb   = (float*)wsb;                       wsb += (size_t)M_TOT * Dc * 4;  // z-half; ybf overwrites later
    float* dtb  = (float*)wsb;                       wsb += (size_t)M_TOT * Dc * 4;  // dtraw -> dcum
    float* bc   = (float*)wsb;                       wsb += (size_t)M_TOT * 32 * 4;
    float* Pb   = (float*)wsb;                       wsb += (size_t)Bc * NCH * Dc * Nc * 4;
    float* Sb   = (float*)wsb;                       wsb += (size_t)Bc * NCH * Dc * Nc * 4;
    float* Ib   = (float*)wsb;                       wsb += (size_t)Bc * NCH * Dc * Nc * 4;
    __hip_bfloat16* xb  = (__hip_bfloat16*)wsb;      wsb += (size_t)M_TOT * Dc * 2;  // bf16(x)
    __hip_bfloat16* xsb = (__hip_bfloat16*)wsb;      wsb += (size_t)M_TOT * Dc * 2;  // bf16(x_ssm)
    float* Abuf = (float*)wsb;                       wsb += (size_t)Dc * Nc * 4;
    __hip_bfloat16* WinT  = (__hip_bfloat16*)wsb;    wsb += (size_t)1536 * Kd * 2;
    __hip_bfloat16* WdtT  = (__hip_bfloat16*)wsb;    wsb += (size_t)768 * Kd * 2;
    __hip_bfloat16* WoutT = (__hip_bfloat16*)wsb;    wsb += (size_t)768 * Kd * 2;
    float* yloc = xc;                    // scanA writes after conv consumed xc
    __hip_bfloat16* ybf = (__hip_bfloat16*)zb;   // written after scanC consumed zb

    // ---- prep ----
    to_bf16_kernel<<<(M_TOT * Dc / 4 + 255) / 256, 256, 0, stream>>>(x, xb, M_TOT * Dc / 4);
    wtrans_kernel<<<(1536 * Kd + 255) / 256, 256, 0, stream>>>(W_in, WinT, 1536);
    wtrans_kernel<<<(768 * Kd + 255) / 256, 256, 0, stream>>>(W_dt, WdtT, 768);
    wtrans_kernel<<<(768 * Kd + 255) / 256, 256, 0, stream>>>(W_out, WoutT, 768);
    aprep_kernel<<<(Dc * Nc + 255) / 256, 256, 0, stream>>>(A_log, Abuf);

    // 1) in_proj, two N=768 dispatches (P7 structure, P5b core)
    gemm_bf16<<<dim3(Dc / 128, M_TOT / 128), 256, 0, stream>>>(xb, WinT, Dc, xc);
    gemm_bf16<<<dim3(Dc / 128, M_TOT / 128), 256, 0, stream>>>(
        xb, WinT + (size_t)768 * Kd, Dc, zb);
    // 2) conv + silu -> bf16 xsb
    conv_silu_kernel<<<(M_TOT * Dc + 255) / 256, 256, 0, stream>>>(xc, conv_w, conv_b, xsb);
    // 3) dtraw = xsb @ W_dt  (softplus+bias applied in scanA)
    gemm_bf16<<<dim3(Dc / 128, M_TOT / 128), 256, 0, stream>>>(xsb, WdtT, Dc, dtb);
    // 4) BC = xsb @ W_x
    bc_kernel<<<M_TOT / 8, 256, 0, stream>>>(xsb, W_x, bc);
    // 5) scan
    scanA<<<Bc * NCH * 3, 256, 0, stream>>>(dtb, xsb, bc, Abuf, b_dt, yloc, Pb, Sb);
    scanB<<<(Bc * Dc * Nc) / 256, 256, 0, stream>>>(Pb, Sb, Ib);
    scanC<<<Bc * NCH * 3, 256, 0, stream>>>(xsb, zb, yloc, dtb, bc, Abuf, Ib, Dvec);
    // 6) y -> bf16, out = y @ W_out
    to_bf16_kernel<<<(M_TOT * Dc / 4 + 255) / 256, 256, 0, stream>>>(yloc, ybf, M_TOT * Dc / 4);
    gemm_bf16<<<dim3(Dc / 128, M_TOT / 128), 256, 0, stream>>>(ybf, WoutT, Dc, out);
    // 7) state pass-through
    hipMemcpyAsync(out + (size_t)M_TOT * Dc, state,
                   (size_t)(Bc * Dc * Nc) * sizeof(float),
                   hipMemcpyDeviceToDevice, stream);
}

// Round 11
// 456.695 us; speedup vs baseline: 4.6762x; 1.0860x over previous
//
#include <hip/hip_runtime.h>
#include <hip/hip_bf16.h>
#include <cstdint>
#include <cstddef>

constexpr int Bc = 4, Lc = 4096, Dc = 768, Nc = 16;
constexpr int M_TOT = Bc * Lc;     // 16384
constexpr int NCH = 128;           // chunks per sequence
constexpr int TCH = Lc / NCH;      // 32
constexpr int Kd = 768;            // K of all GEMMs

typedef __attribute__((ext_vector_type(8))) short short8v;   // 8 bf16 (4 VGPRs)
typedef __attribute__((ext_vector_type(4))) float f32x4;     // MFMA acc

__device__ __forceinline__ float softplusf(float x) {
    return (x > 20.0f) ? x : log1pf(__expf(x));
}
__device__ __forceinline__ float siluf(float x) {
    return x / (1.0f + __expf(-x));
}

// ---------- bf16 MFMA GEMM (P5b-verified core) + global_load_lds staging ----------
// C[M,N] = A[M,768] @ WT[N,768]^T, single fp32 output.
// LDS linear [row][32] bf16; async staging: wave-uniform LDS base + lane*16B,
// lane l covers row seg*16 + l/4, k-elems (l&3)*8.. (matches linear layout).
__global__ __launch_bounds__(256)
void gemm_bf16(const __hip_bfloat16* __restrict__ Ab,
               const __hip_bfloat16* __restrict__ Wt,
               int N, float* __restrict__ out0)
{
    __shared__ __hip_bfloat16 Asm[128 * 32];
    __shared__ __hip_bfloat16 Bsm[128 * 32];
    const int tid = threadIdx.x;
    const int w = tid >> 6, lane = tid & 63;
    const int lr = lane & 15, lc = lane >> 4;
    const int row0 = blockIdx.y * 128, col0 = blockIdx.x * 128;
    const int wrow = (w >> 1) * 64, wcol = (w & 1) * 64;

    const int srow = lane >> 2;          // 0..15 within 16-row segment
    const int scol = (lane & 3) * 8;     // k offset (8 bf16 = 16 B)

    f32x4 acc[4][4] = {};

    const int KT = Kd / 32;
    for (int kt = 0; kt < KT; ++kt) {
        if (kt) __syncthreads();         // prev iter readers done
        #pragma unroll
        for (int i = 0; i < 2; ++i) {
            const int seg = w * 2 + i;   // 0..7, 16 rows each
            const __hip_bfloat16* asrc =
                Ab + (size_t)(row0 + seg * 16 + srow) * Kd + kt * 32 + scol;
            const __hip_bfloat16* bsrc =
                Wt + (size_t)(col0 + seg * 16 + srow) * Kd + kt * 32 + scol;
            __builtin_amdgcn_global_load_lds(
                (const __attribute__((address_space(1))) void*)asrc,
                (__attribute__((address_space(3))) void*)(Asm + seg * 512), 16, 0, 0);
            __builtin_amdgcn_global_load_lds(
                (const __attribute__((address_space(1))) void*)bsrc,
                (__attribute__((address_space(3))) void*)(Bsm + seg * 512), 16, 0, 0);
        }
        asm volatile("s_waitcnt vmcnt(0)" ::: "memory");
        __syncthreads();

        short8v a[4], b[4];
        #pragma unroll
        for (int m = 0; m < 4; ++m)
            a[m] = *(const short8v*)((char*)Asm + (wrow + m * 16 + lr) * 64 + lc * 16);
        #pragma unroll
        for (int nf = 0; nf < 4; ++nf)
            b[nf] = *(const short8v*)((char*)Bsm + (wcol + nf * 16 + lr) * 64 + lc * 16);
        #pragma unroll
        for (int m = 0; m < 4; ++m)
            #pragma unroll
            for (int nf = 0; nf < 4; ++nf)
                acc[m][nf] = __builtin_amdgcn_mfma_f32_16x16x32_bf16(
                    a[m], b[nf], acc[m][nf], 0, 0, 0);
    }

    // epilogue: C/D frag map col=lane&15, row=(lane>>4)*4+reg [HW-verified]
    #pragma unroll
    for (int m = 0; m < 4; ++m)
        #pragma unroll
        for (int nf = 0; nf < 4; ++nf)
            #pragma unroll
            for (int j = 0; j < 4; ++j) {
                const int rg = row0 + wrow + m * 16 + lc * 4 + j;
                const int cg = col0 + wcol + nf * 16 + lr;
                out0[(size_t)rg * N + cg] = acc[m][nf][j];
            }
}

// ---------------- prep kernels (HW-verified) ----------------
__global__ __launch_bounds__(256)
void to_bf16_kernel(const float* __restrict__ src, __hip_bfloat16* __restrict__ dst, int n4)
{
    const int i = blockIdx.x * 256 + threadIdx.x;
    if (i >= n4) return;
    const float4 v = ((const float4*)src)[i];
    dst[i * 4 + 0] = __float2bfloat16(v.x);
    dst[i * 4 + 1] = __float2bfloat16(v.y);
    dst[i * 4 + 2] = __float2bfloat16(v.z);
    dst[i * 4 + 3] = __float2bfloat16(v.w);
}

__global__ __launch_bounds__(256)
void wtrans_kernel(const float* __restrict__ src, __hip_bfloat16* __restrict__ dst, int N)
{
    const int idx = blockIdx.x * 256 + threadIdx.x;
    if (idx >= N * Kd) return;
    const int n = idx / Kd, k = idx % Kd;
    dst[idx] = __float2bfloat16(src[(size_t)k * N + n]);
}

__global__ __launch_bounds__(256)
void aprep_kernel(const float* __restrict__ A_log, float* __restrict__ Abuf)
{
    const int i = blockIdx.x * 256 + threadIdx.x;
    if (i < Dc * Nc) Abuf[i] = -expf(A_log[i]);
}

// ---------------- conv + silu: xc fp32 -> bf16 xsb ----------------
__global__ __launch_bounds__(256)
void conv_silu_kernel(const float* __restrict__ xc, const float* __restrict__ cw,
                      const float* __restrict__ cb, __hip_bfloat16* __restrict__ xsb)
{
    const int idx = blockIdx.x * 256 + threadIdx.x;
    if (idx >= M_TOT * Dc) return;
    const int d = idx % Dc;
    const int t = (idx / Dc) & (Lc - 1);
    float acc = cb[d];
    #pragma unroll
    for (int k = 0; k < 4; ++k) {
        const int tt = t + k - 3;
        if (tt >= 0)
            acc = fmaf(xc[(size_t)idx + (ptrdiff_t)(k - 3) * Dc], cw[d * 4 + k], acc);
    }
    xsb[idx] = __float2bfloat16(siluf(acc));
}

// ---------------- BC = x_ssm @ W_x (772-stride LDS: bank-conflict-free) ----------------
__global__ __launch_bounds__(256)
void bc_kernel(const __hip_bfloat16* __restrict__ xsb, const float* __restrict__ Wx,
               float* __restrict__ BC)
{
    __shared__ float xsh[8][772];   // stride 772: rr*772 % 32 = rr*4, distinct banks
    const int r0 = blockIdx.x * 8;
    const int tid = threadIdx.x;
    for (int i = tid; i < 1536; i += 256) {
        const int rr = i / 192, c4 = (i % 192) * 4;
        const __hip_bfloat16* src = xsb + (size_t)(r0 + rr) * Dc + c4;
        xsh[rr][c4 + 0] = __bfloat162float(src[0]);
        xsh[rr][c4 + 1] = __bfloat162float(src[1]);
        xsh[rr][c4 + 2] = __bfloat162float(src[2]);
        xsh[rr][c4 + 3] = __bfloat162float(src[3]);
    }
    __syncthreads();
    const int c = tid & 31, rr = tid >> 5;
    float acc = 0.f;
    for (int k = 0; k < Kd; ++k)
        acc = fmaf(xsh[rr][k], Wx[k * 32 + c], acc);
    BC[(size_t)(r0 + rr) * 32 + c] = acc;
}

// ---------------- chunked scan, closed-form carry ----------------
// Phase A: thread owns (b,ch,d), 16 n in regs. dt = softplus(dtraw + b_dt[d]).
// Emits yloc, dcum (in-place), end-of-chunk S and scalar dcend (P derived later).
__global__ __launch_bounds__(256)
void scanA(float* __restrict__ dtb, const __hip_bfloat16* __restrict__ xsb,
           const float* __restrict__ bc, const float* __restrict__ Abuf,
           const float* __restrict__ bdt, float* __restrict__ yloc,
           float* __restrict__ S, float* __restrict__ dcend)
{
    const int blk = blockIdx.x;
    const int dblk = blk % 3, ch = (blk / 3) % NCH, b = blk / (3 * NCH);
    const int d = dblk * 256 + threadIdx.x;
    const int t0 = ch * TCH;

    __shared__ float bcs[TCH * 32];   // 4 KB (B|C) chunk tile
    {
        const int row = threadIdx.x >> 3, c4 = (threadIdx.x & 7) * 4;
        *(float4*)&bcs[row * 32 + c4] =
            *(const float4*)(bc + ((size_t)(b * Lc + t0) + row) * 32 + c4);
    }
    __syncthreads();

    float A[16];
    #pragma unroll
    for (int q = 0; q < 4; ++q)
        *(float4*)&A[q * 4] = *(const float4*)(Abuf + d * 16 + q * 4);
    const float bd = bdt[d];

    float s[16];
    #pragma unroll
    for (int n = 0; n < 16; ++n) s[n] = 0.f;

    const size_t base = ((size_t)(b * Lc + t0)) * Dc + d;
    float dc = 0.f;
    for (int t = 0; t < TCH; ++t) {
        const float dt = softplusf(dtb[base + (size_t)t * Dc] + bd);
        const float x  = __bfloat162float(xsb[base + (size_t)t * Dc]);
        dc += dt;
        float yl = 0.f;
        #pragma unroll
        for (int n = 0; n < 16; ++n) {
            const float dA = __expf(dt * A[n]);
            s[n] = fmaf(s[n], dA, bcs[t * 32 + n] * x);
            yl = fmaf(s[n], bcs[t * 32 + 16 + n], yl);
        }
        yloc[base + (size_t)t * Dc] = yl;
        dtb[base + (size_t)t * Dc] = dc;   // dcum over dtraw (consumed)
    }
    const size_t g = (size_t)(b * NCH + ch) * Dc + d;
    #pragma unroll
    for (int n = 0; n < 16; ++n) S[g * 16 + n] = s[n];
    dcend[g] = dc;
}

// Phase B: combine across chunks; S transformed IN PLACE into I (init states).
// P reconstructed as exp(dcend * A_n). Read-before-write per thread (verified r8).
__global__ __launch_bounds__(256)
void scanB(float* __restrict__ S_io, const float* __restrict__ dcend,
           const float* __restrict__ Abuf)
{
    const int tid = blockIdx.x * 256 + threadIdx.x;   // (b, d, n)
    const int n = tid & 15;
    const int d = (tid >> 4) % Dc;
    const int b = tid / (16 * Dc);
    const float An = Abuf[d * 16 + n];
    float s = 0.f;
    for (int ch = 0; ch < NCH; ++ch) {
        const size_t g = (size_t)(b * NCH + ch) * Dc + d;
        const float sv = S_io[g * 16 + n];
        const float p  = __expf(dcend[g] * An);
        S_io[g * 16 + n] = s;              // becomes I
        s = fmaf(s, p, sv);
    }
}

// Phase C: elementwise; y = (yloc + sum_n I_n*exp(A_n*dcum)*C_n + D*x)*silu(z) -> bf16.
__global__ __launch_bounds__(256)
void scanC(const __hip_bfloat16* __restrict__ xsb, const float* __restrict__ zb,
           const float* __restrict__ yloc, const float* __restrict__ dcum,
           const float* __restrict__ bc, const float* __restrict__ Abuf,
           const float* __restrict__ Ibuf, const float* __restrict__ Dvec,
           __hip_bfloat16* __restrict__ ybf)
{
    const int blk = blockIdx.x;
    const int dblk = blk % 3, ch = (blk / 3) % NCH, b = blk / (3 * NCH);
    const int d = dblk * 256 + threadIdx.x;
    const int t0 = ch * TCH;

    __shared__ float bcs[TCH * 32];
    {
        const int row = threadIdx.x >> 3, c4 = (threadIdx.x & 7) * 4;
        *(float4*)&bcs[row * 32 + c4] =
            *(const float4*)(bc + ((size_t)(b * Lc + t0) + row) * 32 + c4);
    }
    __syncthreads();

    float A[16], In[16];
    #pragma unroll
    for (int q = 0; q < 4; ++q)
        *(float4*)&A[q * 4] = *(const float4*)(Abuf + d * 16 + q * 4);
    const size_t g = (size_t)(b * NCH + ch) * Dc + d;
    #pragma unroll
    for (int q = 0; q < 4; ++q)
        *(float4*)&In[q * 4] = *(const float4*)(Ibuf + g * 16 + q * 4);
    const float Dd = Dvec[d];

    const size_t base = ((size_t)(b * Lc + t0)) * Dc + d;
    for (int t = 0; t < TCH; ++t) {
        const float x  = __bfloat162float(xsb[base + (size_t)t * Dc]);
        const float z  = zb[base + (size_t)t * Dc];
        const float yl = yloc[base + (size_t)t * Dc];
        const float dc = dcum[base + (size_t)t * Dc];
        float acc = fmaf(Dd, x, yl);
        #pragma unroll
        for (int n = 0; n < 16; ++n)
            acc = fmaf(In[n] * __expf(dc * A[n]), bcs[t * 32 + 16 + n], acc);
        ybf[base + (size_t)t * Dc] = __float2bfloat16(acc * siluf(z));
    }
}

extern "C" void kernel_launch(void* const* d_in, const int* in_sizes, int n_in,
                              void* d_out, int out_size, void* d_ws, size_t ws_size,
                              hipStream_t stream)
{
    const float* x      = (const float*)d_in[0];
    const float* state  = (const float*)d_in[1];
    const float* W_in   = (const float*)d_in[2];
    const float* conv_w = (const float*)d_in[3];
    const float* conv_b = (const float*)d_in[4];
    const float* W_x    = (const float*)d_in[5];
    const float* W_dt   = (const float*)d_in[6];
    const float* b_dt   = (const float*)d_in[7];
    const float* A_log  = (const float*)d_in[8];
    const float* Dvec   = (const float*)d_in[9];
    const float* W_out  = (const float*)d_in[10];
    float* out = (float*)d_out;

    // ---- workspace (234.9 MB <= 253.75 verified) ----
    char* wsb = (char*)d_ws;
    float* xc    = (float*)wsb;                      wsb += (size_t)M_TOT * Dc * 4;  // x-half; yloc in-place after conv
    float* zb    = (float*)wsb;                      wsb += (size_t)M_TOT * Dc * 4;  // z-half
    float* dtb   = (float*)wsb;                      wsb += (size_t)M_TOT * Dc * 4;  // dtraw -> dcum
    float* bc    = (float*)wsb;                      wsb += (size_t)M_TOT * 32 * 4;
    float* Sb    = (float*)wsb;                      wsb += (size_t)Bc * NCH * Dc * Nc * 4;  // S -> I in place
    float* dcend = (float*)wsb;                      wsb += (size_t)Bc * NCH * Dc * 4;
    __hip_bfloat16* xb  = (__hip_bfloat16*)wsb;      wsb += (size_t)M_TOT * Dc * 2;  // bf16(x); ybf aliases
    __hip_bfloat16* xsb = (__hip_bfloat16*)wsb;      wsb += (size_t)M_TOT * Dc * 2;  // bf16(x_ssm)
    float* Abuf = (float*)wsb;                       wsb += (size_t)Dc * Nc * 4;
    __hip_bfloat16* WinT  = (__hip_bfloat16*)wsb;    wsb += (size_t)1536 * Kd * 2;
    __hip_bfloat16* WdtT  = (__hip_bfloat16*)wsb;    wsb += (size_t)768 * Kd * 2;
    __hip_bfloat16* WoutT = (__hip_bfloat16*)wsb;    wsb += (size_t)768 * Kd * 2;
    float* yloc = xc;                           // written after conv consumed xc
    float* Ib = Sb;                             // scanB in-place (verified pattern)
    __hip_bfloat16* ybf = xb;                   // xb dead after in_proj GEMMs

    // ---- prep ----
    to_bf16_kernel<<<(M_TOT * Dc / 4 + 255) / 256, 256, 0, stream>>>(x, xb, M_TOT * Dc / 4);
    wtrans_kernel<<<(1536 * Kd + 255) / 256, 256, 0, stream>>>(W_in, WinT, 1536);
    wtrans_kernel<<<(768 * Kd + 255) / 256, 256, 0, stream>>>(W_dt, WdtT, 768);
    wtrans_kernel<<<(768 * Kd + 255) / 256, 256, 0, stream>>>(W_out, WoutT, 768);
    aprep_kernel<<<(Dc * Nc + 255) / 256, 256, 0, stream>>>(A_log, Abuf);

    // 1) in_proj, two N=768 dispatches
    gemm_bf16<<<dim3(Dc / 128, M_TOT / 128), 256, 0, stream>>>(xb, WinT, Dc, xc);
    gemm_bf16<<<dim3(Dc / 128, M_TOT / 128), 256, 0, stream>>>(
        xb, WinT + (size_t)768 * Kd, Dc, zb);
    // 2) conv + silu -> bf16 xsb
    conv_silu_kernel<<<(M_TOT * Dc + 255) / 256, 256, 0, stream>>>(xc, conv_w, conv_b, xsb);
    // 3) dtraw = xsb @ W_dt  (softplus+bias in scanA)
    gemm_bf16<<<dim3(Dc / 128, M_TOT / 128), 256, 0, stream>>>(xsb, WdtT, Dc, dtb);
    // 4) BC = xsb @ W_x
    bc_kernel<<<M_TOT / 8, 256, 0, stream>>>(xsb, W_x, bc);
    // 5) scan
    scanA<<<Bc * NCH * 3, 256, 0, stream>>>(dtb, xsb, bc, Abuf, b_dt, yloc, Sb, dcend);
    scanB<<<(Bc * Dc * Nc) / 256, 256, 0, stream>>>(Sb, dcend, Abuf);
    scanC<<<Bc * NCH * 3, 256, 0, stream>>>(xsb, zb, yloc, dtb, bc, Abuf, Ib, Dvec, ybf);
    // 6) out = y @ W_out
    gemm_bf16<<<dim3(Dc / 128, M_TOT / 128), 256, 0, stream>>>(ybf, WoutT, Dc, out);
    // 7) state pass-through
    hipMemcpyAsync(out + (size_t)M_TOT * Dc, state,
                   (size_t)(Bc * Dc * Nc) * sizeof(float),
                   hipMemcpyDeviceToDevice, stream);
}

// Round 12
// 433.082 us; speedup vs baseline: 4.9312x; 1.0545x over previous
//
#include <hip/hip_runtime.h>
#include <hip/hip_bf16.h>
#include <cstdint>
#include <cstddef>

constexpr int Bc = 4, Lc = 4096, Dc = 768, Nc = 16;
constexpr int M_TOT = Bc * Lc;     // 16384
constexpr int NCH = 128;           // chunks per sequence
constexpr int TCH = Lc / NCH;      // 32
constexpr int Kd = 768;            // K of all GEMMs

typedef __attribute__((ext_vector_type(8))) short short8v;   // 8 bf16 (4 VGPRs)
typedef __attribute__((ext_vector_type(4))) float f32x4;     // MFMA acc

// fast softplus: |err| <= ~1e-7 absolute (1+e^x rounds to 1 only when e^x < ulp)
__device__ __forceinline__ float softplusf(float x) {
    return (x > 20.0f) ? x : __logf(1.0f + __expf(x));
}
__device__ __forceinline__ float siluf(float x) {
    return x / (1.0f + __expf(-x));
}

// ---------- bf16 MFMA GEMM (round-11 HW-verified, verbatim) ----------
__global__ __launch_bounds__(256)
void gemm_bf16(const __hip_bfloat16* __restrict__ Ab,
               const __hip_bfloat16* __restrict__ Wt,
               int N, float* __restrict__ out0)
{
    __shared__ __hip_bfloat16 Asm[128 * 32];
    __shared__ __hip_bfloat16 Bsm[128 * 32];
    const int tid = threadIdx.x;
    const int w = tid >> 6, lane = tid & 63;
    const int lr = lane & 15, lc = lane >> 4;
    const int row0 = blockIdx.y * 128, col0 = blockIdx.x * 128;
    const int wrow = (w >> 1) * 64, wcol = (w & 1) * 64;

    const int srow = lane >> 2;          // 0..15 within 16-row segment
    const int scol = (lane & 3) * 8;     // k offset (8 bf16 = 16 B)

    f32x4 acc[4][4] = {};

    const int KT = Kd / 32;
    for (int kt = 0; kt < KT; ++kt) {
        if (kt) __syncthreads();
        #pragma unroll
        for (int i = 0; i < 2; ++i) {
            const int seg = w * 2 + i;
            const __hip_bfloat16* asrc =
                Ab + (size_t)(row0 + seg * 16 + srow) * Kd + kt * 32 + scol;
            const __hip_bfloat16* bsrc =
                Wt + (size_t)(col0 + seg * 16 + srow) * Kd + kt * 32 + scol;
            __builtin_amdgcn_global_load_lds(
                (const __attribute__((address_space(1))) void*)asrc,
                (__attribute__((address_space(3))) void*)(Asm + seg * 512), 16, 0, 0);
            __builtin_amdgcn_global_load_lds(
                (const __attribute__((address_space(1))) void*)bsrc,
                (__attribute__((address_space(3))) void*)(Bsm + seg * 512), 16, 0, 0);
        }
        asm volatile("s_waitcnt vmcnt(0)" ::: "memory");
        __syncthreads();

        short8v a[4], b[4];
        #pragma unroll
        for (int m = 0; m < 4; ++m)
            a[m] = *(const short8v*)((char*)Asm + (wrow + m * 16 + lr) * 64 + lc * 16);
        #pragma unroll
        for (int nf = 0; nf < 4; ++nf)
            b[nf] = *(const short8v*)((char*)Bsm + (wcol + nf * 16 + lr) * 64 + lc * 16);
        #pragma unroll
        for (int m = 0; m < 4; ++m)
            #pragma unroll
            for (int nf = 0; nf < 4; ++nf)
                acc[m][nf] = __builtin_amdgcn_mfma_f32_16x16x32_bf16(
                    a[m], b[nf], acc[m][nf], 0, 0, 0);
    }

    #pragma unroll
    for (int m = 0; m < 4; ++m)
        #pragma unroll
        for (int nf = 0; nf < 4; ++nf)
            #pragma unroll
            for (int j = 0; j < 4; ++j) {
                const int rg = row0 + wrow + m * 16 + lc * 4 + j;
                const int cg = col0 + wcol + nf * 16 + lr;
                out0[(size_t)rg * N + cg] = acc[m][nf][j];
            }
}

// ---------------- prep kernels (HW-verified) ----------------
__global__ __launch_bounds__(256)
void to_bf16_kernel(const float* __restrict__ src, __hip_bfloat16* __restrict__ dst, int n4)
{
    const int i = blockIdx.x * 256 + threadIdx.x;
    if (i >= n4) return;
    const float4 v = ((const float4*)src)[i];
    dst[i * 4 + 0] = __float2bfloat16(v.x);
    dst[i * 4 + 1] = __float2bfloat16(v.y);
    dst[i * 4 + 2] = __float2bfloat16(v.z);
    dst[i * 4 + 3] = __float2bfloat16(v.w);
}

__global__ __launch_bounds__(256)
void wtrans_kernel(const float* __restrict__ src, __hip_bfloat16* __restrict__ dst, int N)
{
    const int idx = blockIdx.x * 256 + threadIdx.x;
    if (idx >= N * Kd) return;
    const int n = idx / Kd, k = idx % Kd;
    dst[idx] = __float2bfloat16(src[(size_t)k * N + n]);
}

__global__ __launch_bounds__(256)
void aprep_kernel(const float* __restrict__ A_log, float* __restrict__ Abuf)
{
    const int i = blockIdx.x * 256 + threadIdx.x;
    if (i < Dc * Nc) Abuf[i] = -expf(A_log[i]);
}

// ---------------- conv + silu: xc fp32 -> bf16 xsb ----------------
__global__ __launch_bounds__(256)
void conv_silu_kernel(const float* __restrict__ xc, const float* __restrict__ cw,
                      const float* __restrict__ cb, __hip_bfloat16* __restrict__ xsb)
{
    const int idx = blockIdx.x * 256 + threadIdx.x;
    if (idx >= M_TOT * Dc) return;
    const int d = idx % Dc;
    const int t = (idx / Dc) & (Lc - 1);
    float acc = cb[d];
    #pragma unroll
    for (int k = 0; k < 4; ++k) {
        const int tt = t + k - 3;
        if (tt >= 0)
            acc = fmaf(xc[(size_t)idx + (ptrdiff_t)(k - 3) * Dc], cw[d * 4 + k], acc);
    }
    xsb[idx] = __float2bfloat16(siluf(acc));
}

// ---------------- BC = x_ssm @ W_x (772-stride LDS, verified) ----------------
__global__ __launch_bounds__(256)
void bc_kernel(const __hip_bfloat16* __restrict__ xsb, const float* __restrict__ Wx,
               float* __restrict__ BC)
{
    __shared__ float xsh[8][772];
    const int r0 = blockIdx.x * 8;
    const int tid = threadIdx.x;
    for (int i = tid; i < 1536; i += 256) {
        const int rr = i / 192, c4 = (i % 192) * 4;
        const __hip_bfloat16* src = xsb + (size_t)(r0 + rr) * Dc + c4;
        xsh[rr][c4 + 0] = __bfloat162float(src[0]);
        xsh[rr][c4 + 1] = __bfloat162float(src[1]);
        xsh[rr][c4 + 2] = __bfloat162float(src[2]);
        xsh[rr][c4 + 3] = __bfloat162float(src[3]);
    }
    __syncthreads();
    const int c = tid & 31, rr = tid >> 5;
    float acc = 0.f;
    for (int k = 0; k < Kd; ++k)
        acc = fmaf(xsh[rr][k], Wx[k * 32 + c], acc);
    BC[(size_t)(r0 + rr) * 32 + c] = acc;
}

// ---------------- chunked scan ----------------
// Phase A (lite): recurrence only; emit end-of-chunk S and dcend. No per-t stores.
__global__ __launch_bounds__(256)
void scanA(const float* __restrict__ dtb, const __hip_bfloat16* __restrict__ xsb,
           const float* __restrict__ bc, const float* __restrict__ Abuf,
           const float* __restrict__ bdt,
           float* __restrict__ S, float* __restrict__ dcend)
{
    const int blk = blockIdx.x;
    const int dblk = blk % 3, ch = (blk / 3) % NCH, b = blk / (3 * NCH);
    const int d = dblk * 256 + threadIdx.x;
    const int t0 = ch * TCH;

    __shared__ float bcs[TCH * 32];   // 4 KB (B|C) chunk tile
    {
        const int row = threadIdx.x >> 3, c4 = (threadIdx.x & 7) * 4;
        *(float4*)&bcs[row * 32 + c4] =
            *(const float4*)(bc + ((size_t)(b * Lc + t0) + row) * 32 + c4);
    }
    __syncthreads();

    float A[16];
    #pragma unroll
    for (int q = 0; q < 4; ++q)
        *(float4*)&A[q * 4] = *(const float4*)(Abuf + d * 16 + q * 4);
    const float bd = bdt[d];

    float s[16];
    #pragma unroll
    for (int n = 0; n < 16; ++n) s[n] = 0.f;

    const size_t base = ((size_t)(b * Lc + t0)) * Dc + d;
    float dc = 0.f;
    for (int t = 0; t < TCH; ++t) {
        const float dt = softplusf(dtb[base + (size_t)t * Dc] + bd);
        const float x  = __bfloat162float(xsb[base + (size_t)t * Dc]);
        dc += dt;
        #pragma unroll
        for (int n = 0; n < 16; ++n) {
            const float dA = __expf(dt * A[n]);
            s[n] = fmaf(s[n], dA, bcs[t * 32 + n] * x);
        }
    }
    const size_t g = (size_t)(b * NCH + ch) * Dc + d;
    #pragma unroll
    for (int n = 0; n < 16; ++n) S[g * 16 + n] = s[n];
    dcend[g] = dc;
}

// Phase B: combine across chunks; S -> I in place (verified r10/r11 pattern).
__global__ __launch_bounds__(256)
void scanB(float* __restrict__ S_io, const float* __restrict__ dcend,
           const float* __restrict__ Abuf)
{
    const int tid = blockIdx.x * 256 + threadIdx.x;   // (b, d, n)
    const int n = tid & 15;
    const int d = (tid >> 4) % Dc;
    const int b = tid / (16 * Dc);
    const float An = Abuf[d * 16 + n];
    float s = 0.f;
    for (int ch = 0; ch < NCH; ++ch) {
        const size_t g = (size_t)(b * NCH + ch) * Dc + d;
        const float sv = S_io[g * 16 + n];
        const float p  = __expf(dcend[g] * An);
        S_io[g * 16 + n] = s;              // becomes I
        s = fmaf(s, p, sv);
    }
}

// Phase C (full): re-run recurrence from true init I; fused y=<s,C>+D*x, gate -> bf16.
__global__ __launch_bounds__(256)
void scanC(const float* __restrict__ dtb, const __hip_bfloat16* __restrict__ xsb,
           const float* __restrict__ zb, const float* __restrict__ bc,
           const float* __restrict__ Abuf, const float* __restrict__ bdt,
           const float* __restrict__ Ibuf, const float* __restrict__ Dvec,
           __hip_bfloat16* __restrict__ ybf)
{
    const int blk = blockIdx.x;
    const int dblk = blk % 3, ch = (blk / 3) % NCH, b = blk / (3 * NCH);
    const int d = dblk * 256 + threadIdx.x;
    const int t0 = ch * TCH;

    __shared__ float bcs[TCH * 32];
    {
        const int row = threadIdx.x >> 3, c4 = (threadIdx.x & 7) * 4;
        *(float4*)&bcs[row * 32 + c4] =
            *(const float4*)(bc + ((size_t)(b * Lc + t0) + row) * 32 + c4);
    }
    __syncthreads();

    float A[16], s[16];
    #pragma unroll
    for (int q = 0; q < 4; ++q)
        *(float4*)&A[q * 4] = *(const float4*)(Abuf + d * 16 + q * 4);
    const size_t g = (size_t)(b * NCH + ch) * Dc + d;
    #pragma unroll
    for (int q = 0; q < 4; ++q)
        *(float4*)&s[q * 4] = *(const float4*)(Ibuf + g * 16 + q * 4);
    const float bd = bdt[d];
    const float Dd = Dvec[d];

    const size_t base = ((size_t)(b * Lc + t0)) * Dc + d;
    for (int t = 0; t < TCH; ++t) {
        const float dt = softplusf(dtb[base + (size_t)t * Dc] + bd);
        const float x  = __bfloat162float(xsb[base + (size_t)t * Dc]);
        const float z  = zb[base + (size_t)t * Dc];
        float yl = fmaf(Dd, x, 0.f);
        #pragma unroll
        for (int n = 0; n < 16; ++n) {
            const float dA = __expf(dt * A[n]);
            s[n] = fmaf(s[n], dA, bcs[t * 32 + n] * x);
            yl = fmaf(s[n], bcs[t * 32 + 16 + n], yl);
        }
        ybf[base + (size_t)t * Dc] = __float2bfloat16(yl * siluf(z));
    }
}

extern "C" void kernel_launch(void* const* d_in, const int* in_sizes, int n_in,
                              void* d_out, int out_size, void* d_ws, size_t ws_size,
                              hipStream_t stream)
{
    const float* x      = (const float*)d_in[0];
    const float* state  = (const float*)d_in[1];
    const float* W_in   = (const float*)d_in[2];
    const float* conv_w = (const float*)d_in[3];
    const float* conv_b = (const float*)d_in[4];
    const float* W_x    = (const float*)d_in[5];
    const float* W_dt   = (const float*)d_in[6];
    const float* b_dt   = (const float*)d_in[7];
    const float* A_log  = (const float*)d_in[8];
    const float* Dvec   = (const float*)d_in[9];
    const float* W_out  = (const float*)d_in[10];
    float* out = (float*)d_out;

    // ---- workspace (234.9 MB, identical size to round-11-verified layout) ----
    char* wsb = (char*)d_ws;
    float* xc    = (float*)wsb;                      wsb += (size_t)M_TOT * Dc * 4;  // conv input; ybf reuses after conv
    float* zb    = (float*)wsb;                      wsb += (size_t)M_TOT * Dc * 4;  // z-half
    float* dtb   = (float*)wsb;                      wsb += (size_t)M_TOT * Dc * 4;  // dtraw (read-only in scans)
    float* bc    = (float*)wsb;                      wsb += (size_t)M_TOT * 32 * 4;
    float* Sb    = (float*)wsb;                      wsb += (size_t)Bc * NCH * Dc * Nc * 4;  // S -> I in place
    float* dcend = (float*)wsb;                      wsb += (size_t)Bc * NCH * Dc * 4;
    __hip_bfloat16* xb  = (__hip_bfloat16*)wsb;      wsb += (size_t)M_TOT * Dc * 2;  // bf16(x)
    __hip_bfloat16* xsb = (__hip_bfloat16*)wsb;      wsb += (size_t)M_TOT * Dc * 2;  // bf16(x_ssm)
    float* Abuf = (float*)wsb;                       wsb += (size_t)Dc * Nc * 4;
    __hip_bfloat16* WinT  = (__hip_bfloat16*)wsb;    wsb += (size_t)1536 * Kd * 2;
    __hip_bfloat16* WdtT  = (__hip_bfloat16*)wsb;    wsb += (size_t)768 * Kd * 2;
    __hip_bfloat16* WoutT = (__hip_bfloat16*)wsb;    wsb += (size_t)768 * Kd * 2;
    float* Ib = Sb;                               // scanB in-place (verified)
    __hip_bfloat16* ybf = (__hip_bfloat16*)xc;    // xc dead after conv

    // ---- prep ----
    to_bf16_kernel<<<(M_TOT * Dc / 4 + 255) / 256, 256, 0, stream>>>(x, xb, M_TOT * Dc / 4);
    wtrans_kernel<<<(1536 * Kd + 255) / 256, 256, 0, stream>>>(W_in, WinT, 1536);
    wtrans_kernel<<<(768 * Kd + 255) / 256, 256, 0, stream>>>(W_dt, WdtT, 768);
    wtrans_kernel<<<(768 * Kd + 255) / 256, 256, 0, stream>>>(W_out, WoutT, 768);
    aprep_kernel<<<(Dc * Nc + 255) / 256, 256, 0, stream>>>(A_log, Abuf);

    // 1) in_proj, two N=768 dispatches (verified config)
    gemm_bf16<<<dim3(Dc / 128, M_TOT / 128), 256, 0, stream>>>(xb, WinT, Dc, xc);
    gemm_bf16<<<dim3(Dc / 128, M_TOT / 128), 256, 0, stream>>>(
        xb, WinT + (size_t)768 * Kd, Dc, zb);
    // 2) conv + silu -> bf16 xsb
    conv_silu_kernel<<<(M_TOT * Dc + 255) / 256, 256, 0, stream>>>(xc, conv_w, conv_b, xsb);
    // 3) dtraw = xsb @ W_dt  (softplus+bias in scan kernels)
    gemm_bf16<<<dim3(Dc / 128, M_TOT / 128), 256, 0, stream>>>(xsb, WdtT, Dc, dtb);
    // 4) BC = xsb @ W_x
    bc_kernel<<<M_TOT / 8, 256, 0, stream>>>(xsb, W_x, bc);
    // 5) scan: A-lite -> B -> C-full
    scanA<<<Bc * NCH * 3, 256, 0, stream>>>(dtb, xsb, bc, Abuf, b_dt, Sb, dcend);
    scanB<<<(Bc * Dc * Nc) / 256, 256, 0, stream>>>(Sb, dcend, Abuf);
    scanC<<<Bc * NCH * 3, 256, 0, stream>>>(dtb, xsb, zb, bc, Abuf, b_dt, Ib, Dvec, ybf);
    // 6) out = y @ W_out
    gemm_bf16<<<dim3(Dc / 128, M_TOT / 128), 256, 0, stream>>>(ybf, WoutT, Dc, out);
    // 7) state pass-through
    hipMemcpyAsync(out + (size_t)M_TOT * Dc, state,
                   (size_t)(Bc * Dc * Nc) * sizeof(float),
                   hipMemcpyDeviceToDevice, stream);
}

// Round 13
// 384.107 us; speedup vs baseline: 5.5599x; 1.1275x over previous
//
#include <hip/hip_runtime.h>
#include <hip/hip_bf16.h>
#include <cstdint>
#include <cstddef>

constexpr int Bc = 4, Lc = 4096, Dc = 768, Nc = 16;
constexpr int M_TOT = Bc * Lc;     // 16384
constexpr int NCH = 128;           // chunks per sequence
constexpr int TCH = Lc / NCH;      // 32
constexpr int Kd = 768;            // K of all GEMMs

typedef __attribute__((ext_vector_type(8))) short short8v;   // 8 bf16 (4 VGPRs)
typedef __attribute__((ext_vector_type(4))) float f32x4;     // MFMA acc

// fast softplus: |err| <= ~1e-7 absolute
__device__ __forceinline__ float softplusf(float x) {
    return (x > 20.0f) ? x : __logf(1.0f + __expf(x));
}
__device__ __forceinline__ float siluf(float x) {
    return x / (1.0f + __expf(-x));
}

// ---------- bf16 MFMA GEMM (round-11 HW-verified, verbatim) ----------
__global__ __launch_bounds__(256)
void gemm_bf16(const __hip_bfloat16* __restrict__ Ab,
               const __hip_bfloat16* __restrict__ Wt,
               int N, float* __restrict__ out0)
{
    __shared__ __hip_bfloat16 Asm[128 * 32];
    __shared__ __hip_bfloat16 Bsm[128 * 32];
    const int tid = threadIdx.x;
    const int w = tid >> 6, lane = tid & 63;
    const int lr = lane & 15, lc = lane >> 4;
    const int row0 = blockIdx.y * 128, col0 = blockIdx.x * 128;
    const int wrow = (w >> 1) * 64, wcol = (w & 1) * 64;

    const int srow = lane >> 2;
    const int scol = (lane & 3) * 8;

    f32x4 acc[4][4] = {};

    const int KT = Kd / 32;
    for (int kt = 0; kt < KT; ++kt) {
        if (kt) __syncthreads();
        #pragma unroll
        for (int i = 0; i < 2; ++i) {
            const int seg = w * 2 + i;
            const __hip_bfloat16* asrc =
                Ab + (size_t)(row0 + seg * 16 + srow) * Kd + kt * 32 + scol;
            const __hip_bfloat16* bsrc =
                Wt + (size_t)(col0 + seg * 16 + srow) * Kd + kt * 32 + scol;
            __builtin_amdgcn_global_load_lds(
                (const __attribute__((address_space(1))) void*)asrc,
                (__attribute__((address_space(3))) void*)(Asm + seg * 512), 16, 0, 0);
            __builtin_amdgcn_global_load_lds(
                (const __attribute__((address_space(1))) void*)bsrc,
                (__attribute__((address_space(3))) void*)(Bsm + seg * 512), 16, 0, 0);
        }
        asm volatile("s_waitcnt vmcnt(0)" ::: "memory");
        __syncthreads();

        short8v a[4], b[4];
        #pragma unroll
        for (int m = 0; m < 4; ++m)
            a[m] = *(const short8v*)((char*)Asm + (wrow + m * 16 + lr) * 64 + lc * 16);
        #pragma unroll
        for (int nf = 0; nf < 4; ++nf)
            b[nf] = *(const short8v*)((char*)Bsm + (wcol + nf * 16 + lr) * 64 + lc * 16);
        #pragma unroll
        for (int m = 0; m < 4; ++m)
            #pragma unroll
            for (int nf = 0; nf < 4; ++nf)
                acc[m][nf] = __builtin_amdgcn_mfma_f32_16x16x32_bf16(
                    a[m], b[nf], acc[m][nf], 0, 0, 0);
    }

    #pragma unroll
    for (int m = 0; m < 4; ++m)
        #pragma unroll
        for (int nf = 0; nf < 4; ++nf)
            #pragma unroll
            for (int j = 0; j < 4; ++j) {
                const int rg = row0 + wrow + m * 16 + lc * 4 + j;
                const int cg = col0 + wcol + nf * 16 + lr;
                out0[(size_t)rg * N + cg] = acc[m][nf][j];
            }
}

// ---------- NEW: skinny BC GEMM via MFMA, direct from global ----------
// BC[M,32] = xsb[M,768] @ WxT[32,768]^T. Wave owns 16 rows x 32 cols.
// Fragment maps identical to gemm_bf16 (HW-verified).
__global__ __launch_bounds__(256)
void bc_mfma(const __hip_bfloat16* __restrict__ xsb,
             const __hip_bfloat16* __restrict__ WxT,
             float* __restrict__ BC)
{
    const int w = threadIdx.x >> 6, lane = threadIdx.x & 63;
    const int lr = lane & 15, lc = lane >> 4;
    const int row0 = blockIdx.x * 64 + w * 16;

    f32x4 acc0 = {}, acc1 = {};
    const __hip_bfloat16* ap = xsb + (size_t)(row0 + lr) * Kd + lc * 8;
    const __hip_bfloat16* b0p = WxT + (size_t)lr * Kd + lc * 8;
    const __hip_bfloat16* b1p = WxT + (size_t)(16 + lr) * Kd + lc * 8;
    #pragma unroll 4
    for (int kt = 0; kt < Kd / 32; ++kt) {
        const short8v a  = *(const short8v*)(ap  + kt * 32);
        const short8v b0 = *(const short8v*)(b0p + kt * 32);
        const short8v b1 = *(const short8v*)(b1p + kt * 32);
        acc0 = __builtin_amdgcn_mfma_f32_16x16x32_bf16(a, b0, acc0, 0, 0, 0);
        acc1 = __builtin_amdgcn_mfma_f32_16x16x32_bf16(a, b1, acc1, 0, 0, 0);
    }
    // C/D map: row = row0 + lc*4 + j, col = lr / 16+lr  [HW-verified]
    #pragma unroll
    for (int j = 0; j < 4; ++j) {
        const size_t r = (size_t)(row0 + lc * 4 + j) * 32;
        BC[r + lr]      = acc0[j];
        BC[r + 16 + lr] = acc1[j];
    }
}

// ---------------- prep kernels (HW-verified) ----------------
__global__ __launch_bounds__(256)
void to_bf16_kernel(const float* __restrict__ src, __hip_bfloat16* __restrict__ dst, int n4)
{
    const int i = blockIdx.x * 256 + threadIdx.x;
    if (i >= n4) return;
    const float4 v = ((const float4*)src)[i];
    dst[i * 4 + 0] = __float2bfloat16(v.x);
    dst[i * 4 + 1] = __float2bfloat16(v.y);
    dst[i * 4 + 2] = __float2bfloat16(v.z);
    dst[i * 4 + 3] = __float2bfloat16(v.w);
}

__global__ __launch_bounds__(256)
void wtrans_kernel(const float* __restrict__ src, __hip_bfloat16* __restrict__ dst, int N)
{
    const int idx = blockIdx.x * 256 + threadIdx.x;
    if (idx >= N * Kd) return;
    const int n = idx / Kd, k = idx % Kd;
    dst[idx] = __float2bfloat16(src[(size_t)k * N + n]);
}

__global__ __launch_bounds__(256)
void aprep_kernel(const float* __restrict__ A_log, float* __restrict__ Abuf)
{
    const int i = blockIdx.x * 256 + threadIdx.x;
    if (i < Dc * Nc) Abuf[i] = -expf(A_log[i]);
}

// ---------------- conv + silu: xc fp32 -> bf16 xsb ----------------
__global__ __launch_bounds__(256)
void conv_silu_kernel(const float* __restrict__ xc, const float* __restrict__ cw,
                      const float* __restrict__ cb, __hip_bfloat16* __restrict__ xsb)
{
    const int idx = blockIdx.x * 256 + threadIdx.x;
    if (idx >= M_TOT * Dc) return;
    const int d = idx % Dc;
    const int t = (idx / Dc) & (Lc - 1);
    float acc = cb[d];
    #pragma unroll
    for (int k = 0; k < 4; ++k) {
        const int tt = t + k - 3;
        if (tt >= 0)
            acc = fmaf(xc[(size_t)idx + (ptrdiff_t)(k - 3) * Dc], cw[d * 4 + k], acc);
    }
    xsb[idx] = __float2bfloat16(siluf(acc));
}

// ---------------- chunked scan (round-12 HW-verified, verbatim) ----------------
__global__ __launch_bounds__(256)
void scanA(const float* __restrict__ dtb, const __hip_bfloat16* __restrict__ xsb,
           const float* __restrict__ bc, const float* __restrict__ Abuf,
           const float* __restrict__ bdt,
           float* __restrict__ S, float* __restrict__ dcend)
{
    const int blk = blockIdx.x;
    const int dblk = blk % 3, ch = (blk / 3) % NCH, b = blk / (3 * NCH);
    const int d = dblk * 256 + threadIdx.x;
    const int t0 = ch * TCH;

    __shared__ float bcs[TCH * 32];
    {
        const int row = threadIdx.x >> 3, c4 = (threadIdx.x & 7) * 4;
        *(float4*)&bcs[row * 32 + c4] =
            *(const float4*)(bc + ((size_t)(b * Lc + t0) + row) * 32 + c4);
    }
    __syncthreads();

    float A[16];
    #pragma unroll
    for (int q = 0; q < 4; ++q)
        *(float4*)&A[q * 4] = *(const float4*)(Abuf + d * 16 + q * 4);
    const float bd = bdt[d];

    float s[16];
    #pragma unroll
    for (int n = 0; n < 16; ++n) s[n] = 0.f;

    const size_t base = ((size_t)(b * Lc + t0)) * Dc + d;
    float dc = 0.f;
    for (int t = 0; t < TCH; ++t) {
        const float dt = softplusf(dtb[base + (size_t)t * Dc] + bd);
        const float x  = __bfloat162float(xsb[base + (size_t)t * Dc]);
        dc += dt;
        #pragma unroll
        for (int n = 0; n < 16; ++n) {
            const float dA = __expf(dt * A[n]);
            s[n] = fmaf(s[n], dA, bcs[t * 32 + n] * x);
        }
    }
    const size_t g = (size_t)(b * NCH + ch) * Dc + d;
    #pragma unroll
    for (int n = 0; n < 16; ++n) S[g * 16 + n] = s[n];
    dcend[g] = dc;
}

__global__ __launch_bounds__(256)
void scanB(float* __restrict__ S_io, const float* __restrict__ dcend,
           const float* __restrict__ Abuf)
{
    const int tid = blockIdx.x * 256 + threadIdx.x;
    const int n = tid & 15;
    const int d = (tid >> 4) % Dc;
    const int b = tid / (16 * Dc);
    const float An = Abuf[d * 16 + n];
    float s = 0.f;
    for (int ch = 0; ch < NCH; ++ch) {
        const size_t g = (size_t)(b * NCH + ch) * Dc + d;
        const float sv = S_io[g * 16 + n];
        const float p  = __expf(dcend[g] * An);
        S_io[g * 16 + n] = s;
        s = fmaf(s, p, sv);
    }
}

__global__ __launch_bounds__(256)
void scanC(const float* __restrict__ dtb, const __hip_bfloat16* __restrict__ xsb,
           const float* __restrict__ zb, const float* __restrict__ bc,
           const float* __restrict__ Abuf, const float* __restrict__ bdt,
           const float* __restrict__ Ibuf, const float* __restrict__ Dvec,
           __hip_bfloat16* __restrict__ ybf)
{
    const int blk = blockIdx.x;
    const int dblk = blk % 3, ch = (blk / 3) % NCH, b = blk / (3 * NCH);
    const int d = dblk * 256 + threadIdx.x;
    const int t0 = ch * TCH;

    __shared__ float bcs[TCH * 32];
    {
        const int row = threadIdx.x >> 3, c4 = (threadIdx.x & 7) * 4;
        *(float4*)&bcs[row * 32 + c4] =
            *(const float4*)(bc + ((size_t)(b * Lc + t0) + row) * 32 + c4);
    }
    __syncthreads();

    float A[16], s[16];
    #pragma unroll
    for (int q = 0; q < 4; ++q)
        *(float4*)&A[q * 4] = *(const float4*)(Abuf + d * 16 + q * 4);
    const size_t g = (size_t)(b * NCH + ch) * Dc + d;
    #pragma unroll
    for (int q = 0; q < 4; ++q)
        *(float4*)&s[q * 4] = *(const float4*)(Ibuf + g * 16 + q * 4);
    const float bd = bdt[d];
    const float Dd = Dvec[d];

    const size_t base = ((size_t)(b * Lc + t0)) * Dc + d;
    for (int t = 0; t < TCH; ++t) {
        const float dt = softplusf(dtb[base + (size_t)t * Dc] + bd);
        const float x  = __bfloat162float(xsb[base + (size_t)t * Dc]);
        const float z  = zb[base + (size_t)t * Dc];
        float yl = fmaf(Dd, x, 0.f);
        #pragma unroll
        for (int n = 0; n < 16; ++n) {
            const float dA = __expf(dt * A[n]);
            s[n] = fmaf(s[n], dA, bcs[t * 32 + n] * x);
            yl = fmaf(s[n], bcs[t * 32 + 16 + n], yl);
        }
        ybf[base + (size_t)t * Dc] = __float2bfloat16(yl * siluf(z));
    }
}

extern "C" void kernel_launch(void* const* d_in, const int* in_sizes, int n_in,
                              void* d_out, int out_size, void* d_ws, size_t ws_size,
                              hipStream_t stream)
{
    const float* x      = (const float*)d_in[0];
    const float* state  = (const float*)d_in[1];
    const float* W_in   = (const float*)d_in[2];
    const float* conv_w = (const float*)d_in[3];
    const float* conv_b = (const float*)d_in[4];
    const float* W_x    = (const float*)d_in[5];
    const float* W_dt   = (const float*)d_in[6];
    const float* b_dt   = (const float*)d_in[7];
    const float* A_log  = (const float*)d_in[8];
    const float* Dvec   = (const float*)d_in[9];
    const float* W_out  = (const float*)d_in[10];
    float* out = (float*)d_out;

    // ---- workspace (round-11 layout + 48 KB WxT; <= 253.75 MB verified) ----
    char* wsb = (char*)d_ws;
    float* xc    = (float*)wsb;                      wsb += (size_t)M_TOT * Dc * 4;
    float* zb    = (float*)wsb;                      wsb += (size_t)M_TOT * Dc * 4;
    float* dtb   = (float*)wsb;                      wsb += (size_t)M_TOT * Dc * 4;
    float* bc    = (float*)wsb;                      wsb += (size_t)M_TOT * 32 * 4;
    float* Sb    = (float*)wsb;                      wsb += (size_t)Bc * NCH * Dc * Nc * 4;
    float* dcend = (float*)wsb;                      wsb += (size_t)Bc * NCH * Dc * 4;
    __hip_bfloat16* xb  = (__hip_bfloat16*)wsb;      wsb += (size_t)M_TOT * Dc * 2;
    __hip_bfloat16* xsb = (__hip_bfloat16*)wsb;      wsb += (size_t)M_TOT * Dc * 2;
    float* Abuf = (float*)wsb;                       wsb += (size_t)Dc * Nc * 4;
    __hip_bfloat16* WinT  = (__hip_bfloat16*)wsb;    wsb += (size_t)1536 * Kd * 2;
    __hip_bfloat16* WdtT  = (__hip_bfloat16*)wsb;    wsb += (size_t)768 * Kd * 2;
    __hip_bfloat16* WoutT = (__hip_bfloat16*)wsb;    wsb += (size_t)768 * Kd * 2;
    __hip_bfloat16* WxT   = (__hip_bfloat16*)wsb;    wsb += (size_t)32 * Kd * 2;
    float* Ib = Sb;                               // scanB in-place (verified)
    __hip_bfloat16* ybf = (__hip_bfloat16*)xc;    // xc dead after conv

    // ---- prep (NO hipMemsetAsync — correlated with all 3 failures) ----
    to_bf16_kernel<<<(M_TOT * Dc / 4 + 255) / 256, 256, 0, stream>>>(x, xb, M_TOT * Dc / 4);
    wtrans_kernel<<<(1536 * Kd + 255) / 256, 256, 0, stream>>>(W_in, WinT, 1536);
    wtrans_kernel<<<(768 * Kd + 255) / 256, 256, 0, stream>>>(W_dt, WdtT, 768);
    wtrans_kernel<<<(768 * Kd + 255) / 256, 256, 0, stream>>>(W_out, WoutT, 768);
    wtrans_kernel<<<(32 * Kd + 255) / 256, 256, 0, stream>>>(W_x, WxT, 32);
    aprep_kernel<<<(Dc * Nc + 255) / 256, 256, 0, stream>>>(A_log, Abuf);

    // 1) in_proj, two N=768 dispatches (verified config)
    gemm_bf16<<<dim3(Dc / 128, M_TOT / 128), 256, 0, stream>>>(xb, WinT, Dc, xc);
    gemm_bf16<<<dim3(Dc / 128, M_TOT / 128), 256, 0, stream>>>(
        xb, WinT + (size_t)768 * Kd, Dc, zb);
    // 2) conv + silu -> bf16 xsb
    conv_silu_kernel<<<(M_TOT * Dc + 255) / 256, 256, 0, stream>>>(xc, conv_w, conv_b, xsb);
    // 3) dtraw = xsb @ W_dt
    gemm_bf16<<<dim3(Dc / 128, M_TOT / 128), 256, 0, stream>>>(xsb, WdtT, Dc, dtb);
    // 4) BC = xsb @ W_x  (MFMA skinny GEMM)
    bc_mfma<<<M_TOT / 64, 256, 0, stream>>>(xsb, WxT, bc);
    // 5) scan: A-lite -> B -> C-full
    scanA<<<Bc * NCH * 3, 256, 0, stream>>>(dtb, xsb, bc, Abuf, b_dt, Sb, dcend);
    scanB<<<(Bc * Dc * Nc) / 256, 256, 0, stream>>>(Sb, dcend, Abuf);
    scanC<<<Bc * NCH * 3, 256, 0, stream>>>(dtb, xsb, zb, bc, Abuf, b_dt, Ib, Dvec, ybf);
    // 6) out = y @ W_out
    gemm_bf16<<<dim3(Dc / 128, M_TOT / 128), 256, 0, stream>>>(ybf, WoutT, Dc, out);
    // 7) state pass-through
    hipMemcpyAsync(out + (size_t)M_TOT * Dc, state,
                   (size_t)(Bc * Dc * Nc) * sizeof(float),
                   hipMemcpyDeviceToDevice, stream);
}

// Round 14
// 336.937 us; speedup vs baseline: 6.3383x; 1.1400x over previous
//
#include <hip/hip_runtime.h>
#include <hip/hip_bf16.h>
#include <cstdint>
#include <cstddef>

constexpr int Bc = 4, Lc = 4096, Dc = 768, Nc = 16;
constexpr int M_TOT = Bc * Lc;     // 16384
constexpr int NCH = 128;           // chunks per sequence
constexpr int TCH = Lc / NCH;      // 32
constexpr int Kd = 768;            // K of all GEMMs
constexpr int TWO_D = 1536;

typedef __attribute__((ext_vector_type(8))) short short8v;   // 8 bf16 (4 VGPRs)
typedef __attribute__((ext_vector_type(4))) float f32x4;     // MFMA acc

// fast softplus: |err| <= ~1e-7 absolute
__device__ __forceinline__ float softplusf(float x) {
    return (x > 20.0f) ? x : __logf(1.0f + __expf(x));
}
__device__ __forceinline__ float siluf(float x) {
    return x / (1.0f + __expf(-x));
}

// ---------- bf16 MFMA GEMM (round-11 HW-verified, verbatim) ----------
__global__ __launch_bounds__(256)
void gemm_bf16(const __hip_bfloat16* __restrict__ Ab,
               const __hip_bfloat16* __restrict__ Wt,
               int N, float* __restrict__ out0)
{
    __shared__ __hip_bfloat16 Asm[128 * 32];
    __shared__ __hip_bfloat16 Bsm[128 * 32];
    const int tid = threadIdx.x;
    const int w = tid >> 6, lane = tid & 63;
    const int lr = lane & 15, lc = lane >> 4;
    const int row0 = blockIdx.y * 128, col0 = blockIdx.x * 128;
    const int wrow = (w >> 1) * 64, wcol = (w & 1) * 64;

    const int srow = lane >> 2;
    const int scol = (lane & 3) * 8;

    f32x4 acc[4][4] = {};

    const int KT = Kd / 32;
    for (int kt = 0; kt < KT; ++kt) {
        if (kt) __syncthreads();
        #pragma unroll
        for (int i = 0; i < 2; ++i) {
            const int seg = w * 2 + i;
            const __hip_bfloat16* asrc =
                Ab + (size_t)(row0 + seg * 16 + srow) * Kd + kt * 32 + scol;
            const __hip_bfloat16* bsrc =
                Wt + (size_t)(col0 + seg * 16 + srow) * Kd + kt * 32 + scol;
            __builtin_amdgcn_global_load_lds(
                (const __attribute__((address_space(1))) void*)asrc,
                (__attribute__((address_space(3))) void*)(Asm + seg * 512), 16, 0, 0);
            __builtin_amdgcn_global_load_lds(
                (const __attribute__((address_space(1))) void*)bsrc,
                (__attribute__((address_space(3))) void*)(Bsm + seg * 512), 16, 0, 0);
        }
        asm volatile("s_waitcnt vmcnt(0)" ::: "memory");
        __syncthreads();

        short8v a[4], b[4];
        #pragma unroll
        for (int m = 0; m < 4; ++m)
            a[m] = *(const short8v*)((char*)Asm + (wrow + m * 16 + lr) * 64 + lc * 16);
        #pragma unroll
        for (int nf = 0; nf < 4; ++nf)
            b[nf] = *(const short8v*)((char*)Bsm + (wcol + nf * 16 + lr) * 64 + lc * 16);
        #pragma unroll
        for (int m = 0; m < 4; ++m)
            #pragma unroll
            for (int nf = 0; nf < 4; ++nf)
                acc[m][nf] = __builtin_amdgcn_mfma_f32_16x16x32_bf16(
                    a[m], b[nf], acc[m][nf], 0, 0, 0);
    }

    #pragma unroll
    for (int m = 0; m < 4; ++m)
        #pragma unroll
        for (int nf = 0; nf < 4; ++nf)
            #pragma unroll
            for (int j = 0; j < 4; ++j) {
                const int rg = row0 + wrow + m * 16 + lc * 4 + j;
                const int cg = col0 + wcol + nf * 16 + lr;
                out0[(size_t)rg * N + cg] = acc[m][nf][j];
            }
}

// ---------- skinny BC GEMM via MFMA (round-13 HW-verified, verbatim) ----------
__global__ __launch_bounds__(256)
void bc_mfma(const __hip_bfloat16* __restrict__ xsb,
             const __hip_bfloat16* __restrict__ WxT,
             float* __restrict__ BC)
{
    const int w = threadIdx.x >> 6, lane = threadIdx.x & 63;
    const int lr = lane & 15, lc = lane >> 4;
    const int row0 = blockIdx.x * 64 + w * 16;

    f32x4 acc0 = {}, acc1 = {};
    const __hip_bfloat16* ap = xsb + (size_t)(row0 + lr) * Kd + lc * 8;
    const __hip_bfloat16* b0p = WxT + (size_t)lr * Kd + lc * 8;
    const __hip_bfloat16* b1p = WxT + (size_t)(16 + lr) * Kd + lc * 8;
    #pragma unroll 4
    for (int kt = 0; kt < Kd / 32; ++kt) {
        const short8v a  = *(const short8v*)(ap  + kt * 32);
        const short8v b0 = *(const short8v*)(b0p + kt * 32);
        const short8v b1 = *(const short8v*)(b1p + kt * 32);
        acc0 = __builtin_amdgcn_mfma_f32_16x16x32_bf16(a, b0, acc0, 0, 0, 0);
        acc1 = __builtin_amdgcn_mfma_f32_16x16x32_bf16(a, b1, acc1, 0, 0, 0);
    }
    #pragma unroll
    for (int j = 0; j < 4; ++j) {
        const size_t r = (size_t)(row0 + lc * 4 + j) * 32;
        BC[r + lr]      = acc0[j];
        BC[r + 16 + lr] = acc1[j];
    }
}

// ---------------- prep kernels (HW-verified) ----------------
__global__ __launch_bounds__(256)
void to_bf16_kernel(const float* __restrict__ src, __hip_bfloat16* __restrict__ dst, int n4)
{
    const int i = blockIdx.x * 256 + threadIdx.x;
    if (i >= n4) return;
    const float4 v = ((const float4*)src)[i];
    dst[i * 4 + 0] = __float2bfloat16(v.x);
    dst[i * 4 + 1] = __float2bfloat16(v.y);
    dst[i * 4 + 2] = __float2bfloat16(v.z);
    dst[i * 4 + 3] = __float2bfloat16(v.w);
}

__global__ __launch_bounds__(256)
void wtrans_kernel(const float* __restrict__ src, __hip_bfloat16* __restrict__ dst, int N)
{
    const int idx = blockIdx.x * 256 + threadIdx.x;
    if (idx >= N * Kd) return;
    const int n = idx / Kd, k = idx % Kd;
    dst[idx] = __float2bfloat16(src[(size_t)k * N + n]);
}

__global__ __launch_bounds__(256)
void aprep_kernel(const float* __restrict__ A_log, float* __restrict__ Abuf)
{
    const int i = blockIdx.x * 256 + threadIdx.x;
    if (i < Dc * Nc) Abuf[i] = -expf(A_log[i]);
}

// ---------------- NEW t-blocked conv + silu ----------------
// Thread produces 8 consecutive t for one (b,d); 3-tap history in registers.
// Reads xz x-half (stride 1536); writes bf16 xsb (stride 768).
__global__ __launch_bounds__(256)
void conv_silu_kernel(const float* __restrict__ xz, const float* __restrict__ cw,
                      const float* __restrict__ cb, __hip_bfloat16* __restrict__ xsb)
{
    const int idx = blockIdx.x * 256 + threadIdx.x;   // (b, tblk, d), d fastest
    if (idx >= (M_TOT / 8) * Dc) return;
    const int d = idx % Dc;
    const int r8 = idx / Dc;
    const int tb = r8 & (Lc / 8 - 1);
    const int b = r8 / (Lc / 8);
    const int t0 = tb * 8;
    const size_t rbase = (size_t)(b * Lc + t0);

    const float w0 = cw[d * 4 + 0], w1 = cw[d * 4 + 1];
    const float w2 = cw[d * 4 + 2], w3 = cw[d * 4 + 3];
    const float bias = cb[d];

    float xm3 = 0.f, xm2 = 0.f, xm1 = 0.f;
    if (t0 >= 3) {
        xm3 = xz[(rbase - 3) * TWO_D + d];
        xm2 = xz[(rbase - 2) * TWO_D + d];
        xm1 = xz[(rbase - 1) * TWO_D + d];
    }
    #pragma unroll
    for (int tt = 0; tt < 8; ++tt) {
        const float x0 = xz[(rbase + tt) * TWO_D + d];
        const float acc = fmaf(w3, x0, fmaf(w2, xm1, fmaf(w1, xm2, fmaf(w0, xm3, bias))));
        xsb[(rbase + tt) * Dc + d] = __float2bfloat16(siluf(acc));
        xm3 = xm2; xm2 = xm1; xm1 = x0;
    }
}

// ---------------- chunked scan (round-12/13 HW-verified; z now stride 1536) ----------------
__global__ __launch_bounds__(256)
void scanA(const float* __restrict__ dtb, const __hip_bfloat16* __restrict__ xsb,
           const float* __restrict__ bc, const float* __restrict__ Abuf,
           const float* __restrict__ bdt,
           float* __restrict__ S, float* __restrict__ dcend)
{
    const int blk = blockIdx.x;
    const int dblk = blk % 3, ch = (blk / 3) % NCH, b = blk / (3 * NCH);
    const int d = dblk * 256 + threadIdx.x;
    const int t0 = ch * TCH;

    __shared__ float bcs[TCH * 32];
    {
        const int row = threadIdx.x >> 3, c4 = (threadIdx.x & 7) * 4;
        *(float4*)&bcs[row * 32 + c4] =
            *(const float4*)(bc + ((size_t)(b * Lc + t0) + row) * 32 + c4);
    }
    __syncthreads();

    float A[16];
    #pragma unroll
    for (int q = 0; q < 4; ++q)
        *(float4*)&A[q * 4] = *(const float4*)(Abuf + d * 16 + q * 4);
    const float bd = bdt[d];

    float s[16];
    #pragma unroll
    for (int n = 0; n < 16; ++n) s[n] = 0.f;

    const size_t base = ((size_t)(b * Lc + t0)) * Dc + d;
    float dc = 0.f;
    for (int t = 0; t < TCH; ++t) {
        const float dt = softplusf(dtb[base + (size_t)t * Dc] + bd);
        const float x  = __bfloat162float(xsb[base + (size_t)t * Dc]);
        dc += dt;
        #pragma unroll
        for (int n = 0; n < 16; ++n) {
            const float dA = __expf(dt * A[n]);
            s[n] = fmaf(s[n], dA, bcs[t * 32 + n] * x);
        }
    }
    const size_t g = (size_t)(b * NCH + ch) * Dc + d;
    #pragma unroll
    for (int n = 0; n < 16; ++n) S[g * 16 + n] = s[n];
    dcend[g] = dc;
}

__global__ __launch_bounds__(256)
void scanB(float* __restrict__ S_io, const float* __restrict__ dcend,
           const float* __restrict__ Abuf)
{
    const int tid = blockIdx.x * 256 + threadIdx.x;
    const int n = tid & 15;
    const int d = (tid >> 4) % Dc;
    const int b = tid / (16 * Dc);
    const float An = Abuf[d * 16 + n];
    float s = 0.f;
    for (int ch = 0; ch < NCH; ++ch) {
        const size_t g = (size_t)(b * NCH + ch) * Dc + d;
        const float sv = S_io[g * 16 + n];
        const float p  = __expf(dcend[g] * An);
        S_io[g * 16 + n] = s;
        s = fmaf(s, p, sv);
    }
}

__global__ __launch_bounds__(256)
void scanC(const float* __restrict__ dtb, const __hip_bfloat16* __restrict__ xsb,
           const float* __restrict__ xz, const float* __restrict__ bc,
           const float* __restrict__ Abuf, const float* __restrict__ bdt,
           const float* __restrict__ Ibuf, const float* __restrict__ Dvec,
           __hip_bfloat16* __restrict__ ybf)
{
    const int blk = blockIdx.x;
    const int dblk = blk % 3, ch = (blk / 3) % NCH, b = blk / (3 * NCH);
    const int d = dblk * 256 + threadIdx.x;
    const int t0 = ch * TCH;

    __shared__ float bcs[TCH * 32];
    {
        const int row = threadIdx.x >> 3, c4 = (threadIdx.x & 7) * 4;
        *(float4*)&bcs[row * 32 + c4] =
            *(const float4*)(bc + ((size_t)(b * Lc + t0) + row) * 32 + c4);
    }
    __syncthreads();

    float A[16], s[16];
    #pragma unroll
    for (int q = 0; q < 4; ++q)
        *(float4*)&A[q * 4] = *(const float4*)(Abuf + d * 16 + q * 4);
    const size_t g = (size_t)(b * NCH + ch) * Dc + d;
    #pragma unroll
    for (int q = 0; q < 4; ++q)
        *(float4*)&s[q * 4] = *(const float4*)(Ibuf + g * 16 + q * 4);
    const float bd = bdt[d];
    const float Dd = Dvec[d];

    const size_t base = ((size_t)(b * Lc + t0)) * Dc + d;
    const size_t zbase = ((size_t)(b * Lc + t0)) * TWO_D + Dc + d;
    for (int t = 0; t < TCH; ++t) {
        const float dt = softplusf(dtb[base + (size_t)t * Dc] + bd);
        const float x  = __bfloat162float(xsb[base + (size_t)t * Dc]);
        const float z  = xz[zbase + (size_t)t * TWO_D];
        float yl = fmaf(Dd, x, 0.f);
        #pragma unroll
        for (int n = 0; n < 16; ++n) {
            const float dA = __expf(dt * A[n]);
            s[n] = fmaf(s[n], dA, bcs[t * 32 + n] * x);
            yl = fmaf(s[n], bcs[t * 32 + 16 + n], yl);
        }
        ybf[base + (size_t)t * Dc] = __float2bfloat16(yl * siluf(z));
    }
}

extern "C" void kernel_launch(void* const* d_in, const int* in_sizes, int n_in,
                              void* d_out, int out_size, void* d_ws, size_t ws_size,
                              hipStream_t stream)
{
    const float* x      = (const float*)d_in[0];
    const float* state  = (const float*)d_in[1];
    const float* W_in   = (const float*)d_in[2];
    const float* conv_w = (const float*)d_in[3];
    const float* conv_b = (const float*)d_in[4];
    const float* W_x    = (const float*)d_in[5];
    const float* W_dt   = (const float*)d_in[6];
    const float* b_dt   = (const float*)d_in[7];
    const float* A_log  = (const float*)d_in[8];
    const float* Dvec   = (const float*)d_in[9];
    const float* W_out  = (const float*)d_in[10];
    float* out = (float*)d_out;

    // ---- workspace (~233 MB <= 253.75 verified) ----
    char* wsb = (char*)d_ws;
    float* xz    = (float*)wsb;                      wsb += (size_t)M_TOT * TWO_D * 4;  // [xc|z] fused in_proj out
    float* dtb   = (float*)wsb;                      wsb += (size_t)M_TOT * Dc * 4;
    float* bc    = (float*)wsb;                      wsb += (size_t)M_TOT * 32 * 4;
    float* Sb    = (float*)wsb;                      wsb += (size_t)Bc * NCH * Dc * Nc * 4;
    float* dcend = (float*)wsb;                      wsb += (size_t)Bc * NCH * Dc * 4;
    __hip_bfloat16* xb  = (__hip_bfloat16*)wsb;      wsb += (size_t)M_TOT * Dc * 2;  // bf16(x); ybf aliases
    __hip_bfloat16* xsb = (__hip_bfloat16*)wsb;      wsb += (size_t)M_TOT * Dc * 2;
    float* Abuf = (float*)wsb;                       wsb += (size_t)Dc * Nc * 4;
    __hip_bfloat16* WinT  = (__hip_bfloat16*)wsb;    wsb += (size_t)1536 * Kd * 2;
    __hip_bfloat16* WdtT  = (__hip_bfloat16*)wsb;    wsb += (size_t)768 * Kd * 2;
    __hip_bfloat16* WoutT = (__hip_bfloat16*)wsb;    wsb += (size_t)768 * Kd * 2;
    __hip_bfloat16* WxT   = (__hip_bfloat16*)wsb;    wsb += (size_t)32 * Kd * 2;
    float* Ib = Sb;                               // scanB in-place (verified)
    __hip_bfloat16* ybf = xb;                     // xb dead after in_proj

    // ---- prep (NO hipMemsetAsync) ----
    to_bf16_kernel<<<(M_TOT * Dc / 4 + 255) / 256, 256, 0, stream>>>(x, xb, M_TOT * Dc / 4);
    wtrans_kernel<<<(1536 * Kd + 255) / 256, 256, 0, stream>>>(W_in, WinT, 1536);
    wtrans_kernel<<<(768 * Kd + 255) / 256, 256, 0, stream>>>(W_dt, WdtT, 768);
    wtrans_kernel<<<(768 * Kd + 255) / 256, 256, 0, stream>>>(W_out, WoutT, 768);
    wtrans_kernel<<<(32 * Kd + 255) / 256, 256, 0, stream>>>(W_x, WxT, 32);
    aprep_kernel<<<(Dc * Nc + 255) / 256, 256, 0, stream>>>(A_log, Abuf);

    // 1) in_proj FUSED: xz = xb @ WinT, N=1536 (memset-free wide-N experiment)
    gemm_bf16<<<dim3(TWO_D / 128, M_TOT / 128), 256, 0, stream>>>(xb, WinT, TWO_D, xz);
    // 2) t-blocked conv + silu -> bf16 xsb
    conv_silu_kernel<<<((M_TOT / 8) * Dc + 255) / 256, 256, 0, stream>>>(
        xz, conv_w, conv_b, xsb);
    // 3) dtraw = xsb @ W_dt
    gemm_bf16<<<dim3(Dc / 128, M_TOT / 128), 256, 0, stream>>>(xsb, WdtT, Dc, dtb);
    // 4) BC = xsb @ W_x
    bc_mfma<<<M_TOT / 64, 256, 0, stream>>>(xsb, WxT, bc);
    // 5) scan
    scanA<<<Bc * NCH * 3, 256, 0, stream>>>(dtb, xsb, bc, Abuf, b_dt, Sb, dcend);
    scanB<<<(Bc * Dc * Nc) / 256, 256, 0, stream>>>(Sb, dcend, Abuf);
    scanC<<<Bc * NCH * 3, 256, 0, stream>>>(dtb, xsb, xz, bc, Abuf, b_dt, Ib, Dvec, ybf);
    // 6) out = y @ W_out
    gemm_bf16<<<dim3(Dc / 128, M_TOT / 128), 256, 0, stream>>>(ybf, WoutT, Dc, out);
    // 7) state pass-through
    hipMemcpyAsync(out + (size_t)M_TOT * Dc, state,
                   (size_t)(Bc * Dc * Nc) * sizeof(float),
                   hipMemcpyDeviceToDevice, stream);
}

// Round 15
// 315.817 us; speedup vs baseline: 6.7621x; 1.0669x over previous
//
#include <hip/hip_runtime.h>
#include <hip/hip_bf16.h>
#include <cstdint>
#include <cstddef>

constexpr int Bc = 4, Lc = 4096, Dc = 768, Nc = 16;
constexpr int M_TOT = Bc * Lc;     // 16384
constexpr int NCH = 128;           // chunks per sequence
constexpr int TCH = Lc / NCH;      // 32
constexpr int Kd = 768;            // K of all GEMMs
constexpr int TWO_D = 1536;

typedef __attribute__((ext_vector_type(8))) short short8v;   // 8 bf16 (4 VGPRs)
typedef __attribute__((ext_vector_type(4))) float f32x4;     // MFMA acc

// native 2^x (v_exp_f32)
__device__ __forceinline__ float fexp2(float x) {
#if __has_builtin(__builtin_amdgcn_exp2f)
    return __builtin_amdgcn_exp2f(x);
#else
    return exp2f(x);
#endif
}

// fast softplus: |err| <= ~1e-7 absolute
__device__ __forceinline__ float softplusf(float x) {
    return (x > 20.0f) ? x : __logf(1.0f + __expf(x));
}
__device__ __forceinline__ float siluf(float x) {
    return x / (1.0f + __expf(-x));
}

// ---------- bf16 MFMA GEMM (round-11 HW-verified, verbatim) ----------
__global__ __launch_bounds__(256)
void gemm_bf16(const __hip_bfloat16* __restrict__ Ab,
               const __hip_bfloat16* __restrict__ Wt,
               int N, float* __restrict__ out0)
{
    __shared__ __hip_bfloat16 Asm[128 * 32];
    __shared__ __hip_bfloat16 Bsm[128 * 32];
    const int tid = threadIdx.x;
    const int w = tid >> 6, lane = tid & 63;
    const int lr = lane & 15, lc = lane >> 4;
    const int row0 = blockIdx.y * 128, col0 = blockIdx.x * 128;
    const int wrow = (w >> 1) * 64, wcol = (w & 1) * 64;

    const int srow = lane >> 2;
    const int scol = (lane & 3) * 8;

    f32x4 acc[4][4] = {};

    const int KT = Kd / 32;
    for (int kt = 0; kt < KT; ++kt) {
        if (kt) __syncthreads();
        #pragma unroll
        for (int i = 0; i < 2; ++i) {
            const int seg = w * 2 + i;
            const __hip_bfloat16* asrc =
                Ab + (size_t)(row0 + seg * 16 + srow) * Kd + kt * 32 + scol;
            const __hip_bfloat16* bsrc =
                Wt + (size_t)(col0 + seg * 16 + srow) * Kd + kt * 32 + scol;
            __builtin_amdgcn_global_load_lds(
                (const __attribute__((address_space(1))) void*)asrc,
                (__attribute__((address_space(3))) void*)(Asm + seg * 512), 16, 0, 0);
            __builtin_amdgcn_global_load_lds(
                (const __attribute__((address_space(1))) void*)bsrc,
                (__attribute__((address_space(3))) void*)(Bsm + seg * 512), 16, 0, 0);
        }
        asm volatile("s_waitcnt vmcnt(0)" ::: "memory");
        __syncthreads();

        short8v a[4], b[4];
        #pragma unroll
        for (int m = 0; m < 4; ++m)
            a[m] = *(const short8v*)((char*)Asm + (wrow + m * 16 + lr) * 64 + lc * 16);
        #pragma unroll
        for (int nf = 0; nf < 4; ++nf)
            b[nf] = *(const short8v*)((char*)Bsm + (wcol + nf * 16 + lr) * 64 + lc * 16);
        #pragma unroll
        for (int m = 0; m < 4; ++m)
            #pragma unroll
            for (int nf = 0; nf < 4; ++nf)
                acc[m][nf] = __builtin_amdgcn_mfma_f32_16x16x32_bf16(
                    a[m], b[nf], acc[m][nf], 0, 0, 0);
    }

    #pragma unroll
    for (int m = 0; m < 4; ++m)
        #pragma unroll
        for (int nf = 0; nf < 4; ++nf)
            #pragma unroll
            for (int j = 0; j < 4; ++j) {
                const int rg = row0 + wrow + m * 16 + lc * 4 + j;
                const int cg = col0 + wcol + nf * 16 + lr;
                out0[(size_t)rg * N + cg] = acc[m][nf][j];
            }
}

// ---------- skinny BC GEMM via MFMA (round-13 HW-verified, verbatim) ----------
__global__ __launch_bounds__(256)
void bc_mfma(const __hip_bfloat16* __restrict__ xsb,
             const __hip_bfloat16* __restrict__ WxT,
             float* __restrict__ BC)
{
    const int w = threadIdx.x >> 6, lane = threadIdx.x & 63;
    const int lr = lane & 15, lc = lane >> 4;
    const int row0 = blockIdx.x * 64 + w * 16;

    f32x4 acc0 = {}, acc1 = {};
    const __hip_bfloat16* ap = xsb + (size_t)(row0 + lr) * Kd + lc * 8;
    const __hip_bfloat16* b0p = WxT + (size_t)lr * Kd + lc * 8;
    const __hip_bfloat16* b1p = WxT + (size_t)(16 + lr) * Kd + lc * 8;
    #pragma unroll 4
    for (int kt = 0; kt < Kd / 32; ++kt) {
        const short8v a  = *(const short8v*)(ap  + kt * 32);
        const short8v b0 = *(const short8v*)(b0p + kt * 32);
        const short8v b1 = *(const short8v*)(b1p + kt * 32);
        acc0 = __builtin_amdgcn_mfma_f32_16x16x32_bf16(a, b0, acc0, 0, 0, 0);
        acc1 = __builtin_amdgcn_mfma_f32_16x16x32_bf16(a, b1, acc1, 0, 0, 0);
    }
    #pragma unroll
    for (int j = 0; j < 4; ++j) {
        const size_t r = (size_t)(row0 + lc * 4 + j) * 32;
        BC[r + lr]      = acc0[j];
        BC[r + 16 + lr] = acc1[j];
    }
}

// ---------------- prep kernels ----------------
__global__ __launch_bounds__(256)
void to_bf16_kernel(const float* __restrict__ src, __hip_bfloat16* __restrict__ dst, int n4)
{
    const int i = blockIdx.x * 256 + threadIdx.x;
    if (i >= n4) return;
    const float4 v = ((const float4*)src)[i];
    dst[i * 4 + 0] = __float2bfloat16(v.x);
    dst[i * 4 + 1] = __float2bfloat16(v.y);
    dst[i * 4 + 2] = __float2bfloat16(v.z);
    dst[i * 4 + 3] = __float2bfloat16(v.w);
}

__global__ __launch_bounds__(256)
void wtrans_kernel(const float* __restrict__ src, __hip_bfloat16* __restrict__ dst, int N)
{
    const int idx = blockIdx.x * 256 + threadIdx.x;
    if (idx >= N * Kd) return;
    const int n = idx / Kd, k = idx % Kd;
    dst[idx] = __float2bfloat16(src[(size_t)k * N + n]);
}

// A2[d][n] = -exp(A_log[d][n]) * log2(e)   (pre-scaled for exp2)
__global__ __launch_bounds__(256)
void aprep_kernel(const float* __restrict__ A_log, float* __restrict__ Abuf)
{
    const int i = blockIdx.x * 256 + threadIdx.x;
    if (i < Dc * Nc) Abuf[i] = -expf(A_log[i]) * 1.4426950408889634f;
}

// ---------------- t-blocked conv + silu (round-14 HW-verified, verbatim) ----------------
__global__ __launch_bounds__(256)
void conv_silu_kernel(const float* __restrict__ xz, const float* __restrict__ cw,
                      const float* __restrict__ cb, __hip_bfloat16* __restrict__ xsb)
{
    const int idx = blockIdx.x * 256 + threadIdx.x;   // (b, tblk, d), d fastest
    if (idx >= (M_TOT / 8) * Dc) return;
    const int d = idx % Dc;
    const int r8 = idx / Dc;
    const int tb = r8 & (Lc / 8 - 1);
    const int b = r8 / (Lc / 8);
    const int t0 = tb * 8;
    const size_t rbase = (size_t)(b * Lc + t0);

    const float w0 = cw[d * 4 + 0], w1 = cw[d * 4 + 1];
    const float w2 = cw[d * 4 + 2], w3 = cw[d * 4 + 3];
    const float bias = cb[d];

    float xm3 = 0.f, xm2 = 0.f, xm1 = 0.f;
    if (t0 >= 3) {
        xm3 = xz[(rbase - 3) * TWO_D + d];
        xm2 = xz[(rbase - 2) * TWO_D + d];
        xm1 = xz[(rbase - 1) * TWO_D + d];
    }
    #pragma unroll
    for (int tt = 0; tt < 8; ++tt) {
        const float x0 = xz[(rbase + tt) * TWO_D + d];
        const float acc = fmaf(w3, x0, fmaf(w2, xm1, fmaf(w1, xm2, fmaf(w0, xm3, bias))));
        xsb[(rbase + tt) * Dc + d] = __float2bfloat16(siluf(acc));
        xm3 = xm2; xm2 = xm1; xm1 = x0;
    }
}

// ---------------- chunked scan (exp2 pre-scaled A) ----------------
__global__ __launch_bounds__(256)
void scanA(const float* __restrict__ dtb, const __hip_bfloat16* __restrict__ xsb,
           const float* __restrict__ bc, const float* __restrict__ Abuf,
           const float* __restrict__ bdt,
           float* __restrict__ S, float* __restrict__ dcend)
{
    const int blk = blockIdx.x;
    const int dblk = blk % 3, ch = (blk / 3) % NCH, b = blk / (3 * NCH);
    const int d = dblk * 256 + threadIdx.x;
    const int t0 = ch * TCH;

    __shared__ float bcs[TCH * 32];
    {
        const int row = threadIdx.x >> 3, c4 = (threadIdx.x & 7) * 4;
        *(float4*)&bcs[row * 32 + c4] =
            *(const float4*)(bc + ((size_t)(b * Lc + t0) + row) * 32 + c4);
    }
    __syncthreads();

    float A[16];
    #pragma unroll
    for (int q = 0; q < 4; ++q)
        *(float4*)&A[q * 4] = *(const float4*)(Abuf + d * 16 + q * 4);
    const float bd = bdt[d];

    float s[16];
    #pragma unroll
    for (int n = 0; n < 16; ++n) s[n] = 0.f;

    const size_t base = ((size_t)(b * Lc + t0)) * Dc + d;
    float dc = 0.f;
    #pragma unroll 2
    for (int t = 0; t < TCH; ++t) {
        const float dt = softplusf(dtb[base + (size_t)t * Dc] + bd);
        const float x  = __bfloat162float(xsb[base + (size_t)t * Dc]);
        dc += dt;
        #pragma unroll
        for (int n = 0; n < 16; ++n) {
            const float dA = fexp2(dt * A[n]);
            s[n] = fmaf(s[n], dA, bcs[t * 32 + n] * x);
        }
    }
    const size_t g = (size_t)(b * NCH + ch) * Dc + d;
    #pragma unroll
    for (int n = 0; n < 16; ++n) S[g * 16 + n] = s[n];
    dcend[g] = dc;
}

__global__ __launch_bounds__(256)
void scanB(float* __restrict__ S_io, const float* __restrict__ dcend,
           const float* __restrict__ Abuf)
{
    const int tid = blockIdx.x * 256 + threadIdx.x;
    const int n = tid & 15;
    const int d = (tid >> 4) % Dc;
    const int b = tid / (16 * Dc);
    const float An = Abuf[d * 16 + n];
    float s = 0.f;
    for (int ch = 0; ch < NCH; ++ch) {
        const size_t g = (size_t)(b * NCH + ch) * Dc + d;
        const float sv = S_io[g * 16 + n];
        const float p  = fexp2(dcend[g] * An);
        S_io[g * 16 + n] = s;
        s = fmaf(s, p, sv);
    }
}

__global__ __launch_bounds__(256)
void scanC(const float* __restrict__ dtb, const __hip_bfloat16* __restrict__ xsb,
           const float* __restrict__ xz, const float* __restrict__ bc,
           const float* __restrict__ Abuf, const float* __restrict__ bdt,
           const float* __restrict__ Ibuf, const float* __restrict__ Dvec,
           __hip_bfloat16* __restrict__ ybf)
{
    const int blk = blockIdx.x;
    const int dblk = blk % 3, ch = (blk / 3) % NCH, b = blk / (3 * NCH);
    const int d = dblk * 256 + threadIdx.x;
    const int t0 = ch * TCH;

    __shared__ float bcs[TCH * 32];
    {
        const int row = threadIdx.x >> 3, c4 = (threadIdx.x & 7) * 4;
        *(float4*)&bcs[row * 32 + c4] =
            *(const float4*)(bc + ((size_t)(b * Lc + t0) + row) * 32 + c4);
    }
    __syncthreads();

    float A[16], s[16];
    #pragma unroll
    for (int q = 0; q < 4; ++q)
        *(float4*)&A[q * 4] = *(const float4*)(Abuf + d * 16 + q * 4);
    const size_t g = (size_t)(b * NCH + ch) * Dc + d;
    #pragma unroll
    for (int q = 0; q < 4; ++q)
        *(float4*)&s[q * 4] = *(const float4*)(Ibuf + g * 16 + q * 4);
    const float bd = bdt[d];
    const float Dd = Dvec[d];

    const size_t base = ((size_t)(b * Lc + t0)) * Dc + d;
    const size_t zbase = ((size_t)(b * Lc + t0)) * TWO_D + Dc + d;
    #pragma unroll 2
    for (int t = 0; t < TCH; ++t) {
        const float dt = softplusf(dtb[base + (size_t)t * Dc] + bd);
        const float x  = __bfloat162float(xsb[base + (size_t)t * Dc]);
        const float z  = xz[zbase + (size_t)t * TWO_D];
        float yl = fmaf(Dd, x, 0.f);
        #pragma unroll
        for (int n = 0; n < 16; ++n) {
            const float dA = fexp2(dt * A[n]);
            s[n] = fmaf(s[n], dA, bcs[t * 32 + n] * x);
            yl = fmaf(s[n], bcs[t * 32 + 16 + n], yl);
        }
        ybf[base + (size_t)t * Dc] = __float2bfloat16(yl * siluf(z));
    }
}

extern "C" void kernel_launch(void* const* d_in, const int* in_sizes, int n_in,
                              void* d_out, int out_size, void* d_ws, size_t ws_size,
                              hipStream_t stream)
{
    const float* x      = (const float*)d_in[0];
    const float* state  = (const float*)d_in[1];
    const float* W_in   = (const float*)d_in[2];
    const float* conv_w = (const float*)d_in[3];
    const float* conv_b = (const float*)d_in[4];
    const float* W_x    = (const float*)d_in[5];
    const float* W_dt   = (const float*)d_in[6];
    const float* b_dt   = (const float*)d_in[7];
    const float* A_log  = (const float*)d_in[8];
    const float* Dvec   = (const float*)d_in[9];
    const float* W_out  = (const float*)d_in[10];
    float* out = (float*)d_out;

    // ---- workspace (~233 MB <= 253.75 verified; round-14 layout verbatim) ----
    char* wsb = (char*)d_ws;
    float* xz    = (float*)wsb;                      wsb += (size_t)M_TOT * TWO_D * 4;
    float* dtb   = (float*)wsb;                      wsb += (size_t)M_TOT * Dc * 4;
    float* bc    = (float*)wsb;                      wsb += (size_t)M_TOT * 32 * 4;
    float* Sb    = (float*)wsb;                      wsb += (size_t)Bc * NCH * Dc * Nc * 4;
    float* dcend = (float*)wsb;                      wsb += (size_t)Bc * NCH * Dc * 4;
    __hip_bfloat16* xb  = (__hip_bfloat16*)wsb;      wsb += (size_t)M_TOT * Dc * 2;
    __hip_bfloat16* xsb = (__hip_bfloat16*)wsb;      wsb += (size_t)M_TOT * Dc * 2;
    float* Abuf = (float*)wsb;                       wsb += (size_t)Dc * Nc * 4;
    __hip_bfloat16* WinT  = (__hip_bfloat16*)wsb;    wsb += (size_t)1536 * Kd * 2;
    __hip_bfloat16* WdtT  = (__hip_bfloat16*)wsb;    wsb += (size_t)768 * Kd * 2;
    __hip_bfloat16* WoutT = (__hip_bfloat16*)wsb;    wsb += (size_t)768 * Kd * 2;
    __hip_bfloat16* WxT   = (__hip_bfloat16*)wsb;    wsb += (size_t)32 * Kd * 2;
    float* Ib = Sb;                               // scanB in-place (verified)
    __hip_bfloat16* ybf = xb;                     // xb dead after in_proj

    // ---- prep (NO hipMemsetAsync) ----
    to_bf16_kernel<<<(M_TOT * Dc / 4 + 255) / 256, 256, 0, stream>>>(x, xb, M_TOT * Dc / 4);
    wtrans_kernel<<<(1536 * Kd + 255) / 256, 256, 0, stream>>>(W_in, WinT, 1536);
    wtrans_kernel<<<(768 * Kd + 255) / 256, 256, 0, stream>>>(W_dt, WdtT, 768);
    wtrans_kernel<<<(768 * Kd + 255) / 256, 256, 0, stream>>>(W_out, WoutT, 768);
    wtrans_kernel<<<(32 * Kd + 255) / 256, 256, 0, stream>>>(W_x, WxT, 32);
    aprep_kernel<<<(Dc * Nc + 255) / 256, 256, 0, stream>>>(A_log, Abuf);

    // 1) in_proj fused: xz = xb @ WinT, N=1536
    gemm_bf16<<<dim3(TWO_D / 128, M_TOT / 128), 256, 0, stream>>>(xb, WinT, TWO_D, xz);
    // 2) t-blocked conv + silu -> bf16 xsb
    conv_silu_kernel<<<((M_TOT / 8) * Dc + 255) / 256, 256, 0, stream>>>(
        xz, conv_w, conv_b, xsb);
    // 3) dtraw = xsb @ W_dt
    gemm_bf16<<<dim3(Dc / 128, M_TOT / 128), 256, 0, stream>>>(xsb, WdtT, Dc, dtb);
    // 4) BC = xsb @ W_x
    bc_mfma<<<M_TOT / 64, 256, 0, stream>>>(xsb, WxT, bc);
    // 5) scan
    scanA<<<Bc * NCH * 3, 256, 0, stream>>>(dtb, xsb, bc, Abuf, b_dt, Sb, dcend);
    scanB<<<(Bc * Dc * Nc) / 256, 256, 0, stream>>>(Sb, dcend, Abuf);
    scanC<<<Bc * NCH * 3, 256, 0, stream>>>(dtb, xsb, xz, bc, Abuf, b_dt, Ib, Dvec, ybf);
    // 6) out = y @ W_out
    gemm_bf16<<<dim3(Dc / 128, M_TOT / 128), 256, 0, stream>>>(ybf, WoutT, Dc, out);
    // 7) state pass-through
    hipMemcpyAsync(out + (size_t)M_TOT * Dc, state,
                   (size_t)(Bc * Dc * Nc) * sizeof(float),
                   hipMemcpyDeviceToDevice, stream);
}

// Round 17
// 304.329 us; speedup vs baseline: 7.0174x; 1.0378x over previous
//
#include <hip/hip_runtime.h>
#include <hip/hip_bf16.h>
#include <cstdint>
#include <cstddef>

constexpr int Bc = 4, Lc = 4096, Dc = 768, Nc = 16;
constexpr int M_TOT = Bc * Lc;     // 16384
constexpr int NCH = 128;           // chunks per sequence
constexpr int TCH = Lc / NCH;      // 32
constexpr int Kd = 768;            // K of all GEMMs
constexpr int TWO_D = 1536;

typedef __attribute__((ext_vector_type(8))) short short8v;   // 8 bf16 (4 VGPRs)
typedef __attribute__((ext_vector_type(4))) float f32x4;     // MFMA acc

__device__ __forceinline__ float fexp2(float x) {
#if __has_builtin(__builtin_amdgcn_exp2f)
    return __builtin_amdgcn_exp2f(x);
#else
    return exp2f(x);
#endif
}
__device__ __forceinline__ float softplusf(float x) {
    return (x > 20.0f) ? x : __logf(1.0f + __expf(x));
}
__device__ __forceinline__ float siluf(float x) {
    return x / (1.0f + __expf(-x));
}

// ---------- bf16 MFMA GEMM, fp32 out (round-11 HW-verified, NON-TEMPLATE) ----------
__global__ __launch_bounds__(256)
void gemm_bf16_f32(const __hip_bfloat16* __restrict__ Ab,
                   const __hip_bfloat16* __restrict__ Wt,
                   int N, float* __restrict__ out0)
{
    __shared__ __hip_bfloat16 Asm[128 * 32];
    __shared__ __hip_bfloat16 Bsm[128 * 32];
    const int tid = threadIdx.x;
    const int w = tid >> 6, lane = tid & 63;
    const int lr = lane & 15, lc = lane >> 4;
    const int row0 = blockIdx.y * 128, col0 = blockIdx.x * 128;
    const int wrow = (w >> 1) * 64, wcol = (w & 1) * 64;

    const int srow = lane >> 2;
    const int scol = (lane & 3) * 8;

    f32x4 acc[4][4] = {};

    const int KT = Kd / 32;
    for (int kt = 0; kt < KT; ++kt) {
        if (kt) __syncthreads();
        #pragma unroll
        for (int i = 0; i < 2; ++i) {
            const int seg = w * 2 + i;
            const __hip_bfloat16* asrc =
                Ab + (size_t)(row0 + seg * 16 + srow) * Kd + kt * 32 + scol;
            const __hip_bfloat16* bsrc =
                Wt + (size_t)(col0 + seg * 16 + srow) * Kd + kt * 32 + scol;
            __builtin_amdgcn_global_load_lds(
                (const __attribute__((address_space(1))) void*)asrc,
                (__attribute__((address_space(3))) void*)(Asm + seg * 512), 16, 0, 0);
            __builtin_amdgcn_global_load_lds(
                (const __attribute__((address_space(1))) void*)bsrc,
                (__attribute__((address_space(3))) void*)(Bsm + seg * 512), 16, 0, 0);
        }
        asm volatile("s_waitcnt vmcnt(0)" ::: "memory");
        __syncthreads();

        short8v a[4], b[4];
        #pragma unroll
        for (int m = 0; m < 4; ++m)
            a[m] = *(const short8v*)((char*)Asm + (wrow + m * 16 + lr) * 64 + lc * 16);
        #pragma unroll
        for (int nf = 0; nf < 4; ++nf)
            b[nf] = *(const short8v*)((char*)Bsm + (wcol + nf * 16 + lr) * 64 + lc * 16);
        #pragma unroll
        for (int m = 0; m < 4; ++m)
            #pragma unroll
            for (int nf = 0; nf < 4; ++nf)
                acc[m][nf] = __builtin_amdgcn_mfma_f32_16x16x32_bf16(
                    a[m], b[nf], acc[m][nf], 0, 0, 0);
    }

    #pragma unroll
    for (int m = 0; m < 4; ++m)
        #pragma unroll
        for (int nf = 0; nf < 4; ++nf)
            #pragma unroll
            for (int j = 0; j < 4; ++j) {
                const int rg = row0 + wrow + m * 16 + lc * 4 + j;
                const int cg = col0 + wcol + nf * 16 + lr;
                out0[(size_t)rg * N + cg] = acc[m][nf][j];
            }
}

// ---------- bf16 MFMA GEMM, bf16 out (same body, SEPARATE non-template kernel) ----------
__global__ __launch_bounds__(256)
void gemm_bf16_b16(const __hip_bfloat16* __restrict__ Ab,
                   const __hip_bfloat16* __restrict__ Wt,
                   int N, __hip_bfloat16* __restrict__ outb)
{
    __shared__ __hip_bfloat16 Asm[128 * 32];
    __shared__ __hip_bfloat16 Bsm[128 * 32];
    const int tid = threadIdx.x;
    const int w = tid >> 6, lane = tid & 63;
    const int lr = lane & 15, lc = lane >> 4;
    const int row0 = blockIdx.y * 128, col0 = blockIdx.x * 128;
    const int wrow = (w >> 1) * 64, wcol = (w & 1) * 64;

    const int srow = lane >> 2;
    const int scol = (lane & 3) * 8;

    f32x4 acc[4][4] = {};

    const int KT = Kd / 32;
    for (int kt = 0; kt < KT; ++kt) {
        if (kt) __syncthreads();
        #pragma unroll
        for (int i = 0; i < 2; ++i) {
            const int seg = w * 2 + i;
            const __hip_bfloat16* asrc =
                Ab + (size_t)(row0 + seg * 16 + srow) * Kd + kt * 32 + scol;
            const __hip_bfloat16* bsrc =
                Wt + (size_t)(col0 + seg * 16 + srow) * Kd + kt * 32 + scol;
            __builtin_amdgcn_global_load_lds(
                (const __attribute__((address_space(1))) void*)asrc,
                (__attribute__((address_space(3))) void*)(Asm + seg * 512), 16, 0, 0);
            __builtin_amdgcn_global_load_lds(
                (const __attribute__((address_space(1))) void*)bsrc,
                (__attribute__((address_space(3))) void*)(Bsm + seg * 512), 16, 0, 0);
        }
        asm volatile("s_waitcnt vmcnt(0)" ::: "memory");
        __syncthreads();

        short8v a[4], b[4];
        #pragma unroll
        for (int m = 0; m < 4; ++m)
            a[m] = *(const short8v*)((char*)Asm + (wrow + m * 16 + lr) * 64 + lc * 16);
        #pragma unroll
        for (int nf = 0; nf < 4; ++nf)
            b[nf] = *(const short8v*)((char*)Bsm + (wcol + nf * 16 + lr) * 64 + lc * 16);
        #pragma unroll
        for (int m = 0; m < 4; ++m)
            #pragma unroll
            for (int nf = 0; nf < 4; ++nf)
                acc[m][nf] = __builtin_amdgcn_mfma_f32_16x16x32_bf16(
                    a[m], b[nf], acc[m][nf], 0, 0, 0);
    }

    #pragma unroll
    for (int m = 0; m < 4; ++m)
        #pragma unroll
        for (int nf = 0; nf < 4; ++nf)
            #pragma unroll
            for (int j = 0; j < 4; ++j) {
                const int rg = row0 + wrow + m * 16 + lc * 4 + j;
                const int cg = col0 + wcol + nf * 16 + lr;
                outb[(size_t)rg * N + cg] = __float2bfloat16(acc[m][nf][j]);
            }
}

// ---------- skinny BC GEMM via MFMA (round-13 HW-verified, verbatim) ----------
__global__ __launch_bounds__(256)
void bc_mfma(const __hip_bfloat16* __restrict__ xsb,
             const __hip_bfloat16* __restrict__ WxT,
             float* __restrict__ BC)
{
    const int w = threadIdx.x >> 6, lane = threadIdx.x & 63;
    const int lr = lane & 15, lc = lane >> 4;
    const int row0 = blockIdx.x * 64 + w * 16;

    f32x4 acc0 = {}, acc1 = {};
    const __hip_bfloat16* ap = xsb + (size_t)(row0 + lr) * Kd + lc * 8;
    const __hip_bfloat16* b0p = WxT + (size_t)lr * Kd + lc * 8;
    const __hip_bfloat16* b1p = WxT + (size_t)(16 + lr) * Kd + lc * 8;
    #pragma unroll 4
    for (int kt = 0; kt < Kd / 32; ++kt) {
        const short8v a  = *(const short8v*)(ap  + kt * 32);
        const short8v b0 = *(const short8v*)(b0p + kt * 32);
        const short8v b1 = *(const short8v*)(b1p + kt * 32);
        acc0 = __builtin_amdgcn_mfma_f32_16x16x32_bf16(a, b0, acc0, 0, 0, 0);
        acc1 = __builtin_amdgcn_mfma_f32_16x16x32_bf16(a, b1, acc1, 0, 0, 0);
    }
    #pragma unroll
    for (int j = 0; j < 4; ++j) {
        const size_t r = (size_t)(row0 + lc * 4 + j) * 32;
        BC[r + lr]      = acc0[j];
        BC[r + 16 + lr] = acc1[j];
    }
}

// ---------------- prep kernels (HW-verified) ----------------
__global__ __launch_bounds__(256)
void to_bf16_kernel(const float* __restrict__ src, __hip_bfloat16* __restrict__ dst, int n4)
{
    const int i = blockIdx.x * 256 + threadIdx.x;
    if (i >= n4) return;
    const float4 v = ((const float4*)src)[i];
    dst[i * 4 + 0] = __float2bfloat16(v.x);
    dst[i * 4 + 1] = __float2bfloat16(v.y);
    dst[i * 4 + 2] = __float2bfloat16(v.z);
    dst[i * 4 + 3] = __float2bfloat16(v.w);
}

__global__ __launch_bounds__(256)
void wtrans_kernel(const float* __restrict__ src, __hip_bfloat16* __restrict__ dst, int N)
{
    const int idx = blockIdx.x * 256 + threadIdx.x;
    if (idx >= N * Kd) return;
    const int n = idx / Kd, k = idx % Kd;
    dst[idx] = __float2bfloat16(src[(size_t)k * N + n]);
}

// A2[d][n] = -exp(A_log[d][n]) * log2(e)
__global__ __launch_bounds__(256)
void aprep_kernel(const float* __restrict__ A_log, float* __restrict__ Abuf)
{
    const int i = blockIdx.x * 256 + threadIdx.x;
    if (i < Dc * Nc) Abuf[i] = -expf(A_log[i]) * 1.4426950408889634f;
}

// ---------------- t-blocked conv + silu (bf16 in, bf16 out) ----------------
__global__ __launch_bounds__(256)
void conv_silu_kernel(const __hip_bfloat16* __restrict__ xz16, const float* __restrict__ cw,
                      const float* __restrict__ cb, __hip_bfloat16* __restrict__ xsb)
{
    const int idx = blockIdx.x * 256 + threadIdx.x;   // (b, tblk, d), d fastest
    if (idx >= (M_TOT / 8) * Dc) return;
    const int d = idx % Dc;
    const int r8 = idx / Dc;
    const int tb = r8 & (Lc / 8 - 1);
    const int b = r8 / (Lc / 8);
    const int t0 = tb * 8;
    const size_t rbase = (size_t)(b * Lc + t0);

    const float w0 = cw[d * 4 + 0], w1 = cw[d * 4 + 1];
    const float w2 = cw[d * 4 + 2], w3 = cw[d * 4 + 3];
    const float bias = cb[d];

    float xm3 = 0.f, xm2 = 0.f, xm1 = 0.f;
    if (t0 >= 3) {
        xm3 = __bfloat162float(xz16[(rbase - 3) * TWO_D + d]);
        xm2 = __bfloat162float(xz16[(rbase - 2) * TWO_D + d]);
        xm1 = __bfloat162float(xz16[(rbase - 1) * TWO_D + d]);
    }
    #pragma unroll
    for (int tt = 0; tt < 8; ++tt) {
        const float x0 = __bfloat162float(xz16[(rbase + tt) * TWO_D + d]);
        const float acc = fmaf(w3, x0, fmaf(w2, xm1, fmaf(w1, xm2, fmaf(w0, xm3, bias))));
        xsb[(rbase + tt) * Dc + d] = __float2bfloat16(siluf(acc));
        xm3 = xm2; xm2 = xm1; xm1 = x0;
    }
}

// ---------------- chunked scan (R15-passing versions; z read bf16 in scanC) ----------------
__global__ __launch_bounds__(256)
void scanA(const float* __restrict__ dtb, const __hip_bfloat16* __restrict__ xsb,
           const float* __restrict__ bc, const float* __restrict__ Abuf,
           const float* __restrict__ bdt,
           float* __restrict__ S, float* __restrict__ dcend)
{
    const int blk = blockIdx.x;
    const int dblk = blk % 3, ch = (blk / 3) % NCH, b = blk / (3 * NCH);
    const int d = dblk * 256 + threadIdx.x;
    const int t0 = ch * TCH;

    __shared__ float bcs[TCH * 32];
    {
        const int row = threadIdx.x >> 3, c4 = (threadIdx.x & 7) * 4;
        *(float4*)&bcs[row * 32 + c4] =
            *(const float4*)(bc + ((size_t)(b * Lc + t0) + row) * 32 + c4);
    }
    __syncthreads();

    float A[16];
    #pragma unroll
    for (int q = 0; q < 4; ++q)
        *(float4*)&A[q * 4] = *(const float4*)(Abuf + d * 16 + q * 4);
    const float bd = bdt[d];

    float s[16];
    #pragma unroll
    for (int n = 0; n < 16; ++n) s[n] = 0.f;

    const size_t base = ((size_t)(b * Lc + t0)) * Dc + d;
    float dc = 0.f;
    #pragma unroll 2
    for (int t = 0; t < TCH; ++t) {
        const float dt = softplusf(dtb[base + (size_t)t * Dc] + bd);
        const float x  = __bfloat162float(xsb[base + (size_t)t * Dc]);
        dc += dt;
        #pragma unroll
        for (int n = 0; n < 16; ++n) {
            const float dA = fexp2(dt * A[n]);
            s[n] = fmaf(s[n], dA, bcs[t * 32 + n] * x);
        }
    }
    const size_t g = (size_t)(b * NCH + ch) * Dc + d;
    #pragma unroll
    for (int n = 0; n < 16; ++n) S[g * 16 + n] = s[n];
    dcend[g] = dc;
}

__global__ __launch_bounds__(256)
void scanB(float* __restrict__ S_io, const float* __restrict__ dcend,
           const float* __restrict__ Abuf)
{
    const int tid = blockIdx.x * 256 + threadIdx.x;
    const int n = tid & 15;
    const int d = (tid >> 4) % Dc;
    const int b = tid / (16 * Dc);
    const float An = Abuf[d * 16 + n];
    float s = 0.f;
    for (int ch = 0; ch < NCH; ++ch) {
        const size_t g = (size_t)(b * NCH + ch) * Dc + d;
        const float sv = S_io[g * 16 + n];
        const float p  = fexp2(dcend[g] * An);
        S_io[g * 16 + n] = s;
        s = fmaf(s, p, sv);
    }
}

__global__ __launch_bounds__(256)
void scanC(const float* __restrict__ dtb, const __hip_bfloat16* __restrict__ xsb,
           const __hip_bfloat16* __restrict__ xz16, const float* __restrict__ bc,
           const float* __restrict__ Abuf, const float* __restrict__ bdt,
           const float* __restrict__ Ibuf, const float* __restrict__ Dvec,
           __hip_bfloat16* __restrict__ ybf)
{
    const int blk = blockIdx.x;
    const int dblk = blk % 3, ch = (blk / 3) % NCH, b = blk / (3 * NCH);
    const int d = dblk * 256 + threadIdx.x;
    const int t0 = ch * TCH;

    __shared__ float bcs[TCH * 32];
    {
        const int row = threadIdx.x >> 3, c4 = (threadIdx.x & 7) * 4;
        *(float4*)&bcs[row * 32 + c4] =
            *(const float4*)(bc + ((size_t)(b * Lc + t0) + row) * 32 + c4);
    }
    __syncthreads();

    float A[16], s[16];
    #pragma unroll
    for (int q = 0; q < 4; ++q)
        *(float4*)&A[q * 4] = *(const float4*)(Abuf + d * 16 + q * 4);
    const size_t g = (size_t)(b * NCH + ch) * Dc + d;
    #pragma unroll
    for (int q = 0; q < 4; ++q)
        *(float4*)&s[q * 4] = *(const float4*)(Ibuf + g * 16 + q * 4);
    const float bd = bdt[d];
    const float Dd = Dvec[d];

    const size_t base = ((size_t)(b * Lc + t0)) * Dc + d;
    const size_t zbase = ((size_t)(b * Lc + t0)) * TWO_D + Dc + d;
    #pragma unroll 2
    for (int t = 0; t < TCH; ++t) {
        const float dt = softplusf(dtb[base + (size_t)t * Dc] + bd);
        const float x  = __bfloat162float(xsb[base + (size_t)t * Dc]);
        const float z  = __bfloat162float(xz16[zbase + (size_t)t * TWO_D]);
        float yl = fmaf(Dd, x, 0.f);
        #pragma unroll
        for (int n = 0; n < 16; ++n) {
            const float dA = fexp2(dt * A[n]);
            s[n] = fmaf(s[n], dA, bcs[t * 32 + n] * x);
            yl = fmaf(s[n], bcs[t * 32 + 16 + n], yl);
        }
        ybf[base + (size_t)t * Dc] = __float2bfloat16(yl * siluf(z));
    }
}

extern "C" void kernel_launch(void* const* d_in, const int* in_sizes, int n_in,
                              void* d_out, int out_size, void* d_ws, size_t ws_size,
                              hipStream_t stream)
{
    const float* x      = (const float*)d_in[0];
    const float* state  = (const float*)d_in[1];
    const float* W_in   = (const float*)d_in[2];
    const float* conv_w = (const float*)d_in[3];
    const float* conv_b = (const float*)d_in[4];
    const float* W_x    = (const float*)d_in[5];
    const float* W_dt   = (const float*)d_in[6];
    const float* b_dt   = (const float*)d_in[7];
    const float* A_log  = (const float*)d_in[8];
    const float* Dvec   = (const float*)d_in[9];
    const float* W_out  = (const float*)d_in[10];
    float* out = (float*)d_out;

    // ---- workspace (~185 MB <= 253.75 verified) ----
    char* wsb = (char*)d_ws;
    __hip_bfloat16* xz16 = (__hip_bfloat16*)wsb;     wsb += (size_t)M_TOT * TWO_D * 2;  // [xc|z] bf16
    float* dtb   = (float*)wsb;                      wsb += (size_t)M_TOT * Dc * 4;     // dtraw
    float* bc    = (float*)wsb;                      wsb += (size_t)M_TOT * 32 * 4;
    float* Sb    = (float*)wsb;                      wsb += (size_t)Bc * NCH * Dc * Nc * 4;
    float* dcend = (float*)wsb;                      wsb += (size_t)Bc * NCH * Dc * 4;
    __hip_bfloat16* xb  = (__hip_bfloat16*)wsb;      wsb += (size_t)M_TOT * Dc * 2;  // bf16(x); ybf aliases
    __hip_bfloat16* xsb = (__hip_bfloat16*)wsb;      wsb += (size_t)M_TOT * Dc * 2;
    float* Abuf = (float*)wsb;                       wsb += (size_t)Dc * Nc * 4;
    __hip_bfloat16* WinT  = (__hip_bfloat16*)wsb;    wsb += (size_t)1536 * Kd * 2;
    __hip_bfloat16* WdtT  = (__hip_bfloat16*)wsb;    wsb += (size_t)768 * Kd * 2;
    __hip_bfloat16* WoutT = (__hip_bfloat16*)wsb;    wsb += (size_t)768 * Kd * 2;
    __hip_bfloat16* WxT   = (__hip_bfloat16*)wsb;    wsb += (size_t)32 * Kd * 2;
    float* Ib = Sb;                               // scanB in-place (verified)
    __hip_bfloat16* ybf = xb;                     // xb dead after in_proj

    // ---- prep (no memset; no templates anywhere) ----
    to_bf16_kernel<<<(M_TOT * Dc / 4 + 255) / 256, 256, 0, stream>>>(x, xb, M_TOT * Dc / 4);
    wtrans_kernel<<<(1536 * Kd + 255) / 256, 256, 0, stream>>>(W_in, WinT, 1536);
    wtrans_kernel<<<(768 * Kd + 255) / 256, 256, 0, stream>>>(W_dt, WdtT, 768);
    wtrans_kernel<<<(768 * Kd + 255) / 256, 256, 0, stream>>>(W_out, WoutT, 768);
    wtrans_kernel<<<(32 * Kd + 255) / 256, 256, 0, stream>>>(W_x, WxT, 32);
    aprep_kernel<<<(Dc * Nc + 255) / 256, 256, 0, stream>>>(A_log, Abuf);

    // 1) in_proj fused N=1536, bf16 out (standalone kernel)
    gemm_bf16_b16<<<dim3(TWO_D / 128, M_TOT / 128), 256, 0, stream>>>(
        xb, WinT, TWO_D, xz16);
    // 2) t-blocked conv + silu (bf16 in) -> bf16 xsb
    conv_silu_kernel<<<((M_TOT / 8) * Dc + 255) / 256, 256, 0, stream>>>(
        xz16, conv_w, conv_b, xsb);
    // 3) dtraw = xsb @ W_dt  (N=768, fp32 out)
    gemm_bf16_f32<<<dim3(Dc / 128, M_TOT / 128), 256, 0, stream>>>(xsb, WdtT, Dc, dtb);
    // 4) BC = xsb @ W_x
    bc_mfma<<<M_TOT / 64, 256, 0, stream>>>(xsb, WxT, bc);
    // 5) scan
    scanA<<<Bc * NCH * 3, 256, 0, stream>>>(dtb, xsb, bc, Abuf, b_dt, Sb, dcend);
    scanB<<<(Bc * Dc * Nc) / 256, 256, 0, stream>>>(Sb, dcend, Abuf);
    scanC<<<Bc * NCH * 3, 256, 0, stream>>>(dtb, xsb, xz16, bc, Abuf, b_dt, Ib, Dvec, ybf);
    // 6) out = y @ W_out  (N=768, fp32 out)
    gemm_bf16_f32<<<dim3(Dc / 128, M_TOT / 128), 256, 0, stream>>>(ybf, WoutT, Dc, out);
    // 7) state pass-through
    hipMemcpyAsync(out + (size_t)M_TOT * Dc, state,
                   (size_t)(Bc * Dc * Nc) * sizeof(float),
                   hipMemcpyDeviceToDevice, stream);
}

// Round 18
// 287.783 us; speedup vs baseline: 7.4209x; 1.0575x over previous
//
#include <hip/hip_runtime.h>
#include <hip/hip_bf16.h>
#include <cstdint>
#include <cstddef>

constexpr int Bc = 4, Lc = 4096, Dc = 768, Nc = 16;
constexpr int M_TOT = Bc * Lc;     // 16384
constexpr int NCH = 128;           // chunks per sequence
constexpr int TCH = Lc / NCH;      // 32
constexpr int Kd = 768;            // K of all GEMMs
constexpr int TWO_D = 1536;

typedef __attribute__((ext_vector_type(8))) short short8v;   // 8 bf16 (4 VGPRs)
typedef __attribute__((ext_vector_type(4))) float f32x4;     // MFMA acc

__device__ __forceinline__ float fexp2(float x) {
#if __has_builtin(__builtin_amdgcn_exp2f)
    return __builtin_amdgcn_exp2f(x);
#else
    return exp2f(x);
#endif
}
__device__ __forceinline__ float softplusf(float x) {
    return (x > 20.0f) ? x : __logf(1.0f + __expf(x));
}
__device__ __forceinline__ float siluf(float x) {
    return x / (1.0f + __expf(-x));
}

// XCD-aware tile swizzle (T1, m157 formula; requires nwg % 8 == 0 — grids are
// 1536 and 768). Consecutive swizzled tiles land on the SAME XCD so A-panel
// reuse hits that XCD's private L2 instead of re-fetching from HBM.
__device__ __forceinline__ void swizzled_tile(int& row0, int& col0)
{
    const int nwg = gridDim.x * gridDim.y;
    const int bid = blockIdx.y * gridDim.x + blockIdx.x;
    const int swz = (bid & 7) * (nwg >> 3) + (bid >> 3);
    row0 = (swz / gridDim.x) * 128;
    col0 = (swz % gridDim.x) * 128;
}

// ---------- bf16 MFMA GEMM, fp32 out (round-11 HW-verified core + T1 swizzle) ----------
__global__ __launch_bounds__(256)
void gemm_bf16_f32(const __hip_bfloat16* __restrict__ Ab,
                   const __hip_bfloat16* __restrict__ Wt,
                   int N, float* __restrict__ out0)
{
    __shared__ __hip_bfloat16 Asm[128 * 32];
    __shared__ __hip_bfloat16 Bsm[128 * 32];
    const int tid = threadIdx.x;
    const int w = tid >> 6, lane = tid & 63;
    const int lr = lane & 15, lc = lane >> 4;
    int row0, col0;
    swizzled_tile(row0, col0);
    const int wrow = (w >> 1) * 64, wcol = (w & 1) * 64;

    const int srow = lane >> 2;
    const int scol = (lane & 3) * 8;

    f32x4 acc[4][4] = {};

    const int KT = Kd / 32;
    for (int kt = 0; kt < KT; ++kt) {
        if (kt) __syncthreads();
        #pragma unroll
        for (int i = 0; i < 2; ++i) {
            const int seg = w * 2 + i;
            const __hip_bfloat16* asrc =
                Ab + (size_t)(row0 + seg * 16 + srow) * Kd + kt * 32 + scol;
            const __hip_bfloat16* bsrc =
                Wt + (size_t)(col0 + seg * 16 + srow) * Kd + kt * 32 + scol;
            __builtin_amdgcn_global_load_lds(
                (const __attribute__((address_space(1))) void*)asrc,
                (__attribute__((address_space(3))) void*)(Asm + seg * 512), 16, 0, 0);
            __builtin_amdgcn_global_load_lds(
                (const __attribute__((address_space(1))) void*)bsrc,
                (__attribute__((address_space(3))) void*)(Bsm + seg * 512), 16, 0, 0);
        }
        asm volatile("s_waitcnt vmcnt(0)" ::: "memory");
        __syncthreads();

        short8v a[4], b[4];
        #pragma unroll
        for (int m = 0; m < 4; ++m)
            a[m] = *(const short8v*)((char*)Asm + (wrow + m * 16 + lr) * 64 + lc * 16);
        #pragma unroll
        for (int nf = 0; nf < 4; ++nf)
            b[nf] = *(const short8v*)((char*)Bsm + (wcol + nf * 16 + lr) * 64 + lc * 16);
        #pragma unroll
        for (int m = 0; m < 4; ++m)
            #pragma unroll
            for (int nf = 0; nf < 4; ++nf)
                acc[m][nf] = __builtin_amdgcn_mfma_f32_16x16x32_bf16(
                    a[m], b[nf], acc[m][nf], 0, 0, 0);
    }

    #pragma unroll
    for (int m = 0; m < 4; ++m)
        #pragma unroll
        for (int nf = 0; nf < 4; ++nf)
            #pragma unroll
            for (int j = 0; j < 4; ++j) {
                const int rg = row0 + wrow + m * 16 + lc * 4 + j;
                const int cg = col0 + wcol + nf * 16 + lr;
                out0[(size_t)rg * N + cg] = acc[m][nf][j];
            }
}

// ---------- bf16 MFMA GEMM, bf16 out (standalone, + T1 swizzle) ----------
__global__ __launch_bounds__(256)
void gemm_bf16_b16(const __hip_bfloat16* __restrict__ Ab,
                   const __hip_bfloat16* __restrict__ Wt,
                   int N, __hip_bfloat16* __restrict__ outb)
{
    __shared__ __hip_bfloat16 Asm[128 * 32];
    __shared__ __hip_bfloat16 Bsm[128 * 32];
    const int tid = threadIdx.x;
    const int w = tid >> 6, lane = tid & 63;
    const int lr = lane & 15, lc = lane >> 4;
    int row0, col0;
    swizzled_tile(row0, col0);
    const int wrow = (w >> 1) * 64, wcol = (w & 1) * 64;

    const int srow = lane >> 2;
    const int scol = (lane & 3) * 8;

    f32x4 acc[4][4] = {};

    const int KT = Kd / 32;
    for (int kt = 0; kt < KT; ++kt) {
        if (kt) __syncthreads();
        #pragma unroll
        for (int i = 0; i < 2; ++i) {
            const int seg = w * 2 + i;
            const __hip_bfloat16* asrc =
                Ab + (size_t)(row0 + seg * 16 + srow) * Kd + kt * 32 + scol;
            const __hip_bfloat16* bsrc =
                Wt + (size_t)(col0 + seg * 16 + srow) * Kd + kt * 32 + scol;
            __builtin_amdgcn_global_load_lds(
                (const __attribute__((address_space(1))) void*)asrc,
                (__attribute__((address_space(3))) void*)(Asm + seg * 512), 16, 0, 0);
            __builtin_amdgcn_global_load_lds(
                (const __attribute__((address_space(1))) void*)bsrc,
                (__attribute__((address_space(3))) void*)(Bsm + seg * 512), 16, 0, 0);
        }
        asm volatile("s_waitcnt vmcnt(0)" ::: "memory");
        __syncthreads();

        short8v a[4], b[4];
        #pragma unroll
        for (int m = 0; m < 4; ++m)
            a[m] = *(const short8v*)((char*)Asm + (wrow + m * 16 + lr) * 64 + lc * 16);
        #pragma unroll
        for (int nf = 0; nf < 4; ++nf)
            b[nf] = *(const short8v*)((char*)Bsm + (wcol + nf * 16 + lr) * 64 + lc * 16);
        #pragma unroll
        for (int m = 0; m < 4; ++m)
            #pragma unroll
            for (int nf = 0; nf < 4; ++nf)
                acc[m][nf] = __builtin_amdgcn_mfma_f32_16x16x32_bf16(
                    a[m], b[nf], acc[m][nf], 0, 0, 0);
    }

    #pragma unroll
    for (int m = 0; m < 4; ++m)
        #pragma unroll
        for (int nf = 0; nf < 4; ++nf)
            #pragma unroll
            for (int j = 0; j < 4; ++j) {
                const int rg = row0 + wrow + m * 16 + lc * 4 + j;
                const int cg = col0 + wcol + nf * 16 + lr;
                outb[(size_t)rg * N + cg] = __float2bfloat16(acc[m][nf][j]);
            }
}

// ---------- skinny BC GEMM via MFMA (round-13 HW-verified, verbatim) ----------
__global__ __launch_bounds__(256)
void bc_mfma(const __hip_bfloat16* __restrict__ xsb,
             const __hip_bfloat16* __restrict__ WxT,
             float* __restrict__ BC)
{
    const int w = threadIdx.x >> 6, lane = threadIdx.x & 63;
    const int lr = lane & 15, lc = lane >> 4;
    const int row0 = blockIdx.x * 64 + w * 16;

    f32x4 acc0 = {}, acc1 = {};
    const __hip_bfloat16* ap = xsb + (size_t)(row0 + lr) * Kd + lc * 8;
    const __hip_bfloat16* b0p = WxT + (size_t)lr * Kd + lc * 8;
    const __hip_bfloat16* b1p = WxT + (size_t)(16 + lr) * Kd + lc * 8;
    #pragma unroll 4
    for (int kt = 0; kt < Kd / 32; ++kt) {
        const short8v a  = *(const short8v*)(ap  + kt * 32);
        const short8v b0 = *(const short8v*)(b0p + kt * 32);
        const short8v b1 = *(const short8v*)(b1p + kt * 32);
        acc0 = __builtin_amdgcn_mfma_f32_16x16x32_bf16(a, b0, acc0, 0, 0, 0);
        acc1 = __builtin_amdgcn_mfma_f32_16x16x32_bf16(a, b1, acc1, 0, 0, 0);
    }
    #pragma unroll
    for (int j = 0; j < 4; ++j) {
        const size_t r = (size_t)(row0 + lc * 4 + j) * 32;
        BC[r + lr]      = acc0[j];
        BC[r + 16 + lr] = acc1[j];
    }
}

// ---------------- prep kernels (HW-verified) ----------------
__global__ __launch_bounds__(256)
void to_bf16_kernel(const float* __restrict__ src, __hip_bfloat16* __restrict__ dst, int n4)
{
    const int i = blockIdx.x * 256 + threadIdx.x;
    if (i >= n4) return;
    const float4 v = ((const float4*)src)[i];
    dst[i * 4 + 0] = __float2bfloat16(v.x);
    dst[i * 4 + 1] = __float2bfloat16(v.y);
    dst[i * 4 + 2] = __float2bfloat16(v.z);
    dst[i * 4 + 3] = __float2bfloat16(v.w);
}

__global__ __launch_bounds__(256)
void wtrans_kernel(const float* __restrict__ src, __hip_bfloat16* __restrict__ dst, int N)
{
    const int idx = blockIdx.x * 256 + threadIdx.x;
    if (idx >= N * Kd) return;
    const int n = idx / Kd, k = idx % Kd;
    dst[idx] = __float2bfloat16(src[(size_t)k * N + n]);
}

// A2[d][n] = -exp(A_log[d][n]) * log2(e)
__global__ __launch_bounds__(256)
void aprep_kernel(const float* __restrict__ A_log, float* __restrict__ Abuf)
{
    const int i = blockIdx.x * 256 + threadIdx.x;
    if (i < Dc * Nc) Abuf[i] = -expf(A_log[i]) * 1.4426950408889634f;
}

// ---------------- t-blocked conv + silu (bf16 in, bf16 out) ----------------
__global__ __launch_bounds__(256)
void conv_silu_kernel(const __hip_bfloat16* __restrict__ xz16, const float* __restrict__ cw,
                      const float* __restrict__ cb, __hip_bfloat16* __restrict__ xsb)
{
    const int idx = blockIdx.x * 256 + threadIdx.x;   // (b, tblk, d), d fastest
    if (idx >= (M_TOT / 8) * Dc) return;
    const int d = idx % Dc;
    const int r8 = idx / Dc;
    const int tb = r8 & (Lc / 8 - 1);
    const int b = r8 / (Lc / 8);
    const int t0 = tb * 8;
    const size_t rbase = (size_t)(b * Lc + t0);

    const float w0 = cw[d * 4 + 0], w1 = cw[d * 4 + 1];
    const float w2 = cw[d * 4 + 2], w3 = cw[d * 4 + 3];
    const float bias = cb[d];

    float xm3 = 0.f, xm2 = 0.f, xm1 = 0.f;
    if (t0 >= 3) {
        xm3 = __bfloat162float(xz16[(rbase - 3) * TWO_D + d]);
        xm2 = __bfloat162float(xz16[(rbase - 2) * TWO_D + d]);
        xm1 = __bfloat162float(xz16[(rbase - 1) * TWO_D + d]);
    }
    #pragma unroll
    for (int tt = 0; tt < 8; ++tt) {
        const float x0 = __bfloat162float(xz16[(rbase + tt) * TWO_D + d]);
        const float acc = fmaf(w3, x0, fmaf(w2, xm1, fmaf(w1, xm2, fmaf(w0, xm3, bias))));
        xsb[(rbase + tt) * Dc + d] = __float2bfloat16(siluf(acc));
        xm3 = xm2; xm2 = xm1; xm1 = x0;
    }
}

// ---------------- chunked scan (R17-passing versions, verbatim) ----------------
__global__ __launch_bounds__(256)
void scanA(const float* __restrict__ dtb, const __hip_bfloat16* __restrict__ xsb,
           const float* __restrict__ bc, const float* __restrict__ Abuf,
           const float* __restrict__ bdt,
           float* __restrict__ S, float* __restrict__ dcend)
{
    const int blk = blockIdx.x;
    const int dblk = blk % 3, ch = (blk / 3) % NCH, b = blk / (3 * NCH);
    const int d = dblk * 256 + threadIdx.x;
    const int t0 = ch * TCH;

    __shared__ float bcs[TCH * 32];
    {
        const int row = threadIdx.x >> 3, c4 = (threadIdx.x & 7) * 4;
        *(float4*)&bcs[row * 32 + c4] =
            *(const float4*)(bc + ((size_t)(b * Lc + t0) + row) * 32 + c4);
    }
    __syncthreads();

    float A[16];
    #pragma unroll
    for (int q = 0; q < 4; ++q)
        *(float4*)&A[q * 4] = *(const float4*)(Abuf + d * 16 + q * 4);
    const float bd = bdt[d];

    float s[16];
    #pragma unroll
    for (int n = 0; n < 16; ++n) s[n] = 0.f;

    const size_t base = ((size_t)(b * Lc + t0)) * Dc + d;
    float dc = 0.f;
    #pragma unroll 2
    for (int t = 0; t < TCH; ++t) {
        const float dt = softplusf(dtb[base + (size_t)t * Dc] + bd);
        const float x  = __bfloat162float(xsb[base + (size_t)t * Dc]);
        dc += dt;
        #pragma unroll
        for (int n = 0; n < 16; ++n) {
            const float dA = fexp2(dt * A[n]);
            s[n] = fmaf(s[n], dA, bcs[t * 32 + n] * x);
        }
    }
    const size_t g = (size_t)(b * NCH + ch) * Dc + d;
    #pragma unroll
    for (int n = 0; n < 16; ++n) S[g * 16 + n] = s[n];
    dcend[g] = dc;
}

__global__ __launch_bounds__(256)
void scanB(float* __restrict__ S_io, const float* __restrict__ dcend,
           const float* __restrict__ Abuf)
{
    const int tid = blockIdx.x * 256 + threadIdx.x;
    const int n = tid & 15;
    const int d = (tid >> 4) % Dc;
    const int b = tid / (16 * Dc);
    const float An = Abuf[d * 16 + n];
    float s = 0.f;
    for (int ch = 0; ch < NCH; ++ch) {
        const size_t g = (size_t)(b * NCH + ch) * Dc + d;
        const float sv = S_io[g * 16 + n];
        const float p  = fexp2(dcend[g] * An);
        S_io[g * 16 + n] = s;
        s = fmaf(s, p, sv);
    }
}

__global__ __launch_bounds__(256)
void scanC(const float* __restrict__ dtb, const __hip_bfloat16* __restrict__ xsb,
           const __hip_bfloat16* __restrict__ xz16, const float* __restrict__ bc,
           const float* __restrict__ Abuf, const float* __restrict__ bdt,
           const float* __restrict__ Ibuf, const float* __restrict__ Dvec,
           __hip_bfloat16* __restrict__ ybf)
{
    const int blk = blockIdx.x;
    const int dblk = blk % 3, ch = (blk / 3) % NCH, b = blk / (3 * NCH);
    const int d = dblk * 256 + threadIdx.x;
    const int t0 = ch * TCH;

    __shared__ float bcs[TCH * 32];
    {
        const int row = threadIdx.x >> 3, c4 = (threadIdx.x & 7) * 4;
        *(float4*)&bcs[row * 32 + c4] =
            *(const float4*)(bc + ((size_t)(b * Lc + t0) + row) * 32 + c4);
    }
    __syncthreads();

    float A[16], s[16];
    #pragma unroll
    for (int q = 0; q < 4; ++q)
        *(float4*)&A[q * 4] = *(const float4*)(Abuf + d * 16 + q * 4);
    const size_t g = (size_t)(b * NCH + ch) * Dc + d;
    #pragma unroll
    for (int q = 0; q < 4; ++q)
        *(float4*)&s[q * 4] = *(const float4*)(Ibuf + g * 16 + q * 4);
    const float bd = bdt[d];
    const float Dd = Dvec[d];

    const size_t base = ((size_t)(b * Lc + t0)) * Dc + d;
    const size_t zbase = ((size_t)(b * Lc + t0)) * TWO_D + Dc + d;
    #pragma unroll 2
    for (int t = 0; t < TCH; ++t) {
        const float dt = softplusf(dtb[base + (size_t)t * Dc] + bd);
        const float x  = __bfloat162float(xsb[base + (size_t)t * Dc]);
        const float z  = __bfloat162float(xz16[zbase + (size_t)t * TWO_D]);
        float yl = fmaf(Dd, x, 0.f);
        #pragma unroll
        for (int n = 0; n < 16; ++n) {
            const float dA = fexp2(dt * A[n]);
            s[n] = fmaf(s[n], dA, bcs[t * 32 + n] * x);
            yl = fmaf(s[n], bcs[t * 32 + 16 + n], yl);
        }
        ybf[base + (size_t)t * Dc] = __float2bfloat16(yl * siluf(z));
    }
}

extern "C" void kernel_launch(void* const* d_in, const int* in_sizes, int n_in,
                              void* d_out, int out_size, void* d_ws, size_t ws_size,
                              hipStream_t stream)
{
    const float* x      = (const float*)d_in[0];
    const float* state  = (const float*)d_in[1];
    const float* W_in   = (const float*)d_in[2];
    const float* conv_w = (const float*)d_in[3];
    const float* conv_b = (const float*)d_in[4];
    const float* W_x    = (const float*)d_in[5];
    const float* W_dt   = (const float*)d_in[6];
    const float* b_dt   = (const float*)d_in[7];
    const float* A_log  = (const float*)d_in[8];
    const float* Dvec   = (const float*)d_in[9];
    const float* W_out  = (const float*)d_in[10];
    float* out = (float*)d_out;

    // ---- workspace (~185 MB <= 253.75 verified; R17 layout verbatim) ----
    char* wsb = (char*)d_ws;
    __hip_bfloat16* xz16 = (__hip_bfloat16*)wsb;     wsb += (size_t)M_TOT * TWO_D * 2;
    float* dtb   = (float*)wsb;                      wsb += (size_t)M_TOT * Dc * 4;
    float* bc    = (float*)wsb;                      wsb += (size_t)M_TOT * 32 * 4;
    float* Sb    = (float*)wsb;                      wsb += (size_t)Bc * NCH * Dc * Nc * 4;
    float* dcend = (float*)wsb;                      wsb += (size_t)Bc * NCH * Dc * 4;
    __hip_bfloat16* xb  = (__hip_bfloat16*)wsb;      wsb += (size_t)M_TOT * Dc * 2;
    __hip_bfloat16* xsb = (__hip_bfloat16*)wsb;      wsb += (size_t)M_TOT * Dc * 2;
    float* Abuf = (float*)wsb;                       wsb += (size_t)Dc * Nc * 4;
    __hip_bfloat16* WinT  = (__hip_bfloat16*)wsb;    wsb += (size_t)1536 * Kd * 2;
    __hip_bfloat16* WdtT  = (__hip_bfloat16*)wsb;    wsb += (size_t)768 * Kd * 2;
    __hip_bfloat16* WoutT = (__hip_bfloat16*)wsb;    wsb += (size_t)768 * Kd * 2;
    __hip_bfloat16* WxT   = (__hip_bfloat16*)wsb;    wsb += (size_t)32 * Kd * 2;
    float* Ib = Sb;                               // scanB in-place (verified)
    __hip_bfloat16* ybf = xb;                     // xb dead after in_proj

    // ---- prep (no memset; no templates) ----
    to_bf16_kernel<<<(M_TOT * Dc / 4 + 255) / 256, 256, 0, stream>>>(x, xb, M_TOT * Dc / 4);
    wtrans_kernel<<<(1536 * Kd + 255) / 256, 256, 0, stream>>>(W_in, WinT, 1536);
    wtrans_kernel<<<(768 * Kd + 255) / 256, 256, 0, stream>>>(W_dt, WdtT, 768);
    wtrans_kernel<<<(768 * Kd + 255) / 256, 256, 0, stream>>>(W_out, WoutT, 768);
    wtrans_kernel<<<(32 * Kd + 255) / 256, 256, 0, stream>>>(W_x, WxT, 32);
    aprep_kernel<<<(Dc * Nc + 255) / 256, 256, 0, stream>>>(A_log, Abuf);

    // 1) in_proj fused N=1536, bf16 out (+T1 swizzle)
    gemm_bf16_b16<<<dim3(TWO_D / 128, M_TOT / 128), 256, 0, stream>>>(
        xb, WinT, TWO_D, xz16);
    // 2) t-blocked conv + silu (bf16 in) -> bf16 xsb
    conv_silu_kernel<<<((M_TOT / 8) * Dc + 255) / 256, 256, 0, stream>>>(
        xz16, conv_w, conv_b, xsb);
    // 3) dtraw = xsb @ W_dt  (N=768, fp32 out, +T1 swizzle)
    gemm_bf16_f32<<<dim3(Dc / 128, M_TOT / 128), 256, 0, stream>>>(xsb, WdtT, Dc, dtb);
    // 4) BC = xsb @ W_x
    bc_mfma<<<M_TOT / 64, 256, 0, stream>>>(xsb, WxT, bc);
    // 5) scan
    scanA<<<Bc * NCH * 3, 256, 0, stream>>>(dtb, xsb, bc, Abuf, b_dt, Sb, dcend);
    scanB<<<(Bc * Dc * Nc) / 256, 256, 0, stream>>>(Sb, dcend, Abuf);
    scanC<<<Bc * NCH * 3, 256, 0, stream>>>(dtb, xsb, xz16, bc, Abuf, b_dt, Ib, Dvec, ybf);
    // 6) out = y @ W_out  (N=768, fp32 out, +T1 swizzle)
    gemm_bf16_f32<<<dim3(Dc / 128, M_TOT / 128), 256, 0, stream>>>(ybf, WoutT, Dc, out);
    // 7) state pass-through
    hipMemcpyAsync(out + (size_t)M_TOT * Dc, state,
                   (size_t)(Bc * Dc * Nc) * sizeof(float),
                   hipMemcpyDeviceToDevice, stream);
}

// Round 19
// 278.568 us; speedup vs baseline: 7.6663x; 1.0331x over previous
//
#include <hip/hip_runtime.h>
#include <hip/hip_bf16.h>
#include <cstdint>
#include <cstddef>

constexpr int Bc = 4, Lc = 4096, Dc = 768, Nc = 16;
constexpr int M_TOT = Bc * Lc;     // 16384
constexpr int NCH = 128;           // chunks per sequence
constexpr int TCH = Lc / NCH;      // 32
constexpr int Kd = 768;            // K of all GEMMs
constexpr int TWO_D = 1536;
constexpr int NDTBC = 896;         // fused [dt | B,C | pad] width (7*128)

typedef __attribute__((ext_vector_type(8))) short short8v;   // 8 bf16 (4 VGPRs)
typedef __attribute__((ext_vector_type(4))) float f32x4;     // MFMA acc

__device__ __forceinline__ float fexp2(float x) {
#if __has_builtin(__builtin_amdgcn_exp2f)
    return __builtin_amdgcn_exp2f(x);
#else
    return exp2f(x);
#endif
}
__device__ __forceinline__ float softplusf(float x) {
    return (x > 20.0f) ? x : __logf(1.0f + __expf(x));
}
__device__ __forceinline__ float siluf(float x) {
    return x / (1.0f + __expf(-x));
}

// XCD-aware tile swizzle (T1; requires nwg % 8 == 0 — grids are 1536, 896, 768).
__device__ __forceinline__ void swizzled_tile(int& row0, int& col0)
{
    const int nwg = gridDim.x * gridDim.y;
    const int bid = blockIdx.y * gridDim.x + blockIdx.x;
    const int swz = (bid & 7) * (nwg >> 3) + (bid >> 3);
    row0 = (swz / gridDim.x) * 128;
    col0 = (swz % gridDim.x) * 128;
}

// ---------- bf16 MFMA GEMM, fp32 out (HW-verified core + T1; NON-TEMPLATE) ----------
__global__ __launch_bounds__(256)
void gemm_bf16_f32(const __hip_bfloat16* __restrict__ Ab,
                   const __hip_bfloat16* __restrict__ Wt,
                   int N, float* __restrict__ out0)
{
    __shared__ __hip_bfloat16 Asm[128 * 32];
    __shared__ __hip_bfloat16 Bsm[128 * 32];
    const int tid = threadIdx.x;
    const int w = tid >> 6, lane = tid & 63;
    const int lr = lane & 15, lc = lane >> 4;
    int row0, col0;
    swizzled_tile(row0, col0);
    const int wrow = (w >> 1) * 64, wcol = (w & 1) * 64;

    const int srow = lane >> 2;
    const int scol = (lane & 3) * 8;

    f32x4 acc[4][4] = {};

    const int KT = Kd / 32;
    for (int kt = 0; kt < KT; ++kt) {
        if (kt) __syncthreads();
        #pragma unroll
        for (int i = 0; i < 2; ++i) {
            const int seg = w * 2 + i;
            const __hip_bfloat16* asrc =
                Ab + (size_t)(row0 + seg * 16 + srow) * Kd + kt * 32 + scol;
            const __hip_bfloat16* bsrc =
                Wt + (size_t)(col0 + seg * 16 + srow) * Kd + kt * 32 + scol;
            __builtin_amdgcn_global_load_lds(
                (const __attribute__((address_space(1))) void*)asrc,
                (__attribute__((address_space(3))) void*)(Asm + seg * 512), 16, 0, 0);
            __builtin_amdgcn_global_load_lds(
                (const __attribute__((address_space(1))) void*)bsrc,
                (__attribute__((address_space(3))) void*)(Bsm + seg * 512), 16, 0, 0);
        }
        asm volatile("s_waitcnt vmcnt(0)" ::: "memory");
        __syncthreads();

        short8v a[4], b[4];
        #pragma unroll
        for (int m = 0; m < 4; ++m)
            a[m] = *(const short8v*)((char*)Asm + (wrow + m * 16 + lr) * 64 + lc * 16);
        #pragma unroll
        for (int nf = 0; nf < 4; ++nf)
            b[nf] = *(const short8v*)((char*)Bsm + (wcol + nf * 16 + lr) * 64 + lc * 16);
        #pragma unroll
        for (int m = 0; m < 4; ++m)
            #pragma unroll
            for (int nf = 0; nf < 4; ++nf)
                acc[m][nf] = __builtin_amdgcn_mfma_f32_16x16x32_bf16(
                    a[m], b[nf], acc[m][nf], 0, 0, 0);
    }

    #pragma unroll
    for (int m = 0; m < 4; ++m)
        #pragma unroll
        for (int nf = 0; nf < 4; ++nf)
            #pragma unroll
            for (int j = 0; j < 4; ++j) {
                const int rg = row0 + wrow + m * 16 + lc * 4 + j;
                const int cg = col0 + wcol + nf * 16 + lr;
                out0[(size_t)rg * N + cg] = acc[m][nf][j];
            }
}

// ---------- bf16 MFMA GEMM, bf16 out (standalone, + T1) ----------
__global__ __launch_bounds__(256)
void gemm_bf16_b16(const __hip_bfloat16* __restrict__ Ab,
                   const __hip_bfloat16* __restrict__ Wt,
                   int N, __hip_bfloat16* __restrict__ outb)
{
    __shared__ __hip_bfloat16 Asm[128 * 32];
    __shared__ __hip_bfloat16 Bsm[128 * 32];
    const int tid = threadIdx.x;
    const int w = tid >> 6, lane = tid & 63;
    const int lr = lane & 15, lc = lane >> 4;
    int row0, col0;
    swizzled_tile(row0, col0);
    const int wrow = (w >> 1) * 64, wcol = (w & 1) * 64;

    const int srow = lane >> 2;
    const int scol = (lane & 3) * 8;

    f32x4 acc[4][4] = {};

    const int KT = Kd / 32;
    for (int kt = 0; kt < KT; ++kt) {
        if (kt) __syncthreads();
        #pragma unroll
        for (int i = 0; i < 2; ++i) {
            const int seg = w * 2 + i;
            const __hip_bfloat16* asrc =
                Ab + (size_t)(row0 + seg * 16 + srow) * Kd + kt * 32 + scol;
            const __hip_bfloat16* bsrc =
                Wt + (size_t)(col0 + seg * 16 + srow) * Kd + kt * 32 + scol;
            __builtin_amdgcn_global_load_lds(
                (const __attribute__((address_space(1))) void*)asrc,
                (__attribute__((address_space(3))) void*)(Asm + seg * 512), 16, 0, 0);
            __builtin_amdgcn_global_load_lds(
                (const __attribute__((address_space(1))) void*)bsrc,
                (__attribute__((address_space(3))) void*)(Bsm + seg * 512), 16, 0, 0);
        }
        asm volatile("s_waitcnt vmcnt(0)" ::: "memory");
        __syncthreads();

        short8v a[4], b[4];
        #pragma unroll
        for (int m = 0; m < 4; ++m)
            a[m] = *(const short8v*)((char*)Asm + (wrow + m * 16 + lr) * 64 + lc * 16);
        #pragma unroll
        for (int nf = 0; nf < 4; ++nf)
            b[nf] = *(const short8v*)((char*)Bsm + (wcol + nf * 16 + lr) * 64 + lc * 16);
        #pragma unroll
        for (int m = 0; m < 4; ++m)
            #pragma unroll
            for (int nf = 0; nf < 4; ++nf)
                acc[m][nf] = __builtin_amdgcn_mfma_f32_16x16x32_bf16(
                    a[m], b[nf], acc[m][nf], 0, 0, 0);
    }

    #pragma unroll
    for (int m = 0; m < 4; ++m)
        #pragma unroll
        for (int nf = 0; nf < 4; ++nf)
            #pragma unroll
            for (int j = 0; j < 4; ++j) {
                const int rg = row0 + wrow + m * 16 + lc * 4 + j;
                const int cg = col0 + wcol + nf * 16 + lr;
                outb[(size_t)rg * N + cg] = __float2bfloat16(acc[m][nf][j]);
            }
}

// ---------------- prep kernels ----------------
__global__ __launch_bounds__(256)
void to_bf16_kernel(const float* __restrict__ src, __hip_bfloat16* __restrict__ dst, int n4)
{
    const int i = blockIdx.x * 256 + threadIdx.x;
    if (i >= n4) return;
    const float4 v = ((const float4*)src)[i];
    dst[i * 4 + 0] = __float2bfloat16(v.x);
    dst[i * 4 + 1] = __float2bfloat16(v.y);
    dst[i * 4 + 2] = __float2bfloat16(v.z);
    dst[i * 4 + 3] = __float2bfloat16(v.w);
}

// LDS-tiled transpose+convert: src[Kd][N] fp32 -> dst[N][Kd] bf16. Coalesced both ways.
// Grid: (N/32, Kd/32); N % 32 == 0.
__global__ __launch_bounds__(256)
void wtrans_tile(const float* __restrict__ src, __hip_bfloat16* __restrict__ dst, int N)
{
    __shared__ float tile[32][33];
    const int n0 = blockIdx.x * 32, k0 = blockIdx.y * 32;
    const int tx = threadIdx.x & 31, ty = threadIdx.x >> 5;   // 8 rows x 32 cols
    #pragma unroll
    for (int r = 0; r < 4; ++r) {
        const int k = ty + r * 8;
        tile[k][tx] = src[(size_t)(k0 + k) * N + n0 + tx];    // coalesced in n
    }
    __syncthreads();
    #pragma unroll
    for (int r = 0; r < 4; ++r) {
        const int n = ty + r * 8;
        dst[(size_t)(n0 + n) * Kd + k0 + tx] = __float2bfloat16(tile[tx][n]);  // coalesced in k
    }
}

// A2[d][n] = -exp(A_log[d][n]) * log2(e)
__global__ __launch_bounds__(256)
void aprep_kernel(const float* __restrict__ A_log, float* __restrict__ Abuf)
{
    const int i = blockIdx.x * 256 + threadIdx.x;
    if (i < Dc * Nc) Abuf[i] = -expf(A_log[i]) * 1.4426950408889634f;
}

// ---------------- t-blocked conv + silu (bf16 in, bf16 out; HW-verified) ----------------
__global__ __launch_bounds__(256)
void conv_silu_kernel(const __hip_bfloat16* __restrict__ xz16, const float* __restrict__ cw,
                      const float* __restrict__ cb, __hip_bfloat16* __restrict__ xsb)
{
    const int idx = blockIdx.x * 256 + threadIdx.x;   // (b, tblk, d), d fastest
    if (idx >= (M_TOT / 8) * Dc) return;
    const int d = idx % Dc;
    const int r8 = idx / Dc;
    const int tb = r8 & (Lc / 8 - 1);
    const int b = r8 / (Lc / 8);
    const int t0 = tb * 8;
    const size_t rbase = (size_t)(b * Lc + t0);

    const float w0 = cw[d * 4 + 0], w1 = cw[d * 4 + 1];
    const float w2 = cw[d * 4 + 2], w3 = cw[d * 4 + 3];
    const float bias = cb[d];

    float xm3 = 0.f, xm2 = 0.f, xm1 = 0.f;
    if (t0 >= 3) {
        xm3 = __bfloat162float(xz16[(rbase - 3) * TWO_D + d]);
        xm2 = __bfloat162float(xz16[(rbase - 2) * TWO_D + d]);
        xm1 = __bfloat162float(xz16[(rbase - 1) * TWO_D + d]);
    }
    #pragma unroll
    for (int tt = 0; tt < 8; ++tt) {
        const float x0 = __bfloat162float(xz16[(rbase + tt) * TWO_D + d]);
        const float acc = fmaf(w3, x0, fmaf(w2, xm1, fmaf(w1, xm2, fmaf(w0, xm3, bias))));
        xsb[(rbase + tt) * Dc + d] = __float2bfloat16(siluf(acc));
        xm3 = xm2; xm2 = xm1; xm1 = x0;
    }
}

// ---------------- chunked scan (dt + B,C from fused dtbc, stride 896) ----------------
__global__ __launch_bounds__(256)
void scanA(const float* __restrict__ dtbc, const __hip_bfloat16* __restrict__ xsb,
           const float* __restrict__ Abuf, const float* __restrict__ bdt,
           float* __restrict__ S, float* __restrict__ dcend)
{
    const int blk = blockIdx.x;
    const int dblk = blk % 3, ch = (blk / 3) % NCH, b = blk / (3 * NCH);
    const int d = dblk * 256 + threadIdx.x;
    const int t0 = ch * TCH;
    const size_t brow = (size_t)(b * Lc + t0);

    __shared__ float bcs[TCH * 32];   // 4 KB (B|C) tile from dtbc cols 768..799
    {
        const int row = threadIdx.x >> 3, c4 = (threadIdx.x & 7) * 4;
        *(float4*)&bcs[row * 32 + c4] =
            *(const float4*)(dtbc + (brow + row) * NDTBC + Dc + c4);
    }
    __syncthreads();

    float A[16];
    #pragma unroll
    for (int q = 0; q < 4; ++q)
        *(float4*)&A[q * 4] = *(const float4*)(Abuf + d * 16 + q * 4);
    const float bd = bdt[d];

    float s[16];
    #pragma unroll
    for (int n = 0; n < 16; ++n) s[n] = 0.f;

    float dc = 0.f;
    #pragma unroll 2
    for (int t = 0; t < TCH; ++t) {
        const float dt = softplusf(dtbc[(brow + t) * NDTBC + d] + bd);
        const float x  = __bfloat162float(xsb[(brow + t) * Dc + d]);
        dc += dt;
        float Bt[16], Ct[16];
        #pragma unroll
        for (int q = 0; q < 4; ++q) {
            *(float4*)&Bt[q * 4] = *(const float4*)&bcs[t * 32 + q * 4];
            *(float4*)&Ct[q * 4] = *(const float4*)&bcs[t * 32 + 16 + q * 4];
        }
        (void)Ct;   // Ct unused in scanA (kept for symmetric codegen)
        #pragma unroll
        for (int n = 0; n < 16; ++n) {
            const float dA = fexp2(dt * A[n]);
            s[n] = fmaf(s[n], dA, Bt[n] * x);
        }
    }
    const size_t g = (size_t)(b * NCH + ch) * Dc + d;
    #pragma unroll
    for (int n = 0; n < 16; ++n) S[g * 16 + n] = s[n];
    dcend[g] = dc;
}

__global__ __launch_bounds__(256)
void scanB(float* __restrict__ S_io, const float* __restrict__ dcend,
           const float* __restrict__ Abuf)
{
    const int tid = blockIdx.x * 256 + threadIdx.x;
    const int n = tid & 15;
    const int d = (tid >> 4) % Dc;
    const int b = tid / (16 * Dc);
    const float An = Abuf[d * 16 + n];
    float s = 0.f;
    for (int ch = 0; ch < NCH; ++ch) {
        const size_t g = (size_t)(b * NCH + ch) * Dc + d;
        const float sv = S_io[g * 16 + n];
        const float p  = fexp2(dcend[g] * An);
        S_io[g * 16 + n] = s;
        s = fmaf(s, p, sv);
    }
}

__global__ __launch_bounds__(256)
void scanC(const float* __restrict__ dtbc, const __hip_bfloat16* __restrict__ xsb,
           const __hip_bfloat16* __restrict__ xz16,
           const float* __restrict__ Abuf, const float* __restrict__ bdt,
           const float* __restrict__ Ibuf, const float* __restrict__ Dvec,
           __hip_bfloat16* __restrict__ ybf)
{
    const int blk = blockIdx.x;
    const int dblk = blk % 3, ch = (blk / 3) % NCH, b = blk / (3 * NCH);
    const int d = dblk * 256 + threadIdx.x;
    const int t0 = ch * TCH;
    const size_t brow = (size_t)(b * Lc + t0);

    __shared__ float bcs[TCH * 32];
    {
        const int row = threadIdx.x >> 3, c4 = (threadIdx.x & 7) * 4;
        *(float4*)&bcs[row * 32 + c4] =
            *(const float4*)(dtbc + (brow + row) * NDTBC + Dc + c4);
    }
    __syncthreads();

    float A[16], s[16];
    #pragma unroll
    for (int q = 0; q < 4; ++q)
        *(float4*)&A[q * 4] = *(const float4*)(Abuf + d * 16 + q * 4);
    const size_t g = (size_t)(b * NCH + ch) * Dc + d;
    #pragma unroll
    for (int q = 0; q < 4; ++q)
        *(float4*)&s[q * 4] = *(const float4*)(Ibuf + g * 16 + q * 4);
    const float bd = bdt[d];
    const float Dd = Dvec[d];

    #pragma unroll 2
    for (int t = 0; t < TCH; ++t) {
        const float dt = softplusf(dtbc[(brow + t) * NDTBC + d] + bd);
        const float x  = __bfloat162float(xsb[(brow + t) * Dc + d]);
        const float z  = __bfloat162float(xz16[(brow + t) * TWO_D + Dc + d]);
        float Bt[16], Ct[16];
        #pragma unroll
        for (int q = 0; q < 4; ++q) {
            *(float4*)&Bt[q * 4] = *(const float4*)&bcs[t * 32 + q * 4];
            *(float4*)&Ct[q * 4] = *(const float4*)&bcs[t * 32 + 16 + q * 4];
        }
        float yl = fmaf(Dd, x, 0.f);
        #pragma unroll
        for (int n = 0; n < 16; ++n) {
            const float dA = fexp2(dt * A[n]);
            s[n] = fmaf(s[n], dA, Bt[n] * x);
            yl = fmaf(s[n], Ct[n], yl);
        }
        ybf[(brow + t) * Dc + d] = __float2bfloat16(yl * siluf(z));
    }
}

extern "C" void kernel_launch(void* const* d_in, const int* in_sizes, int n_in,
                              void* d_out, int out_size, void* d_ws, size_t ws_size,
                              hipStream_t stream)
{
    const float* x      = (const float*)d_in[0];
    const float* state  = (const float*)d_in[1];
    const float* W_in   = (const float*)d_in[2];
    const float* conv_w = (const float*)d_in[3];
    const float* conv_b = (const float*)d_in[4];
    const float* W_x    = (const float*)d_in[5];
    const float* W_dt   = (const float*)d_in[6];
    const float* b_dt   = (const float*)d_in[7];
    const float* A_log  = (const float*)d_in[8];
    const float* Dvec   = (const float*)d_in[9];
    const float* W_out  = (const float*)d_in[10];
    float* out = (float*)d_out;

    // ---- workspace (~191 MB <= 253.75 verified) ----
    char* wsb = (char*)d_ws;
    __hip_bfloat16* xz16 = (__hip_bfloat16*)wsb;     wsb += (size_t)M_TOT * TWO_D * 2;
    float* dtbc  = (float*)wsb;                      wsb += (size_t)M_TOT * NDTBC * 4;  // [dt | B,C | pad]
    float* Sb    = (float*)wsb;                      wsb += (size_t)Bc * NCH * Dc * Nc * 4;
    float* dcend = (float*)wsb;                      wsb += (size_t)Bc * NCH * Dc * 4;
    __hip_bfloat16* xb  = (__hip_bfloat16*)wsb;      wsb += (size_t)M_TOT * Dc * 2;
    __hip_bfloat16* xsb = (__hip_bfloat16*)wsb;      wsb += (size_t)M_TOT * Dc * 2;
    float* Abuf = (float*)wsb;                       wsb += (size_t)Dc * Nc * 4;
    __hip_bfloat16* WinT  = (__hip_bfloat16*)wsb;    wsb += (size_t)1536 * Kd * 2;
    __hip_bfloat16* WcatT = (__hip_bfloat16*)wsb;    wsb += (size_t)NDTBC * Kd * 2;  // [W_dt|W_x|poison]
    __hip_bfloat16* WoutT = (__hip_bfloat16*)wsb;    wsb += (size_t)768 * Kd * 2;
    float* Ib = Sb;                               // scanB in-place (verified)
    __hip_bfloat16* ybf = xb;                     // xb dead after in_proj

    // ---- prep (no memset; no templates; tiled transposes) ----
    to_bf16_kernel<<<(M_TOT * Dc / 4 + 255) / 256, 256, 0, stream>>>(x, xb, M_TOT * Dc / 4);
    wtrans_tile<<<dim3(1536 / 32, Kd / 32), 256, 0, stream>>>(W_in, WinT, 1536);
    wtrans_tile<<<dim3(768 / 32, Kd / 32), 256, 0, stream>>>(W_dt, WcatT, 768);
    wtrans_tile<<<dim3(32 / 32, Kd / 32), 256, 0, stream>>>(W_x, WcatT + (size_t)768 * Kd, 32);
    wtrans_tile<<<dim3(768 / 32, Kd / 32), 256, 0, stream>>>(W_out, WoutT, 768);
    aprep_kernel<<<(Dc * Nc + 255) / 256, 256, 0, stream>>>(A_log, Abuf);

    // 1) in_proj fused N=1536, bf16 out
    gemm_bf16_b16<<<dim3(TWO_D / 128, M_TOT / 128), 256, 0, stream>>>(
        xb, WinT, TWO_D, xz16);
    // 2) t-blocked conv + silu -> bf16 xsb
    conv_silu_kernel<<<((M_TOT / 8) * Dc + 255) / 256, 256, 0, stream>>>(
        xz16, conv_w, conv_b, xsb);
    // 3) fused dt|BC: dtbc = xsb @ [W_dt|W_x|pad], N=896 (same non-template kernel)
    gemm_bf16_f32<<<dim3(NDTBC / 128, M_TOT / 128), 256, 0, stream>>>(
        xsb, WcatT, NDTBC, dtbc);
    // 4) scan
    scanA<<<Bc * NCH * 3, 256, 0, stream>>>(dtbc, xsb, Abuf, b_dt, Sb, dcend);
    scanB<<<(Bc * Dc * Nc) / 256, 256, 0, stream>>>(Sb, dcend, Abuf);
    scanC<<<Bc * NCH * 3, 256, 0, stream>>>(dtbc, xsb, xz16, Abuf, b_dt, Ib, Dvec, ybf);
    // 5) out = y @ W_out (N=768)
    gemm_bf16_f32<<<dim3(Dc / 128, M_TOT / 128), 256, 0, stream>>>(ybf, WoutT, Dc, out);
    // 6) state pass-through
    hipMemcpyAsync(out + (size_t)M_TOT * Dc, state,
                   (size_t)(Bc * Dc * Nc) * sizeof(float),
                   hipMemcpyDeviceToDevice, stream);
}